// Round 10
// baseline (2209.126 us; speedup 1.0000x reference)
//
#include <hip/hip_runtime.h>
#include <hip/hip_bf16.h>
#include <stdint.h>

#define BB 4
#define TT 64
#define NN 4096
#define HH 128
#define EE 65536
#define BN (BB*NN)   // 16384

typedef __attribute__((ext_vector_type(8))) short short8;
typedef __attribute__((ext_vector_type(4))) float f32x4;

__device__ __forceinline__ unsigned short bf16r(float f) {
    unsigned u = __float_as_uint(f);
    u += 0x7fffu + ((u >> 16) & 1u);
    return (unsigned short)(u >> 16);
}
__device__ __forceinline__ float bf2f(unsigned bits16) {
    return __uint_as_float(bits16 << 16);
}
__device__ __forceinline__ float sigm(float x) { return 1.f / (1.f + __expf(-x)); }
__device__ __forceinline__ float tanhfast(float x) {
    return 1.f - 2.f / (__expf(2.f * x) + 1.f);
}
// byte address within a [64][128]-bf16 tile image, XOR-swizzled
__device__ __forceinline__ unsigned swz(int row, int colbyte) {
    return (unsigned)(row * 256 + (colbyte ^ ((row & 7) << 4)));
}

#define GLD_LDS16(g, s) __builtin_amdgcn_global_load_lds( \
    (const __attribute__((address_space(1))) void*)(g), \
    (__attribute__((address_space(3))) void*)(s), 16, 0, 0)

// ================= packs =================
__global__ void pack_wcb_kernel(const float* __restrict__ W_msg, const float* __restrict__ W_mix,
                                short* __restrict__ out)
{
    int idx = blockIdx.x * 256 + threadIdx.x;   // 4096
    if (idx >= 4096) return;
    int l = idx & 63, ks = (idx >> 6) & 3, nt = (idx >> 8) & 7, half = idx >> 11;
    int lo = l & 15, hi = l >> 4;
    int col = nt * 16 + lo;
    short8 v;
    #pragma unroll
    for (int i = 0; i < 8; ++i) {
        int k = ks * 32 + hi * 8 + i;
        float s;
        if (half == 0) {
            s = 0.f;
            for (int j = 0; j < 128; ++j) s += W_msg[k * 128 + j] * W_mix[j * 128 + col];
        } else {
            s = W_mix[(128 + k) * 128 + col];
        }
        v[i] = (short)bf16r(s);
    }
    *(short8*)(out + (size_t)idx * 8) = v;
}

__global__ void pack_ihh_kernel(const float* __restrict__ Wih, const float* __restrict__ Whh,
                                short* __restrict__ out)
{
    int idx = blockIdx.x * 256 + threadIdx.x;   // 16384
    if (idx >= 32 * 8 * 64) return;
    int l = idx & 63, ks = (idx >> 6) & 7, nt = idx >> 9;
    int lo = l & 15, hi = l >> 4;
    short8 v;
    #pragma unroll
    for (int i = 0; i < 8; ++i) {
        int k = ks * 32 + hi * 8 + i;
        float s = 0.f;
        if (nt < 16) {
            int col = nt * 16 + lo;
            s = (ks < 4) ? Wih[k * 384 + col] : Whh[(k - 128) * 384 + col];
        } else if (nt < 24) {
            int col = 256 + (nt - 16) * 16 + lo;
            s = (ks < 4) ? Wih[k * 384 + col] : 0.f;
        } else {
            int col = 256 + (nt - 24) * 16 + lo;
            s = (ks >= 4) ? Whh[(k - 128) * 384 + col] : 0.f;
        }
        v[i] = (short)bf16r(s);
    }
    *(short8*)(out + (size_t)idx * 8) = v;
}

__global__ void pack_bias_kernel(const float* __restrict__ b_ih, const float* __restrict__ b_hh,
                                 const float* __restrict__ b_msg, const float* __restrict__ W_mix,
                                 float* __restrict__ biasRZ, float* __restrict__ bvec)
{
    int j = threadIdx.x;
    biasRZ[j]       = b_ih[j]       + b_hh[j];
    biasRZ[128 + j] = b_ih[128 + j] + b_hh[128 + j];
    float s = 0.f;
    for (int jj = 0; jj < 128; ++jj) s += b_msg[jj] * W_mix[jj * 128 + j];
    bvec[j] = s;
}

// ===== gather + x-convert fused: aimg/ximg pre-swizzled bf16 tile images =====
__global__ __launch_bounds__(256)
void gather_img_kernel(const float* __restrict__ x,
                       const int* __restrict__ off, const int* __restrict__ srcs,
                       char* __restrict__ aimg, char* __restrict__ ximg)
{
    int rb = blockIdx.x * 4 + (threadIdx.x >> 6);   // bt*4096 + dst
    int l = threadIdx.x & 63;
    int dst = rb & 4095;
    int bt  = rb >> 12;                              // b*64 + t
    const float* __restrict__ xr = x + (size_t)bt * NN * HH;
    int s = off[dst], e = off[dst + 1];
    float a0 = 0.f, a1 = 0.f;
    int i = s;
    for (; i + 7 < e; i += 8) {
        float2 v0 = *(const float2*)(xr + (size_t)srcs[i + 0] * HH + l * 2);
        float2 v1 = *(const float2*)(xr + (size_t)srcs[i + 1] * HH + l * 2);
        float2 v2 = *(const float2*)(xr + (size_t)srcs[i + 2] * HH + l * 2);
        float2 v3 = *(const float2*)(xr + (size_t)srcs[i + 3] * HH + l * 2);
        float2 v4 = *(const float2*)(xr + (size_t)srcs[i + 4] * HH + l * 2);
        float2 v5 = *(const float2*)(xr + (size_t)srcs[i + 5] * HH + l * 2);
        float2 v6 = *(const float2*)(xr + (size_t)srcs[i + 6] * HH + l * 2);
        float2 v7 = *(const float2*)(xr + (size_t)srcs[i + 7] * HH + l * 2);
        a0 += ((v0.x + v1.x) + (v2.x + v3.x)) + ((v4.x + v5.x) + (v6.x + v7.x));
        a1 += ((v0.y + v1.y) + (v2.y + v3.y)) + ((v4.y + v5.y) + (v6.y + v7.y));
    }
    for (; i + 1 < e; i += 2) {
        float2 v0 = *(const float2*)(xr + (size_t)srcs[i] * HH + l * 2);
        float2 v1 = *(const float2*)(xr + (size_t)srcs[i + 1] * HH + l * 2);
        a0 += v0.x + v1.x; a1 += v0.y + v1.y;
    }
    if (i < e) {
        float2 v0 = *(const float2*)(xr + (size_t)srcs[i] * HH + l * 2);
        a0 += v0.x; a1 += v0.y;
    }
    int b = bt >> 6, t = bt & 63;
    int phys = (b << 6) | (dst >> 6);
    int row = dst & 63;
    size_t tile = ((size_t)phys * TT + t) * 16384;
    *(unsigned*)(aimg + tile + swz(row, l * 4)) =
        (unsigned)bf16r(a0) | ((unsigned)bf16r(a1) << 16);
    // also convert this node's own x row into ximg (slab is L2-hot)
    float2 xv = *(const float2*)(xr + (size_t)dst * HH + l * 2);
    *(unsigned*)(ximg + tile + swz(row, l * 4)) =
        (unsigned)bf16r(xv.x) | ((unsigned)bf16r(xv.y) << 16);
}

// ================= persistent T-loop: compile-time ping-pong + asm barriers =================
#define MID_BARRIER() do { \
    asm volatile("s_waitcnt lgkmcnt(0)" ::: "memory"); \
    __builtin_amdgcn_sched_barrier(0); \
    __builtin_amdgcn_s_barrier(); \
    __builtin_amdgcn_sched_barrier(0); } while (0)

#define END_BARRIER() do { \
    asm volatile("s_waitcnt vmcnt(0) lgkmcnt(0)" ::: "memory"); \
    __builtin_amdgcn_sched_barrier(0); \
    __builtin_amdgcn_s_barrier(); \
    __builtin_amdgcn_sched_barrier(0); } while (0)

#define STEP_BODY(T, SAC, SAN, SXC, SXN) { \
    const int t = (T); \
    /* loss consume for t-1 + targets prefetch for t */ \
    { \
        float tgtNew = tgtReg, mvNew = mvReg; \
        if (tid < 64) { \
            if (t > 0) { \
                float out = bro; \
                _Pragma("unroll") \
                for (int ww = 0; ww < 8; ++ww) out += pP[ww][tid]; \
                float d = out - tgtReg; \
                lossAcc += 0.5f * d * d * mvReg; \
            } \
            size_t ti = (size_t)(b * TT + t) * NN + n0 + tid; \
            tgtNew = targets[ti]; \
            mvNew = fl ? (((const unsigned char*)maskp)[ti] ? 1.f : 0.f) \
                       : (((const int*)maskp)[ti] ? 1.f : 0.f); \
        } \
        tgtReg = tgtNew; mvReg = mvNew; \
    } \
    /* issue async staging for t+1 into the ping buffers (drained before END barrier) */ \
    if (t + 1 < TT) { \
        const size_t toff = tbase + (size_t)(t + 1) * 16384; \
        const char* gx = ximg + toff + (w * 2) * 1024 + l * 16; \
        const char* ga = aimg + toff + (w * 2) * 1024 + l * 16; \
        GLD_LDS16(gx,        (char*)SXN + (w * 2) * 1024); \
        GLD_LDS16(gx + 1024, (char*)SXN + (w * 2 + 1) * 1024); \
        GLD_LDS16(ga,        (char*)SAN + (w * 2) * 1024); \
        GLD_LDS16(ga + 1024, (char*)SAN + (w * 2 + 1) * 1024); \
    } \
    /* B: mi = agg@Wc + state@Wb + deg*bvec + b_mix */ \
    { \
        f32x4 mAcc[4] = {}; \
        _Pragma("unroll") \
        for (int ks = 0; ks < 8; ++ks) { \
            _Pragma("unroll") \
            for (int s4 = 0; s4 < 4; ++s4) { \
                short8 af = (ks < 4) \
                    ? *(const short8*)((const char*)SAC + swz(s4 * 16 + lo, ks * 64 + hi * 16)) \
                    : *(const short8*)((const char*)sSt + swz(s4 * 16 + lo, (ks - 4) * 64 + hi * 16)); \
                mAcc[s4] = __builtin_amdgcn_mfma_f32_16x16x32_bf16(af, wB[ks], mAcc[s4], 0, 0, 0); \
            } \
        } \
        _Pragma("unroll") \
        for (int s4 = 0; s4 < 4; ++s4) \
            _Pragma("unroll") \
            for (int q = 0; q < 4; ++q) { \
                int row = s4 * 16 + hi * 4 + q; \
                float v = mAcc[s4][q] + sdeg[row] * bv + bm; \
                unsigned bits = bf16r(v); \
                unsigned other = (unsigned)__shfl_xor((int)bits, 1); \
                if (!(lo & 1)) \
                    *(unsigned*)((char*)sMi + swz(row, jcol * 2)) = bits | (other << 16); \
            } \
    } \
    MID_BARRIER(); \
    /* C: R/Z (K=256), N (K=128, A=mi), H (K=128, A=x) */ \
    f32x4 aR[4] = {}, aZ[4] = {}, aN4[4] = {}, aH4[4] = {}; \
    _Pragma("unroll") \
    for (int ks = 0; ks < 8; ++ks) { \
        short8 af[4]; \
        _Pragma("unroll") \
        for (int s4 = 0; s4 < 4; ++s4) \
            af[s4] = (ks < 4) \
                ? *(const short8*)((const char*)sMi + swz(s4 * 16 + lo, ks * 64 + hi * 16)) \
                : *(const short8*)((const char*)SXC + swz(s4 * 16 + lo, (ks - 4) * 64 + hi * 16)); \
        _Pragma("unroll") \
        for (int s4 = 0; s4 < 4; ++s4) \
            aR[s4] = __builtin_amdgcn_mfma_f32_16x16x32_bf16(af[s4], wR[ks], aR[s4], 0, 0, 0); \
        _Pragma("unroll") \
        for (int s4 = 0; s4 < 4; ++s4) \
            aZ[s4] = __builtin_amdgcn_mfma_f32_16x16x32_bf16(af[s4], wZ[ks], aZ[s4], 0, 0, 0); \
        if (ks < 4) { \
            _Pragma("unroll") \
            for (int s4 = 0; s4 < 4; ++s4) \
                aN4[s4] = __builtin_amdgcn_mfma_f32_16x16x32_bf16(af[s4], wN[ks], aN4[s4], 0, 0, 0); \
        } else { \
            _Pragma("unroll") \
            for (int s4 = 0; s4 < 4; ++s4) \
                aH4[s4] = __builtin_amdgcn_mfma_f32_16x16x32_bf16(af[s4], wH[ks - 4], aH4[s4], 0, 0, 0); \
        } \
    } \
    /* D: gates, state write, W_ro partial dot */ \
    { \
        float pacc[4][4]; \
        _Pragma("unroll") \
        for (int s4 = 0; s4 < 4; ++s4) \
            _Pragma("unroll") \
            for (int q = 0; q < 4; ++q) { \
                int row = s4 * 16 + hi * 4 + q; \
                float rg = sigm(aR[s4][q] + br); \
                float zg = sigm(aZ[s4][q] + bz); \
                float ng = tanhfast(aN4[s4][q] + bi + rg * (aH4[s4][q] + bh)); \
                float xv = bf2f(*(const unsigned short*)((const char*)SXC + swz(row, jcol * 2))); \
                float ns = (1.f - zg) * ng + zg * xv; \
                unsigned bits = bf16r(ns); \
                unsigned other = (unsigned)__shfl_xor((int)bits, 1); \
                if (!(lo & 1)) \
                    *(unsigned*)((char*)sSt + swz(row, jcol * 2)) = bits | (other << 16); \
                pacc[s4][q] = ns * wro; \
            } \
        _Pragma("unroll") \
        for (int o = 1; o < 16; o <<= 1) \
            _Pragma("unroll") \
            for (int s4 = 0; s4 < 4; ++s4) \
                _Pragma("unroll") \
                for (int q = 0; q < 4; ++q) \
                    pacc[s4][q] += __shfl_xor(pacc[s4][q], o); \
        if (lo == 0) { \
            _Pragma("unroll") \
            for (int s4 = 0; s4 < 4; ++s4) \
                _Pragma("unroll") \
                for (int q = 0; q < 4; ++q) \
                    pP[w][s4 * 16 + hi * 4 + q] = pacc[s4][q]; \
        } \
    } \
    END_BARRIER(); \
}

__global__ __launch_bounds__(512, 2)
void mega6_kernel(const char* __restrict__ ximg, const char* __restrict__ aimg,
                  const short* __restrict__ WcbP, const short* __restrict__ Wp4,
                  const float* __restrict__ degf,
                  const float* __restrict__ bvec, const float* __restrict__ b_mix,
                  const float* __restrict__ biasRZ,
                  const float* __restrict__ b_ih, const float* __restrict__ b_hh,
                  const float* __restrict__ W_ro, const float* __restrict__ b_ro,
                  const float* __restrict__ targets, const void* __restrict__ maskp,
                  const int* __restrict__ flag,
                  float* __restrict__ lossBlock)
{
    __shared__ char sX0[16384];
    __shared__ char sX1[16384];
    __shared__ char sA0[16384];
    __shared__ char sA1[16384];
    __shared__ char sMi[16384];
    __shared__ char sSt[16384];
    __shared__ float pP[8][64];
    __shared__ float sdeg[64];

    const int tid = threadIdx.x;
    const int w = tid >> 6, l = tid & 63, lo = l & 15, hi = l >> 4;
    const int nt = w;
    const int phys = blockIdx.x;
    const int b = phys >> 6;
    const int n0 = (phys & 63) * 64;
    const size_t tbase = (size_t)phys * TT * 16384;

    // ---- all B-fragments in registers, loaded once ----
    short8 wB[8], wR[8], wZ[8], wN[4], wH[4];
    #pragma unroll
    for (int ks = 0; ks < 8; ++ks) {
        wB[ks] = *(const short8*)(WcbP + (size_t)((((ks >> 2) * 8 + nt) * 4 + (ks & 3)) * 64 + l) * 8);
        wR[ks] = *(const short8*)(Wp4 + (size_t)((nt * 8 + ks) * 64 + l) * 8);
        wZ[ks] = *(const short8*)(Wp4 + (size_t)(((8 + nt) * 8 + ks) * 64 + l) * 8);
    }
    #pragma unroll
    for (int ks = 0; ks < 4; ++ks) {
        wN[ks] = *(const short8*)(Wp4 + (size_t)(((16 + nt) * 8 + ks) * 64 + l) * 8);
        wH[ks] = *(const short8*)(Wp4 + (size_t)(((24 + nt) * 8 + (ks + 4)) * 64 + l) * 8);
    }

    const int jcol = nt * 16 + lo;
    const float br = biasRZ[jcol], bz = biasRZ[128 + jcol];
    const float bi = b_ih[256 + jcol], bh = b_hh[256 + jcol];
    const float wro = W_ro[jcol];
    const float bv = bvec[jcol], bm = b_mix[jcol];
    const float bro = b_ro[0];
    const int fl = *flag;

    // ---- prologue: async-stage t=0, zero state, first targets prefetch ----
    {
        const char* gx = ximg + tbase + (w * 2) * 1024 + l * 16;
        const char* ga = aimg + tbase + (w * 2) * 1024 + l * 16;
        GLD_LDS16(gx,        sX0 + (w * 2) * 1024);
        GLD_LDS16(gx + 1024, sX0 + (w * 2 + 1) * 1024);
        GLD_LDS16(ga,        sA0 + (w * 2) * 1024);
        GLD_LDS16(ga + 1024, sA0 + (w * 2 + 1) * 1024);
    }
    #pragma unroll
    for (int it = 0; it < 8; ++it) ((unsigned*)sSt)[tid + it * 512] = 0u;
    if (tid < 64) sdeg[tid] = degf[n0 + tid];

    float tgtReg = 0.f, mvReg = 0.f, lossAcc = 0.f;
    __syncthreads();   // drains prologue staging (vmcnt+lgkm)

    for (int tt = 0; tt < TT; tt += 2) {
        STEP_BODY(tt,     sA0, sA1, sX0, sX1)
        STEP_BODY(tt + 1, sA1, sA0, sX1, sX0)
    }

    // final loss consume (t=63) + block reduce
    if (tid < 64) {
        float out = bro;
        #pragma unroll
        for (int ww = 0; ww < 8; ++ww) out += pP[ww][tid];
        float d = out - tgtReg;
        lossAcc += 0.5f * d * d * mvReg;
        float v = lossAcc;
        #pragma unroll
        for (int o = 1; o < 64; o <<= 1) v += __shfl_xor(v, o);
        if (tid == 0) lossBlock[phys] = v;
    }
}

// ================= CSR build =================
__global__ void count_kernel(const int* __restrict__ dst, int* __restrict__ counts)
{
    int e = blockIdx.x * 256 + threadIdx.x;
    if (e < EE) atomicAdd(&counts[dst[e]], 1);
}

__global__ __launch_bounds__(1024)
void scan_kernel(const int* __restrict__ counts, int* __restrict__ off, int* __restrict__ cursor,
                 float* __restrict__ degf)
{
    __shared__ int s[1024];
    int tid = threadIdx.x;
    int base = tid * 4;
    int c[4]; int sum = 0;
    #pragma unroll
    for (int i = 0; i < 4; ++i) { c[i] = counts[base + i]; sum += c[i]; }
    s[tid] = sum; __syncthreads();
    for (int o = 1; o < 1024; o <<= 1) {
        int v = (tid >= o) ? s[tid - o] : 0;
        __syncthreads();
        s[tid] += v;
        __syncthreads();
    }
    int incl = s[tid];
    int run = incl - sum;
    #pragma unroll
    for (int i = 0; i < 4; ++i) {
        off[base + i] = run; cursor[base + i] = run;
        degf[base + i] = (float)c[i];
        run += c[i];
    }
    if (tid == 1023) off[4096] = incl;
}

__global__ void fill_kernel(const int* __restrict__ src, const int* __restrict__ dst,
                            int* __restrict__ cursor, int* __restrict__ csr_src)
{
    int e = blockIdx.x * 256 + threadIdx.x;
    if (e < EE) {
        int d = dst[e];
        int pos = atomicAdd(&cursor[d], 1);
        csr_src[pos] = src[e];
    }
}

// ================= mask detect / masked count =================
__global__ void detect_kernel(const unsigned char* __restrict__ maskb, int* __restrict__ flag)
{
    int i = blockIdx.x * 256 + threadIdx.x;
    bool hit = (i < BB * TT * NN) && (i & 3) && maskb[i];
    if (__any(hit) && (threadIdx.x & 63) == 0) atomicOr(flag, 1);
}

__global__ void masksum_kernel(const void* __restrict__ maskp, const int* __restrict__ flag,
                               float* __restrict__ den)
{
    int i = blockIdx.x * 256 + threadIdx.x;
    float v = 0.f;
    if (i < BB * TT * NN) {
        if (*flag) v = ((const unsigned char*)maskp)[i] ? 1.f : 0.f;
        else       v = ((const int*)maskp)[i] ? 1.f : 0.f;
    }
    #pragma unroll
    for (int o = 32; o > 0; o >>= 1) v += __shfl_down(v, o);
    __shared__ float sm[4];
    if ((threadIdx.x & 63) == 0) sm[threadIdx.x >> 6] = v;
    __syncthreads();
    if (threadIdx.x == 0) atomicAdd(den, sm[0] + sm[1] + sm[2] + sm[3]);
}

// ================= final reduce + dual-dtype output =================
__global__ __launch_bounds__(256)
void final_kernel(const float* __restrict__ lossBlock, const float* __restrict__ den,
                  unsigned* __restrict__ out)
{
    __shared__ float s[256];
    s[threadIdx.x] = lossBlock[threadIdx.x];
    __syncthreads();
    for (int o = 128; o > 0; o >>= 1) {
        if (threadIdx.x < o) s[threadIdx.x] += s[threadIdx.x + o];
        __syncthreads();
    }
    if (threadIdx.x == 0) {
        float L = s[0] / den[0];
        unsigned u = __float_as_uint(L);
        u += 0x7fffu + ((u >> 16) & 1u);
        unsigned hi = u >> 16;
        out[0] = hi * 0x10001u;   // bf16-exact low half; ~bf16 value as f32
    }
}

extern "C" void kernel_launch(void* const* d_in, const int* in_sizes, int n_in,
                              void* d_out, int out_size, void* d_ws, size_t ws_size,
                              hipStream_t stream)
{
    const float* x       = (const float*)d_in[0];
    const float* targets = (const float*)d_in[1];
    const float* W_msg   = (const float*)d_in[2];
    const float* b_msg   = (const float*)d_in[3];
    const float* W_mix   = (const float*)d_in[4];
    const float* b_mix   = (const float*)d_in[5];
    const float* W_ih    = (const float*)d_in[6];
    const float* b_ih    = (const float*)d_in[7];
    const float* W_hh    = (const float*)d_in[8];
    const float* b_hh    = (const float*)d_in[9];
    const float* W_ro    = (const float*)d_in[10];
    const float* b_ro    = (const float*)d_in[11];
    const void*  maskp   = d_in[12];
    const int*   esrc    = (const int*)d_in[13];
    const int*   edst    = (const int*)d_in[14];

    char* ws = (char*)d_ws;
    char* ximg = ws; ws += (size_t)16384 * 16384;   // 268 MB pre-swizzled x tiles
    char* aimg = ws; ws += (size_t)16384 * 16384;   // 268 MB pre-swizzled agg tiles
    short* WcbP        = (short*)ws; ws += (size_t)4096 * 8 * 2;
    short* Wp4         = (short*)ws; ws += (size_t)32 * 8 * 64 * 8 * 2;
    float* biasRZ      = (float*)ws; ws += 256 * 4;
    float* bvec        = (float*)ws; ws += 128 * 4;
    float* degf        = (float*)ws; ws += 4096 * 4;
    float* lossBlock   = (float*)ws; ws += 256 * 4;
    int*   csr_off     = (int*)ws;   ws += 4104 * 4;
    int*   cursor      = (int*)ws;   ws += 4096 * 4;
    int*   counts      = (int*)ws;   ws += 4096 * 4;
    int*   csr_src     = (int*)ws;   ws += (size_t)EE * 4;
    int*   flag        = (int*)ws;   ws += 64;
    float* den         = (float*)ws; ws += 64;

    hipMemsetAsync(counts, 0, 4096 * 4, stream);
    hipMemsetAsync(flag, 0, 64, stream);
    hipMemsetAsync(den, 0, 4, stream);

    detect_kernel   <<<4096, 256, 0, stream>>>((const unsigned char*)maskp, flag);
    masksum_kernel  <<<4096, 256, 0, stream>>>(maskp, flag, den);
    count_kernel    <<<EE / 256, 256, 0, stream>>>(edst, counts);
    scan_kernel     <<<1, 1024, 0, stream>>>(counts, csr_off, cursor, degf);
    fill_kernel     <<<EE / 256, 256, 0, stream>>>(esrc, edst, cursor, csr_src);
    pack_wcb_kernel <<<16, 256, 0, stream>>>(W_msg, W_mix, WcbP);
    pack_ihh_kernel <<<64, 256, 0, stream>>>(W_ih, W_hh, Wp4);
    pack_bias_kernel<<<1, 128, 0, stream>>>(b_ih, b_hh, b_msg, W_mix, biasRZ, bvec);

    gather_img_kernel<<<(BB * TT * NN) / 4, 256, 0, stream>>>(x, csr_off, csr_src, aimg, ximg);

    mega6_kernel<<<256, 512, 0, stream>>>(ximg, aimg, WcbP, Wp4, degf, bvec, b_mix, biasRZ,
                                          b_ih, b_hh, W_ro, b_ro, targets, maskp, flag,
                                          lossBlock);
    final_kernel<<<1, 256, 0, stream>>>(lossBlock, den, (unsigned*)d_out);
}

// Round 11
// 2009.169 us; speedup vs baseline: 1.0995x; 1.0995x over previous
//
#include <hip/hip_runtime.h>
#include <hip/hip_bf16.h>
#include <stdint.h>

#define BB 4
#define TT 64
#define NN 4096
#define HH 128
#define EE 65536
#define BN (BB*NN)   // 16384

typedef __attribute__((ext_vector_type(8))) short short8;
typedef __attribute__((ext_vector_type(4))) float f32x4;

__device__ __forceinline__ unsigned short bf16r(float f) {
    unsigned u = __float_as_uint(f);
    u += 0x7fffu + ((u >> 16) & 1u);
    return (unsigned short)(u >> 16);
}
__device__ __forceinline__ float bf2f(unsigned bits16) {
    return __uint_as_float(bits16 << 16);
}
__device__ __forceinline__ float sigm(float x) { return 1.f / (1.f + __expf(-x)); }
__device__ __forceinline__ float tanhfast(float x) {
    return 1.f - 2.f / (__expf(2.f * x) + 1.f);
}
// byte address within a [64][128]-bf16 LDS tile, XOR-swizzled (16B-unit granularity)
__device__ __forceinline__ unsigned swz(int row, int colbyte) {
    return (unsigned)(row * 256 + (colbyte ^ ((row & 7) << 4)));
}

// ================= packs =================
// WcbP: [half][nt(8)][ks(4)][lane(64)][8].  half0: Wc = W_msg@W_mix[0:128]; half1: W_mix[128:256]
__global__ void pack_wcb_kernel(const float* __restrict__ W_msg, const float* __restrict__ W_mix,
                                short* __restrict__ out)
{
    int idx = blockIdx.x * 256 + threadIdx.x;   // 4096
    if (idx >= 4096) return;
    int l = idx & 63, ks = (idx >> 6) & 3, nt = (idx >> 8) & 7, half = idx >> 11;
    int lo = l & 15, hi = l >> 4;
    int col = nt * 16 + lo;
    short8 v;
    #pragma unroll
    for (int i = 0; i < 8; ++i) {
        int k = ks * 32 + hi * 8 + i;
        float s;
        if (half == 0) {
            s = 0.f;
            for (int j = 0; j < 128; ++j) s += W_msg[k * 128 + j] * W_mix[j * 128 + col];
        } else {
            s = W_mix[(128 + k) * 128 + col];
        }
        v[i] = (short)bf16r(s);
    }
    *(short8*)(out + (size_t)idx * 8) = v;
}

__global__ void pack_ihh_kernel(const float* __restrict__ Wih, const float* __restrict__ Whh,
                                short* __restrict__ out)
{
    int idx = blockIdx.x * 256 + threadIdx.x;   // 16384
    if (idx >= 32 * 8 * 64) return;
    int l = idx & 63, ks = (idx >> 6) & 7, nt = idx >> 9;
    int lo = l & 15, hi = l >> 4;
    short8 v;
    #pragma unroll
    for (int i = 0; i < 8; ++i) {
        int k = ks * 32 + hi * 8 + i;
        float s = 0.f;
        if (nt < 16) {
            int col = nt * 16 + lo;
            s = (ks < 4) ? Wih[k * 384 + col] : Whh[(k - 128) * 384 + col];
        } else if (nt < 24) {
            int col = 256 + (nt - 16) * 16 + lo;
            s = (ks < 4) ? Wih[k * 384 + col] : 0.f;
        } else {
            int col = 256 + (nt - 24) * 16 + lo;
            s = (ks >= 4) ? Whh[(k - 128) * 384 + col] : 0.f;
        }
        v[i] = (short)bf16r(s);
    }
    *(short8*)(out + (size_t)idx * 8) = v;
}

// W_roP: [ks(4)][lane(64)][8]; B[k][col]: col=lo -> only col 0 nonzero = W_ro[k]
__global__ void pack_wro_kernel(const float* __restrict__ W_ro, short* __restrict__ out)
{
    int idx = threadIdx.x;      // 256
    int l = idx & 63, ks = idx >> 6;
    int lo = l & 15, hi = l >> 4;
    short8 v;
    #pragma unroll
    for (int i = 0; i < 8; ++i) {
        int k = ks * 32 + hi * 8 + i;
        v[i] = (lo == 0) ? (short)bf16r(W_ro[k]) : (short)0;
    }
    *(short8*)(out + (size_t)idx * 8) = v;
}

__global__ void pack_bias_kernel(const float* __restrict__ b_ih, const float* __restrict__ b_hh,
                                 const float* __restrict__ b_msg, const float* __restrict__ W_mix,
                                 float* __restrict__ biasRZ, float* __restrict__ bvec)
{
    int j = threadIdx.x;
    biasRZ[j]       = b_ih[j]       + b_hh[j];
    biasRZ[128 + j] = b_ih[128 + j] + b_hh[128 + j];
    float s = 0.f;
    for (int jj = 0; jj < 128; ++jj) s += b_msg[jj] * W_mix[jj * 128 + j];
    bvec[j] = s;
}

// ================= x -> bf16 row-major (once) =================
__global__ __launch_bounds__(256)
void cvt_all_kernel(const float* __restrict__ src, unsigned short* __restrict__ dst, long nchunk)
{
    long i = (long)blockIdx.x * 256 + threadIdx.x;
    long stride = (long)gridDim.x * 256;
    for (; i < nchunk; i += stride) {
        float4 v = *(const float4*)(src + i * 4);
        ushort4 o;
        o.x = bf16r(v.x); o.y = bf16r(v.y); o.z = bf16r(v.z); o.w = bf16r(v.w);
        *(ushort4*)(dst + i * 4) = o;
    }
}

// ===== gather from bf16 slabs (1MB, L2-resident; XCD-affine bt mapping) =====
__global__ __launch_bounds__(256)
void gather_xb_kernel(const unsigned short* __restrict__ xb,
                      const int* __restrict__ off, const int* __restrict__ srcs,
                      unsigned short* __restrict__ agg)
{
    int bid = blockIdx.x;               // 262144 blocks
    int xcd = bid & 7;
    int idx = bid >> 3;                 // 0..32767
    int btl = idx >> 10;                // 0..31
    int chunk = idx & 1023;             // 0..1023
    int bt = btl * 8 + xcd;             // each XCD owns 32 bts -> slab L2-resident
    int rb = bt * 4096 + chunk * 4 + (threadIdx.x >> 6);
    int l = threadIdx.x & 63;
    int dst = rb & 4095;
    const unsigned short* __restrict__ xr = xb + (size_t)bt * NN * HH;
    int s = off[dst], e = off[dst + 1];
    float a0 = 0.f, a1 = 0.f;
    int i = s;
    for (; i + 7 < e; i += 8) {
        unsigned v0 = *(const unsigned*)(xr + (size_t)srcs[i + 0] * HH + l * 2);
        unsigned v1 = *(const unsigned*)(xr + (size_t)srcs[i + 1] * HH + l * 2);
        unsigned v2 = *(const unsigned*)(xr + (size_t)srcs[i + 2] * HH + l * 2);
        unsigned v3 = *(const unsigned*)(xr + (size_t)srcs[i + 3] * HH + l * 2);
        unsigned v4 = *(const unsigned*)(xr + (size_t)srcs[i + 4] * HH + l * 2);
        unsigned v5 = *(const unsigned*)(xr + (size_t)srcs[i + 5] * HH + l * 2);
        unsigned v6 = *(const unsigned*)(xr + (size_t)srcs[i + 6] * HH + l * 2);
        unsigned v7 = *(const unsigned*)(xr + (size_t)srcs[i + 7] * HH + l * 2);
        a0 += bf2f(v0 & 0xffffu) + bf2f(v1 & 0xffffu) + bf2f(v2 & 0xffffu) + bf2f(v3 & 0xffffu)
            + bf2f(v4 & 0xffffu) + bf2f(v5 & 0xffffu) + bf2f(v6 & 0xffffu) + bf2f(v7 & 0xffffu);
        a1 += bf2f(v0 >> 16) + bf2f(v1 >> 16) + bf2f(v2 >> 16) + bf2f(v3 >> 16)
            + bf2f(v4 >> 16) + bf2f(v5 >> 16) + bf2f(v6 >> 16) + bf2f(v7 >> 16);
    }
    for (; i < e; ++i) {
        unsigned v0 = *(const unsigned*)(xr + (size_t)srcs[i] * HH + l * 2);
        a0 += bf2f(v0 & 0xffffu); a1 += bf2f(v0 >> 16);
    }
    *(unsigned*)(agg + (size_t)rb * HH + l * 2) = (unsigned)bf16r(a0) | ((unsigned)bf16r(a1) << 16);
}

// ================= persistent T-loop: mega2 core + GEMV loss + reg staging =================
__global__ __launch_bounds__(512, 2)
void mega7_kernel(const unsigned short* __restrict__ xb,
                  const unsigned short* __restrict__ agg,
                  const short* __restrict__ WcbP, const short* __restrict__ Wp4,
                  const short* __restrict__ WroP,
                  const float* __restrict__ degf,
                  const float* __restrict__ bvec, const float* __restrict__ b_mix,
                  const float* __restrict__ biasRZ,
                  const float* __restrict__ b_ih, const float* __restrict__ b_hh,
                  const float* __restrict__ b_ro,
                  const float* __restrict__ targets, const void* __restrict__ maskp,
                  const int* __restrict__ flag,
                  float* __restrict__ lossBlock)
{
    __shared__ char sX0[16384];
    __shared__ char sX1[16384];
    __shared__ char sA0[16384];
    __shared__ char sA1[16384];
    __shared__ char sMi[16384];
    __shared__ char sSt[16384];
    __shared__ float sdeg[64];
    __shared__ float pLoss[8];

    const int tid = threadIdx.x;
    const int w = tid >> 6, l = tid & 63, lo = l & 15, hi = l >> 4;
    const int nt = w;
    const int phys = blockIdx.x;
    const int b = phys >> 6;
    const int n0 = (phys & 63) * 64;

    // ---- all B-fragments in registers, loaded once ----
    short8 wB[8], wR[8], wZ[8], wN[4], wH[4];
    #pragma unroll
    for (int ks = 0; ks < 8; ++ks) {
        wB[ks] = *(const short8*)(WcbP + (size_t)((((ks >> 2) * 8 + nt) * 4 + (ks & 3)) * 64 + l) * 8);
        wR[ks] = *(const short8*)(Wp4 + (size_t)((nt * 8 + ks) * 64 + l) * 8);
        wZ[ks] = *(const short8*)(Wp4 + (size_t)(((8 + nt) * 8 + ks) * 64 + l) * 8);
    }
    #pragma unroll
    for (int ks = 0; ks < 4; ++ks) {
        wN[ks] = *(const short8*)(Wp4 + (size_t)(((16 + nt) * 8 + ks) * 64 + l) * 8);
        wH[ks] = *(const short8*)(Wp4 + (size_t)(((24 + nt) * 8 + (ks + 4)) * 64 + l) * 8);
    }

    const int jcol = nt * 16 + lo;
    const float br = biasRZ[jcol], bz = biasRZ[128 + jcol];
    const float bi = b_ih[256 + jcol], bh = b_hh[256 + jcol];
    const float bv = bvec[jcol], bm = b_mix[jcol];
    const float bro = b_ro[0];
    const int fl = *flag;

    // staging decomposition: thread -> 2 units (16B) per buffer
    const int srow1 = tid >> 3, sseg1 = tid & 7;            // units 0..511
    const int srow2 = (tid + 512) >> 3, sseg2 = tid & 7;    // won't use: recompute properly below
    // unit u: row = u>>4, seg = u&15 ; thread handles u=tid and u=tid+512
    const int uar = tid >> 4, uas = tid & 15;               // unit tid
    const int ubr = (tid + 512) >> 4, ubs = tid & 15;       // unit tid+512 (seg same low 4? no)
    (void)srow1; (void)sseg1; (void)srow2; (void)sseg2; (void)ubs;
    const int ubs2 = (tid + 512) & 15;

    const size_t slab0 = ((size_t)(b * TT) * NN + n0) * HH;   // shorts

    // ---- prologue: stage t=0, zero state ----
    {
        short8 x1 = *(const short8*)(xb + slab0 + uar * HH + uas * 8);
        short8 x2 = *(const short8*)(xb + slab0 + ubr * HH + ubs2 * 8);
        short8 a1 = *(const short8*)(agg + slab0 + uar * HH + uas * 8);
        short8 a2 = *(const short8*)(agg + slab0 + ubr * HH + ubs2 * 8);
        *(short8*)(sX0 + swz(uar, uas * 16)) = x1;
        *(short8*)(sX0 + swz(ubr, ubs2 * 16)) = x2;
        *(short8*)(sA0 + swz(uar, uas * 16)) = a1;
        *(short8*)(sA0 + swz(ubr, ubs2 * 16)) = a2;
    }
    #pragma unroll
    for (int it = 0; it < 8; ++it) ((unsigned*)sSt)[tid + it * 512] = 0u;
    if (tid < 64) sdeg[tid] = degf[n0 + tid];
    float lossAcc = 0.f;
    __syncthreads();

    char* sXc = sX0; char* sXn = sX1;
    char* sAc = sA0; char* sAn = sA1;

    for (int t = 0; t < TT; ++t) {
        // ---- issue reg loads for t+1 (consumed after bar1) ----
        short8 rx1, rx2, ra1, ra2;
        const bool havenext = (t + 1 < TT);
        if (havenext) {
            const size_t slab = slab0 + (size_t)(t + 1) * NN * HH;
            rx1 = *(const short8*)(xb + slab + uar * HH + uas * 8);
            rx2 = *(const short8*)(xb + slab + ubr * HH + ubs2 * 8);
            ra1 = *(const short8*)(agg + slab + uar * HH + uas * 8);
            ra2 = *(const short8*)(agg + slab + ubr * HH + ubs2 * 8);
        }

        // ---- GEMV loss for t-1 (waves 0-3): out = state @ W_ro ----
        if (w < 4 && t > 0) {
            f32x4 acc = {};
            #pragma unroll
            for (int ks = 0; ks < 4; ++ks) {
                short8 af = *(const short8*)(sSt + swz(w * 16 + lo, ks * 64 + hi * 16));
                short8 bw = *(const short8*)(WroP + (size_t)(ks * 64 + l) * 8);
                acc = __builtin_amdgcn_mfma_f32_16x16x32_bf16(af, bw, acc, 0, 0, 0);
            }
            if (lo == 0) {
                #pragma unroll
                for (int q = 0; q < 4; ++q) {
                    int row = w * 16 + hi * 4 + q;
                    size_t ti = (size_t)(b * TT + (t - 1)) * NN + n0 + row;
                    float tgt = targets[ti];
                    float mv = fl ? (((const unsigned char*)maskp)[ti] ? 1.f : 0.f)
                                  : (((const int*)maskp)[ti] ? 1.f : 0.f);
                    float d = acc[q] + bro - tgt;
                    lossAcc += 0.5f * d * d * mv;
                }
            }
        }

        // ---- B: mi = agg@Wc + state@Wb + deg*bvec + b_mix ----
        f32x4 mAcc[4] = {};
        #pragma unroll
        for (int ks = 0; ks < 8; ++ks) {
            #pragma unroll
            for (int s4 = 0; s4 < 4; ++s4) {
                short8 af = (ks < 4)
                    ? *(const short8*)(sAc + swz(s4 * 16 + lo, ks * 64 + hi * 16))
                    : *(const short8*)(sSt + swz(s4 * 16 + lo, (ks - 4) * 64 + hi * 16));
                mAcc[s4] = __builtin_amdgcn_mfma_f32_16x16x32_bf16(af, wB[ks], mAcc[s4], 0, 0, 0);
            }
        }
        #pragma unroll
        for (int s4 = 0; s4 < 4; ++s4)
            #pragma unroll
            for (int q = 0; q < 4; ++q) {
                int row = s4 * 16 + hi * 4 + q;
                float v = mAcc[s4][q] + sdeg[row] * bv + bm;
                *(unsigned short*)(sMi + swz(row, jcol * 2)) = bf16r(v);
            }
        __syncthreads();   // bar1: sMi ready; sAc/sSt reads done

        // ---- stage-write t+1 into the spare buffers ----
        if (havenext) {
            *(short8*)(sXn + swz(uar, uas * 16)) = rx1;
            *(short8*)(sXn + swz(ubr, ubs2 * 16)) = rx2;
            *(short8*)(sAn + swz(uar, uas * 16)) = ra1;
            *(short8*)(sAn + swz(ubr, ubs2 * 16)) = ra2;
        }

        // ---- C: R/Z (K=256), N (K=128, A=mi), H (K=128, A=sXc) ----
        f32x4 aR[4] = {}, aZ[4] = {}, aN4[4] = {}, aH4[4] = {};
        #pragma unroll
        for (int ks = 0; ks < 8; ++ks) {
            short8 af[4];
            #pragma unroll
            for (int s4 = 0; s4 < 4; ++s4)
                af[s4] = (ks < 4)
                    ? *(const short8*)(sMi + swz(s4 * 16 + lo, ks * 64 + hi * 16))
                    : *(const short8*)(sXc + swz(s4 * 16 + lo, (ks - 4) * 64 + hi * 16));
            #pragma unroll
            for (int s4 = 0; s4 < 4; ++s4)
                aR[s4] = __builtin_amdgcn_mfma_f32_16x16x32_bf16(af[s4], wR[ks], aR[s4], 0, 0, 0);
            #pragma unroll
            for (int s4 = 0; s4 < 4; ++s4)
                aZ[s4] = __builtin_amdgcn_mfma_f32_16x16x32_bf16(af[s4], wZ[ks], aZ[s4], 0, 0, 0);
            if (ks < 4) {
                #pragma unroll
                for (int s4 = 0; s4 < 4; ++s4)
                    aN4[s4] = __builtin_amdgcn_mfma_f32_16x16x32_bf16(af[s4], wN[ks], aN4[s4], 0, 0, 0);
            } else {
                #pragma unroll
                for (int s4 = 0; s4 < 4; ++s4)
                    aH4[s4] = __builtin_amdgcn_mfma_f32_16x16x32_bf16(af[s4], wH[ks - 4], aH4[s4], 0, 0, 0);
            }
        }

        // ---- D: gates, state write (u16 direct) ----
        #pragma unroll
        for (int s4 = 0; s4 < 4; ++s4)
            #pragma unroll
            for (int q = 0; q < 4; ++q) {
                int row = s4 * 16 + hi * 4 + q;
                float rg = sigm(aR[s4][q] + br);
                float zg = sigm(aZ[s4][q] + bz);
                float ng = tanhfast(aN4[s4][q] + bi + rg * (aH4[s4][q] + bh));
                float xv = bf2f(*(const unsigned short*)(sXc + swz(row, jcol * 2)));
                float ns = (1.f - zg) * ng + zg * xv;
                *(unsigned short*)(sSt + swz(row, jcol * 2)) = bf16r(ns);
            }
        __syncthreads();   // bar2: sSt + staged t+1 published

        char* tp = sXc; sXc = sXn; sXn = tp;
        tp = sAc; sAc = sAn; sAn = tp;
    }

    // ---- epilogue GEMV for t=63 ----
    if (w < 4) {
        f32x4 acc = {};
        #pragma unroll
        for (int ks = 0; ks < 4; ++ks) {
            short8 af = *(const short8*)(sSt + swz(w * 16 + lo, ks * 64 + hi * 16));
            short8 bw = *(const short8*)(WroP + (size_t)(ks * 64 + l) * 8);
            acc = __builtin_amdgcn_mfma_f32_16x16x32_bf16(af, bw, acc, 0, 0, 0);
        }
        if (lo == 0) {
            #pragma unroll
            for (int q = 0; q < 4; ++q) {
                int row = w * 16 + hi * 4 + q;
                size_t ti = (size_t)(b * TT + 63) * NN + n0 + row;
                float tgt = targets[ti];
                float mv = fl ? (((const unsigned char*)maskp)[ti] ? 1.f : 0.f)
                              : (((const int*)maskp)[ti] ? 1.f : 0.f);
                float d = acc[q] + bro - tgt;
                lossAcc += 0.5f * d * d * mv;
            }
        }
    }

    // ---- block loss reduce ----
    float v = lossAcc;
    #pragma unroll
    for (int o = 1; o < 64; o <<= 1) v += __shfl_xor(v, o);
    if (l == 0) pLoss[w] = v;
    __syncthreads();
    if (tid == 0) {
        float s = 0.f;
        #pragma unroll
        for (int ww = 0; ww < 8; ++ww) s += pLoss[ww];
        lossBlock[phys] = s;
    }
}

// ================= CSR build =================
__global__ void count_kernel(const int* __restrict__ dst, int* __restrict__ counts)
{
    int e = blockIdx.x * 256 + threadIdx.x;
    if (e < EE) atomicAdd(&counts[dst[e]], 1);
}

__global__ __launch_bounds__(1024)
void scan_kernel(const int* __restrict__ counts, int* __restrict__ off, int* __restrict__ cursor,
                 float* __restrict__ degf)
{
    __shared__ int s[1024];
    int tid = threadIdx.x;
    int base = tid * 4;
    int c[4]; int sum = 0;
    #pragma unroll
    for (int i = 0; i < 4; ++i) { c[i] = counts[base + i]; sum += c[i]; }
    s[tid] = sum; __syncthreads();
    for (int o = 1; o < 1024; o <<= 1) {
        int v = (tid >= o) ? s[tid - o] : 0;
        __syncthreads();
        s[tid] += v;
        __syncthreads();
    }
    int incl = s[tid];
    int run = incl - sum;
    #pragma unroll
    for (int i = 0; i < 4; ++i) {
        off[base + i] = run; cursor[base + i] = run;
        degf[base + i] = (float)c[i];
        run += c[i];
    }
    if (tid == 1023) off[4096] = incl;
}

__global__ void fill_kernel(const int* __restrict__ src, const int* __restrict__ dst,
                            int* __restrict__ cursor, int* __restrict__ csr_src)
{
    int e = blockIdx.x * 256 + threadIdx.x;
    if (e < EE) {
        int d = dst[e];
        int pos = atomicAdd(&cursor[d], 1);
        csr_src[pos] = src[e];
    }
}

// ================= mask detect / masked count =================
__global__ void detect_kernel(const unsigned char* __restrict__ maskb, int* __restrict__ flag)
{
    int i = blockIdx.x * 256 + threadIdx.x;
    bool hit = (i < BB * TT * NN) && (i & 3) && maskb[i];
    if (__any(hit) && (threadIdx.x & 63) == 0) atomicOr(flag, 1);
}

__global__ void masksum_kernel(const void* __restrict__ maskp, const int* __restrict__ flag,
                               float* __restrict__ den)
{
    int i = blockIdx.x * 256 + threadIdx.x;
    float v = 0.f;
    if (i < BB * TT * NN) {
        if (*flag) v = ((const unsigned char*)maskp)[i] ? 1.f : 0.f;
        else       v = ((const int*)maskp)[i] ? 1.f : 0.f;
    }
    #pragma unroll
    for (int o = 32; o > 0; o >>= 1) v += __shfl_down(v, o);
    __shared__ float sm[4];
    if ((threadIdx.x & 63) == 0) sm[threadIdx.x >> 6] = v;
    __syncthreads();
    if (threadIdx.x == 0) atomicAdd(den, sm[0] + sm[1] + sm[2] + sm[3]);
}

// ================= final reduce + dual-dtype output =================
__global__ __launch_bounds__(256)
void final_kernel(const float* __restrict__ lossBlock, const float* __restrict__ den,
                  unsigned* __restrict__ out)
{
    __shared__ float s[256];
    s[threadIdx.x] = lossBlock[threadIdx.x];
    __syncthreads();
    for (int o = 128; o > 0; o >>= 1) {
        if (threadIdx.x < o) s[threadIdx.x] += s[threadIdx.x + o];
        __syncthreads();
    }
    if (threadIdx.x == 0) {
        float L = s[0] / den[0];
        unsigned u = __float_as_uint(L);
        u += 0x7fffu + ((u >> 16) & 1u);
        unsigned hi = u >> 16;
        out[0] = hi * 0x10001u;   // bf16-exact low half; ~bf16 value as f32
    }
}

extern "C" void kernel_launch(void* const* d_in, const int* in_sizes, int n_in,
                              void* d_out, int out_size, void* d_ws, size_t ws_size,
                              hipStream_t stream)
{
    const float* x       = (const float*)d_in[0];
    const float* targets = (const float*)d_in[1];
    const float* W_msg   = (const float*)d_in[2];
    const float* b_msg   = (const float*)d_in[3];
    const float* W_mix   = (const float*)d_in[4];
    const float* b_mix   = (const float*)d_in[5];
    const float* W_ih    = (const float*)d_in[6];
    const float* b_ih    = (const float*)d_in[7];
    const float* W_hh    = (const float*)d_in[8];
    const float* b_hh    = (const float*)d_in[9];
    const float* W_ro    = (const float*)d_in[10];
    const float* b_ro    = (const float*)d_in[11];
    const void*  maskp   = d_in[12];
    const int*   esrc    = (const int*)d_in[13];
    const int*   edst    = (const int*)d_in[14];

    char* ws = (char*)d_ws;
    unsigned short* xb  = (unsigned short*)ws; ws += (size_t)BB * TT * NN * HH * 2;  // 268 MB
    unsigned short* agg = (unsigned short*)ws; ws += (size_t)BB * TT * NN * HH * 2;  // 268 MB
    short* WcbP        = (short*)ws; ws += (size_t)4096 * 8 * 2;
    short* Wp4         = (short*)ws; ws += (size_t)32 * 8 * 64 * 8 * 2;
    short* WroP        = (short*)ws; ws += (size_t)256 * 8 * 2;
    float* biasRZ      = (float*)ws; ws += 256 * 4;
    float* bvec        = (float*)ws; ws += 128 * 4;
    float* degf        = (float*)ws; ws += 4096 * 4;
    float* lossBlock   = (float*)ws; ws += 256 * 4;
    int*   csr_off     = (int*)ws;   ws += 4104 * 4;
    int*   cursor      = (int*)ws;   ws += 4096 * 4;
    int*   counts      = (int*)ws;   ws += 4096 * 4;
    int*   csr_src     = (int*)ws;   ws += (size_t)EE * 4;
    int*   flag        = (int*)ws;   ws += 64;
    float* den         = (float*)ws; ws += 64;

    hipMemsetAsync(counts, 0, 4096 * 4, stream);
    hipMemsetAsync(flag, 0, 64, stream);
    hipMemsetAsync(den, 0, 4, stream);

    detect_kernel   <<<4096, 256, 0, stream>>>((const unsigned char*)maskp, flag);
    masksum_kernel  <<<4096, 256, 0, stream>>>(maskp, flag, den);
    count_kernel    <<<EE / 256, 256, 0, stream>>>(edst, counts);
    scan_kernel     <<<1, 1024, 0, stream>>>(counts, csr_off, cursor, degf);
    fill_kernel     <<<EE / 256, 256, 0, stream>>>(esrc, edst, cursor, csr_src);
    pack_wcb_kernel <<<16, 256, 0, stream>>>(W_msg, W_mix, WcbP);
    pack_ihh_kernel <<<64, 256, 0, stream>>>(W_ih, W_hh, Wp4);
    pack_wro_kernel <<<1, 256, 0, stream>>>(W_ro, WroP);
    pack_bias_kernel<<<1, 128, 0, stream>>>(b_ih, b_hh, b_msg, W_mix, biasRZ, bvec);

    cvt_all_kernel  <<<2048, 256, 0, stream>>>(x, xb, (long)BB * TT * NN * HH / 4);
    gather_xb_kernel<<<(BB * TT * NN) / 4, 256, 0, stream>>>(xb, csr_off, csr_src, agg);

    mega7_kernel<<<256, 512, 0, stream>>>(xb, agg, WcbP, Wp4, WroP, degf, bvec, b_mix, biasRZ,
                                          b_ih, b_hh, b_ro, targets, maskp, flag, lossBlock);
    final_kernel<<<1, 256, 0, stream>>>(lossBlock, den, (unsigned*)d_out);
}

// Round 12
// 1672.116 us; speedup vs baseline: 1.3212x; 1.2016x over previous
//
#include <hip/hip_runtime.h>
#include <hip/hip_bf16.h>
#include <stdint.h>

#define BB 4
#define TT 64
#define NN 4096
#define HH 128
#define EE 65536
#define BN (BB*NN)   // 16384

typedef __attribute__((ext_vector_type(8))) short short8;
typedef __attribute__((ext_vector_type(4))) float f32x4;

__device__ __forceinline__ unsigned short bf16r(float f) {
    unsigned u = __float_as_uint(f);
    u += 0x7fffu + ((u >> 16) & 1u);
    return (unsigned short)(u >> 16);
}
__device__ __forceinline__ float bf2f(unsigned bits16) {
    return __uint_as_float(bits16 << 16);
}
__device__ __forceinline__ float sigm(float x) { return 1.f / (1.f + __expf(-x)); }
__device__ __forceinline__ float tanhfast(float x) {
    return 1.f - 2.f / (__expf(2.f * x) + 1.f);
}
// byte address within a [64][128]-bf16 tile, XOR-swizzled
__device__ __forceinline__ unsigned swz(int row, int colbyte) {
    return (unsigned)(row * 256 + (colbyte ^ ((row & 7) << 4)));
}

// ================= packs =================
// WcbP: [half][nt(8)][ks(4)][lane(64)][8].  half0: Wc = W_msg@W_mix[0:128]; half1: W_mix[128:256]
__global__ void pack_wcb_kernel(const float* __restrict__ W_msg, const float* __restrict__ W_mix,
                                short* __restrict__ out)
{
    int idx = blockIdx.x * 256 + threadIdx.x;   // 4096
    if (idx >= 4096) return;
    int l = idx & 63, ks = (idx >> 6) & 3, nt = (idx >> 8) & 7, half = idx >> 11;
    int lo = l & 15, hi = l >> 4;
    int col = nt * 16 + lo;
    short8 v;
    #pragma unroll
    for (int i = 0; i < 8; ++i) {
        int k = ks * 32 + hi * 8 + i;
        float s;
        if (half == 0) {
            s = 0.f;
            for (int j = 0; j < 128; ++j) s += W_msg[k * 128 + j] * W_mix[j * 128 + col];
        } else {
            s = W_mix[(128 + k) * 128 + col];
        }
        v[i] = (short)bf16r(s);
    }
    *(short8*)(out + (size_t)idx * 8) = v;
}

__global__ void pack_ihh_kernel(const float* __restrict__ Wih, const float* __restrict__ Whh,
                                short* __restrict__ out)
{
    int idx = blockIdx.x * 256 + threadIdx.x;   // 16384
    if (idx >= 32 * 8 * 64) return;
    int l = idx & 63, ks = (idx >> 6) & 7, nt = idx >> 9;
    int lo = l & 15, hi = l >> 4;
    short8 v;
    #pragma unroll
    for (int i = 0; i < 8; ++i) {
        int k = ks * 32 + hi * 8 + i;
        float s = 0.f;
        if (nt < 16) {
            int col = nt * 16 + lo;
            s = (ks < 4) ? Wih[k * 384 + col] : Whh[(k - 128) * 384 + col];
        } else if (nt < 24) {
            int col = 256 + (nt - 16) * 16 + lo;
            s = (ks < 4) ? Wih[k * 384 + col] : 0.f;
        } else {
            int col = 256 + (nt - 24) * 16 + lo;
            s = (ks >= 4) ? Whh[(k - 128) * 384 + col] : 0.f;
        }
        v[i] = (short)bf16r(s);
    }
    *(short8*)(out + (size_t)idx * 8) = v;
}

// W_roP: [ks(4)][lane(64)][8]; only col 0 nonzero = W_ro[k]
__global__ void pack_wro_kernel(const float* __restrict__ W_ro, short* __restrict__ out)
{
    int idx = threadIdx.x;      // 256
    int l = idx & 63, ks = idx >> 6;
    int lo = l & 15, hi = l >> 4;
    short8 v;
    #pragma unroll
    for (int i = 0; i < 8; ++i) {
        int k = ks * 32 + hi * 8 + i;
        v[i] = (lo == 0) ? (short)bf16r(W_ro[k]) : (short)0;
    }
    *(short8*)(out + (size_t)idx * 8) = v;
}

__global__ void pack_bias_kernel(const float* __restrict__ b_ih, const float* __restrict__ b_hh,
                                 const float* __restrict__ b_msg, const float* __restrict__ W_mix,
                                 float* __restrict__ biasRZ, float* __restrict__ bvec)
{
    int j = threadIdx.x;
    biasRZ[j]       = b_ih[j]       + b_hh[j];
    biasRZ[128 + j] = b_ih[128 + j] + b_hh[128 + j];
    float s = 0.f;
    for (int jj = 0; jj < 128; ++jj) s += b_msg[jj] * W_mix[jj * 128 + j];
    bvec[j] = s;
}

// ===== fused gather + x-convert from f32 x (XCD slab affinity), write interleaved stream =====
// img[phys][t] = 32KB: [0,16K) = x tile (pre-swizzled bf16), [16K,32K) = agg tile
__global__ __launch_bounds__(256)
void gather_cvt_kernel(const float* __restrict__ x,
                       const int* __restrict__ off, const int* __restrict__ srcs,
                       char* __restrict__ img)
{
    int bid = blockIdx.x;               // 262144 blocks
    int xcd = bid & 7;
    int i = bid >> 3;                   // 0..32767
    int btl = i >> 10;                  // 0..31
    int chunk = i & 1023;               // 0..1023
    int bt = btl * 8 + xcd;             // all blocks of bt land on one XCD -> 2MB f32 slab L2-hot
    int dst = chunk * 4 + (threadIdx.x >> 6);
    int l = threadIdx.x & 63;
    const float* __restrict__ xr = x + (size_t)bt * NN * HH;
    int s = off[dst], e = off[dst + 1];
    float a0 = 0.f, a1 = 0.f;
    int ii = s;
    for (; ii + 7 < e; ii += 8) {
        float2 v0 = *(const float2*)(xr + (size_t)srcs[ii + 0] * HH + l * 2);
        float2 v1 = *(const float2*)(xr + (size_t)srcs[ii + 1] * HH + l * 2);
        float2 v2 = *(const float2*)(xr + (size_t)srcs[ii + 2] * HH + l * 2);
        float2 v3 = *(const float2*)(xr + (size_t)srcs[ii + 3] * HH + l * 2);
        float2 v4 = *(const float2*)(xr + (size_t)srcs[ii + 4] * HH + l * 2);
        float2 v5 = *(const float2*)(xr + (size_t)srcs[ii + 5] * HH + l * 2);
        float2 v6 = *(const float2*)(xr + (size_t)srcs[ii + 6] * HH + l * 2);
        float2 v7 = *(const float2*)(xr + (size_t)srcs[ii + 7] * HH + l * 2);
        a0 += ((v0.x + v1.x) + (v2.x + v3.x)) + ((v4.x + v5.x) + (v6.x + v7.x));
        a1 += ((v0.y + v1.y) + (v2.y + v3.y)) + ((v4.y + v5.y) + (v6.y + v7.y));
    }
    for (; ii < e; ++ii) {
        float2 v0 = *(const float2*)(xr + (size_t)srcs[ii] * HH + l * 2);
        a0 += v0.x; a1 += v0.y;
    }
    int b = bt >> 6, t = bt & 63;
    int phys = (b << 6) | (dst >> 6);
    int row = dst & 63;
    size_t base = ((size_t)phys * TT + t) * 32768;
    *(unsigned*)(img + base + 16384 + swz(row, l * 4)) =
        (unsigned)bf16r(a0) | ((unsigned)bf16r(a1) << 16);
    float2 xv = *(const float2*)(xr + (size_t)dst * HH + l * 2);
    *(unsigned*)(img + base + swz(row, l * 4)) =
        (unsigned)bf16r(xv.x) | ((unsigned)bf16r(xv.y) << 16);
}

// ================= persistent T-loop: mega2 core, contiguous staging, GEMV loss =================
__global__ __launch_bounds__(512, 2)
void mega8_kernel(const char* __restrict__ img,
                  const short* __restrict__ WcbP, const short* __restrict__ Wp4,
                  const short* __restrict__ WroP,
                  const float* __restrict__ degf,
                  const float* __restrict__ bvec, const float* __restrict__ b_mix,
                  const float* __restrict__ biasRZ,
                  const float* __restrict__ b_ih, const float* __restrict__ b_hh,
                  const float* __restrict__ b_ro,
                  const float* __restrict__ targets, const void* __restrict__ maskp,
                  const int* __restrict__ flag,
                  float* __restrict__ lossBlock)
{
    __shared__ char sX[16384];
    __shared__ char sA[16384];
    __shared__ char sMi[16384];
    __shared__ char sSt[16384];
    __shared__ float sdeg[64];
    __shared__ float pOut[2][64];
    __shared__ float pLoss[8];

    const int tid = threadIdx.x;
    const int w = tid >> 6, l = tid & 63, lo = l & 15, hi = l >> 4;
    const int nt = w;
    const int phys = blockIdx.x;
    const int b = phys >> 6;
    const int n0 = (phys & 63) * 64;
    const size_t tbase = (size_t)phys * TT * 32768;

    // ---- all B-fragments in registers, loaded once ----
    short8 wB[8], wR[8], wZ[8], wN[4], wH[4];
    #pragma unroll
    for (int ks = 0; ks < 8; ++ks) {
        wB[ks] = *(const short8*)(WcbP + (size_t)((((ks >> 2) * 8 + nt) * 4 + (ks & 3)) * 64 + l) * 8);
        wR[ks] = *(const short8*)(Wp4 + (size_t)((nt * 8 + ks) * 64 + l) * 8);
        wZ[ks] = *(const short8*)(Wp4 + (size_t)(((8 + nt) * 8 + ks) * 64 + l) * 8);
    }
    #pragma unroll
    for (int ks = 0; ks < 4; ++ks) {
        wN[ks] = *(const short8*)(Wp4 + (size_t)(((16 + nt) * 8 + ks) * 64 + l) * 8);
        wH[ks] = *(const short8*)(Wp4 + (size_t)(((24 + nt) * 8 + (ks + 4)) * 64 + l) * 8);
    }

    const int jcol = nt * 16 + lo;
    const float br = biasRZ[jcol], bz = biasRZ[128 + jcol];
    const float bi = b_ih[256 + jcol], bh = b_hh[256 + jcol];
    const float bv = bvec[jcol], bm = b_mix[jcol];
    const float bro = b_ro[0];
    const int fl = *flag;

    #pragma unroll
    for (int it = 0; it < 8; ++it) ((unsigned*)sSt)[tid + it * 512] = 0u;
    if (tid < 64) sdeg[tid] = degf[n0 + tid];
    float tgtCur = 0.f, mvCur = 0.f, lossAcc = 0.f;
    __syncthreads();

    for (int t = 0; t < TT; ++t) {
        // ---- targets/mask prefetch for t (consumed at end of step t+1) ----
        float tgtNext = 0.f, mvNext = 0.f;
        if (tid < 64) {
            size_t ti = (size_t)(b * TT + t) * NN + n0 + tid;
            tgtNext = targets[ti];
            mvNext = fl ? (((const unsigned char*)maskp)[ti] ? 1.f : 0.f)
                        : (((const int*)maskp)[ti] ? 1.f : 0.f);
        }

        // ---- sync stage: contiguous 32KB -> sX, sA (linear ds_write, pre-swizzled src) ----
        {
            const char* g = img + tbase + (size_t)t * 32768;
            #pragma unroll
            for (int k = 0; k < 4; ++k) {
                int u = tid + k * 512;
                short8 v = *(const short8*)(g + u * 16);
                if (k < 2) *(short8*)(sX + u * 16) = v;
                else       *(short8*)(sA + (u - 1024) * 16) = v;
            }
        }
        __syncthreads();   // bar1: tiles ready

        // ---- B: mi = agg@Wc + state@Wb + deg*bvec + b_mix ----
        f32x4 mAcc[4] = {};
        #pragma unroll
        for (int ks = 0; ks < 8; ++ks) {
            #pragma unroll
            for (int s4 = 0; s4 < 4; ++s4) {
                short8 af = (ks < 4)
                    ? *(const short8*)(sA + swz(s4 * 16 + lo, ks * 64 + hi * 16))
                    : *(const short8*)(sSt + swz(s4 * 16 + lo, (ks - 4) * 64 + hi * 16));
                mAcc[s4] = __builtin_amdgcn_mfma_f32_16x16x32_bf16(af, wB[ks], mAcc[s4], 0, 0, 0);
            }
        }
        #pragma unroll
        for (int s4 = 0; s4 < 4; ++s4)
            #pragma unroll
            for (int q = 0; q < 4; ++q) {
                int row = s4 * 16 + hi * 4 + q;
                float v = mAcc[s4][q] + sdeg[row] * bv + bm;
                *(unsigned short*)(sMi + swz(row, jcol * 2)) = bf16r(v);
            }
        __syncthreads();   // bar2: sMi ready

        // ---- C: R/Z (K=256), N (K=128, A=mi), H (K=128, A=sX) ----
        f32x4 aR[4] = {}, aZ[4] = {}, aN4[4] = {}, aH4[4] = {};
        #pragma unroll
        for (int ks = 0; ks < 8; ++ks) {
            short8 af[4];
            #pragma unroll
            for (int s4 = 0; s4 < 4; ++s4)
                af[s4] = (ks < 4)
                    ? *(const short8*)(sMi + swz(s4 * 16 + lo, ks * 64 + hi * 16))
                    : *(const short8*)(sX + swz(s4 * 16 + lo, (ks - 4) * 64 + hi * 16));
            #pragma unroll
            for (int s4 = 0; s4 < 4; ++s4)
                aR[s4] = __builtin_amdgcn_mfma_f32_16x16x32_bf16(af[s4], wR[ks], aR[s4], 0, 0, 0);
            #pragma unroll
            for (int s4 = 0; s4 < 4; ++s4)
                aZ[s4] = __builtin_amdgcn_mfma_f32_16x16x32_bf16(af[s4], wZ[ks], aZ[s4], 0, 0, 0);
            if (ks < 4) {
                #pragma unroll
                for (int s4 = 0; s4 < 4; ++s4)
                    aN4[s4] = __builtin_amdgcn_mfma_f32_16x16x32_bf16(af[s4], wN[ks], aN4[s4], 0, 0, 0);
            } else {
                #pragma unroll
                for (int s4 = 0; s4 < 4; ++s4)
                    aH4[s4] = __builtin_amdgcn_mfma_f32_16x16x32_bf16(af[s4], wH[ks - 4], aH4[s4], 0, 0, 0);
            }
        }

        // ---- D: gates, state write (u16 direct) ----
        #pragma unroll
        for (int s4 = 0; s4 < 4; ++s4)
            #pragma unroll
            for (int q = 0; q < 4; ++q) {
                int row = s4 * 16 + hi * 4 + q;
                float rg = sigm(aR[s4][q] + br);
                float zg = sigm(aZ[s4][q] + bz);
                float ng = tanhfast(aN4[s4][q] + bi + rg * (aH4[s4][q] + bh));
                float xv = bf2f(*(const unsigned short*)(sX + swz(row, jcol * 2)));
                float ns = (1.f - zg) * ng + zg * xv;
                *(unsigned short*)(sSt + swz(row, jcol * 2)) = bf16r(ns);
            }
        __syncthreads();   // bar3: sSt(t) published

        // ---- GEMV: out(t) = state(t)@W_ro -> pOut[t&1]; consume out(t-1) ----
        if (w < 4) {
            f32x4 acc = {};
            #pragma unroll
            for (int ks = 0; ks < 4; ++ks) {
                short8 af = *(const short8*)(sSt + swz(w * 16 + lo, ks * 64 + hi * 16));
                short8 bw = *(const short8*)(WroP + (size_t)(ks * 64 + l) * 8);
                acc = __builtin_amdgcn_mfma_f32_16x16x32_bf16(af, bw, acc, 0, 0, 0);
            }
            if (lo == 0) {
                #pragma unroll
                for (int q = 0; q < 4; ++q)
                    pOut[t & 1][w * 16 + hi * 4 + q] = acc[q];
            }
        }
        if (tid < 64 && t > 0) {
            float out = pOut[(t & 1) ^ 1][tid] + bro;
            float d = out - tgtCur;
            lossAcc += 0.5f * d * d * mvCur;
        }
        tgtCur = tgtNext; mvCur = mvNext;
    }

    __syncthreads();   // pOut[1] (t=63) visible to wave 0
    if (tid < 64) {
        float out = pOut[1][tid] + bro;
        float d = out - tgtCur;
        lossAcc += 0.5f * d * d * mvCur;
    }

    // ---- block loss reduce ----
    float v = lossAcc;
    #pragma unroll
    for (int o = 1; o < 64; o <<= 1) v += __shfl_xor(v, o);
    if (l == 0) pLoss[w] = v;
    __syncthreads();
    if (tid == 0) {
        float s = 0.f;
        #pragma unroll
        for (int ww = 0; ww < 8; ++ww) s += pLoss[ww];
        lossBlock[phys] = s;
    }
}

// ================= CSR build =================
__global__ void count_kernel(const int* __restrict__ dst, int* __restrict__ counts)
{
    int e = blockIdx.x * 256 + threadIdx.x;
    if (e < EE) atomicAdd(&counts[dst[e]], 1);
}

__global__ __launch_bounds__(1024)
void scan_kernel(const int* __restrict__ counts, int* __restrict__ off, int* __restrict__ cursor,
                 float* __restrict__ degf)
{
    __shared__ int s[1024];
    int tid = threadIdx.x;
    int base = tid * 4;
    int c[4]; int sum = 0;
    #pragma unroll
    for (int i = 0; i < 4; ++i) { c[i] = counts[base + i]; sum += c[i]; }
    s[tid] = sum; __syncthreads();
    for (int o = 1; o < 1024; o <<= 1) {
        int v = (tid >= o) ? s[tid - o] : 0;
        __syncthreads();
        s[tid] += v;
        __syncthreads();
    }
    int incl = s[tid];
    int run = incl - sum;
    #pragma unroll
    for (int i = 0; i < 4; ++i) {
        off[base + i] = run; cursor[base + i] = run;
        degf[base + i] = (float)c[i];
        run += c[i];
    }
    if (tid == 1023) off[4096] = incl;
}

__global__ void fill_kernel(const int* __restrict__ src, const int* __restrict__ dst,
                            int* __restrict__ cursor, int* __restrict__ csr_src)
{
    int e = blockIdx.x * 256 + threadIdx.x;
    if (e < EE) {
        int d = dst[e];
        int pos = atomicAdd(&cursor[d], 1);
        csr_src[pos] = src[e];
    }
}

// ================= mask detect / masked count =================
__global__ void detect_kernel(const unsigned char* __restrict__ maskb, int* __restrict__ flag)
{
    int i = blockIdx.x * 256 + threadIdx.x;
    bool hit = (i < BB * TT * NN) && (i & 3) && maskb[i];
    if (__any(hit) && (threadIdx.x & 63) == 0) atomicOr(flag, 1);
}

__global__ void masksum_kernel(const void* __restrict__ maskp, const int* __restrict__ flag,
                               float* __restrict__ den)
{
    int i = blockIdx.x * 256 + threadIdx.x;
    float v = 0.f;
    if (i < BB * TT * NN) {
        if (*flag) v = ((const unsigned char*)maskp)[i] ? 1.f : 0.f;
        else       v = ((const int*)maskp)[i] ? 1.f : 0.f;
    }
    #pragma unroll
    for (int o = 32; o > 0; o >>= 1) v += __shfl_down(v, o);
    __shared__ float sm[4];
    if ((threadIdx.x & 63) == 0) sm[threadIdx.x >> 6] = v;
    __syncthreads();
    if (threadIdx.x == 0) atomicAdd(den, sm[0] + sm[1] + sm[2] + sm[3]);
}

// ================= final reduce + dual-dtype output =================
__global__ __launch_bounds__(256)
void final_kernel(const float* __restrict__ lossBlock, const float* __restrict__ den,
                  unsigned* __restrict__ out)
{
    __shared__ float s[256];
    s[threadIdx.x] = lossBlock[threadIdx.x];
    __syncthreads();
    for (int o = 128; o > 0; o >>= 1) {
        if (threadIdx.x < o) s[threadIdx.x] += s[threadIdx.x + o];
        __syncthreads();
    }
    if (threadIdx.x == 0) {
        float L = s[0] / den[0];
        unsigned u = __float_as_uint(L);
        u += 0x7fffu + ((u >> 16) & 1u);
        unsigned hi = u >> 16;
        out[0] = hi * 0x10001u;   // bf16-exact low half; ~bf16 value as f32
    }
}

extern "C" void kernel_launch(void* const* d_in, const int* in_sizes, int n_in,
                              void* d_out, int out_size, void* d_ws, size_t ws_size,
                              hipStream_t stream)
{
    const float* x       = (const float*)d_in[0];
    const float* targets = (const float*)d_in[1];
    const float* W_msg   = (const float*)d_in[2];
    const float* b_msg   = (const float*)d_in[3];
    const float* W_mix   = (const float*)d_in[4];
    const float* b_mix   = (const float*)d_in[5];
    const float* W_ih    = (const float*)d_in[6];
    const float* b_ih    = (const float*)d_in[7];
    const float* W_hh    = (const float*)d_in[8];
    const float* b_hh    = (const float*)d_in[9];
    const float* W_ro    = (const float*)d_in[10];
    const float* b_ro    = (const float*)d_in[11];
    const void*  maskp   = d_in[12];
    const int*   esrc    = (const int*)d_in[13];
    const int*   edst    = (const int*)d_in[14];

    char* ws = (char*)d_ws;
    char* img = ws; ws += (size_t)256 * TT * 32768;   // 512 MB interleaved x/agg tile stream
    short* WcbP        = (short*)ws; ws += (size_t)4096 * 8 * 2;
    short* Wp4         = (short*)ws; ws += (size_t)32 * 8 * 64 * 8 * 2;
    short* WroP        = (short*)ws; ws += (size_t)256 * 8 * 2;
    float* biasRZ      = (float*)ws; ws += 256 * 4;
    float* bvec        = (float*)ws; ws += 128 * 4;
    float* degf        = (float*)ws; ws += 4096 * 4;
    float* lossBlock   = (float*)ws; ws += 256 * 4;
    int*   csr_off     = (int*)ws;   ws += 4104 * 4;
    int*   cursor      = (int*)ws;   ws += 4096 * 4;
    int*   counts      = (int*)ws;   ws += 4096 * 4;
    int*   csr_src     = (int*)ws;   ws += (size_t)EE * 4;
    int*   flag        = (int*)ws;   ws += 64;
    float* den         = (float*)ws; ws += 64;

    hipMemsetAsync(counts, 0, 4096 * 4, stream);
    hipMemsetAsync(flag, 0, 64, stream);
    hipMemsetAsync(den, 0, 4, stream);

    detect_kernel   <<<4096, 256, 0, stream>>>((const unsigned char*)maskp, flag);
    masksum_kernel  <<<4096, 256, 0, stream>>>(maskp, flag, den);
    count_kernel    <<<EE / 256, 256, 0, stream>>>(edst, counts);
    scan_kernel     <<<1, 1024, 0, stream>>>(counts, csr_off, cursor, degf);
    fill_kernel     <<<EE / 256, 256, 0, stream>>>(esrc, edst, cursor, csr_src);
    pack_wcb_kernel <<<16, 256, 0, stream>>>(W_msg, W_mix, WcbP);
    pack_ihh_kernel <<<64, 256, 0, stream>>>(W_ih, W_hh, Wp4);
    pack_wro_kernel <<<1, 256, 0, stream>>>(W_ro, WroP);
    pack_bias_kernel<<<1, 128, 0, stream>>>(b_ih, b_hh, b_msg, W_mix, biasRZ, bvec);

    gather_cvt_kernel<<<(BB * TT * NN) / 4, 256, 0, stream>>>(x, csr_off, csr_src, img);

    mega8_kernel<<<256, 512, 0, stream>>>(img, WcbP, Wp4, WroP, degf, bvec, b_mix, biasRZ,
                                          b_ih, b_hh, b_ro, targets, maskp, flag, lossBlock);
    final_kernel<<<1, 256, 0, stream>>>(lossBlock, den, (unsigned*)d_out);
}

// Round 13
// 1514.580 us; speedup vs baseline: 1.4586x; 1.1040x over previous
//
#include <hip/hip_runtime.h>
#include <hip/hip_bf16.h>
#include <stdint.h>

#define BB 4
#define TT 64
#define NN 4096
#define HH 128
#define EE 65536
#define BN (BB*NN)   // 16384

typedef __attribute__((ext_vector_type(8))) short short8;
typedef __attribute__((ext_vector_type(4))) float f32x4;

__device__ __forceinline__ unsigned short bf16r(float f) {
    unsigned u = __float_as_uint(f);
    u += 0x7fffu + ((u >> 16) & 1u);
    return (unsigned short)(u >> 16);
}
__device__ __forceinline__ float bf2f(unsigned bits16) {
    return __uint_as_float(bits16 << 16);
}
__device__ __forceinline__ float sigm(float x) { return 1.f / (1.f + __expf(-x)); }
__device__ __forceinline__ float tanhfast(float x) {
    return 1.f - 2.f / (__expf(2.f * x) + 1.f);
}
// byte address within a [64][128]-bf16 tile, XOR-swizzled (16B-block permutation)
__device__ __forceinline__ unsigned swz(int row, int colbyte) {
    return (unsigned)(row * 256 + (colbyte ^ ((row & 7) << 4)));
}

// ================= packs =================
// WcbP: [half][nt(8)][ks(4)][lane(64)][8].  half0: Wc = W_msg@W_mix[0:128]; half1: W_mix[128:256]
__global__ void pack_wcb_kernel(const float* __restrict__ W_msg, const float* __restrict__ W_mix,
                                short* __restrict__ out)
{
    int idx = blockIdx.x * 256 + threadIdx.x;   // 4096
    if (idx >= 4096) return;
    int l = idx & 63, ks = (idx >> 6) & 3, nt = (idx >> 8) & 7, half = idx >> 11;
    int lo = l & 15, hi = l >> 4;
    int col = nt * 16 + lo;
    short8 v;
    #pragma unroll
    for (int i = 0; i < 8; ++i) {
        int k = ks * 32 + hi * 8 + i;
        float s;
        if (half == 0) {
            s = 0.f;
            for (int j = 0; j < 128; ++j) s += W_msg[k * 128 + j] * W_mix[j * 128 + col];
        } else {
            s = W_mix[(128 + k) * 128 + col];
        }
        v[i] = (short)bf16r(s);
    }
    *(short8*)(out + (size_t)idx * 8) = v;
}

__global__ void pack_ihh_kernel(const float* __restrict__ Wih, const float* __restrict__ Whh,
                                short* __restrict__ out)
{
    int idx = blockIdx.x * 256 + threadIdx.x;   // 16384
    if (idx >= 32 * 8 * 64) return;
    int l = idx & 63, ks = (idx >> 6) & 7, nt = idx >> 9;
    int lo = l & 15, hi = l >> 4;
    short8 v;
    #pragma unroll
    for (int i = 0; i < 8; ++i) {
        int k = ks * 32 + hi * 8 + i;
        float s = 0.f;
        if (nt < 16) {
            int col = nt * 16 + lo;
            s = (ks < 4) ? Wih[k * 384 + col] : Whh[(k - 128) * 384 + col];
        } else if (nt < 24) {
            int col = 256 + (nt - 16) * 16 + lo;
            s = (ks < 4) ? Wih[k * 384 + col] : 0.f;
        } else {
            int col = 256 + (nt - 24) * 16 + lo;
            s = (ks >= 4) ? Whh[(k - 128) * 384 + col] : 0.f;
        }
        v[i] = (short)bf16r(s);
    }
    *(short8*)(out + (size_t)idx * 8) = v;
}

// W_roP: [ks(4)][lane(64)][8]; only col 0 nonzero = W_ro[k]
__global__ void pack_wro_kernel(const float* __restrict__ W_ro, short* __restrict__ out)
{
    int idx = threadIdx.x;      // 256
    int l = idx & 63, ks = idx >> 6;
    int lo = l & 15, hi = l >> 4;
    short8 v;
    #pragma unroll
    for (int i = 0; i < 8; ++i) {
        int k = ks * 32 + hi * 8 + i;
        v[i] = (lo == 0) ? (short)bf16r(W_ro[k]) : (short)0;
    }
    *(short8*)(out + (size_t)idx * 8) = v;
}

__global__ void pack_bias_kernel(const float* __restrict__ b_ih, const float* __restrict__ b_hh,
                                 const float* __restrict__ b_msg, const float* __restrict__ W_mix,
                                 float* __restrict__ biasRZ, float* __restrict__ bvec)
{
    int j = threadIdx.x;
    biasRZ[j]       = b_ih[j]       + b_hh[j];
    biasRZ[128 + j] = b_ih[128 + j] + b_hh[128 + j];
    float s = 0.f;
    for (int jj = 0; jj < 128; ++jj) s += b_msg[jj] * W_mix[jj * 128 + j];
    bvec[j] = s;
}

// ================= x -> pre-swizzled bf16 x-tiles inside img =================
// img tile layout: img[phys*64+t] = 32KB: [0,16K) x tile, [16K,32K) agg tile
__global__ __launch_bounds__(256)
void cvt_img_kernel(const float* __restrict__ x, char* __restrict__ img)
{
    int tileid = blockIdx.x;              // phys*64 + t  (16384)
    int phys = tileid >> 6, t = tileid & 63;
    int b = phys >> 6, n0 = (phys & 63) * 64;
    const float* __restrict__ src = x + ((size_t)(b * TT + t) * NN + n0) * HH;
    char* __restrict__ dst = img + (size_t)tileid * 32768;
    int tid = threadIdx.x;
    #pragma unroll
    for (int u4 = 0; u4 < 4; ++u4) {
        int unit = tid + u4 * 256;          // 1024 units of 16B
        int row = unit >> 4, g = unit & 15;
        const float* sp = src + row * HH + g * 8;
        float4 v0 = *(const float4*)sp;
        float4 v1 = *(const float4*)(sp + 4);
        short8 p;
        p[0] = (short)bf16r(v0.x); p[1] = (short)bf16r(v0.y);
        p[2] = (short)bf16r(v0.z); p[3] = (short)bf16r(v0.w);
        p[4] = (short)bf16r(v1.x); p[5] = (short)bf16r(v1.y);
        p[6] = (short)bf16r(v1.z); p[7] = (short)bf16r(v1.w);
        *(short8*)(dst + swz(row, g * 16)) = p;
    }
}

// ================= gather: half-wave edge pairing, bf16 source from img-x =================
// lanes 0-31 process even edges, 32-63 odd. Lane L handles cols 4L..4L+3 (8B).
__global__ __launch_bounds__(256)
void gather_pair_kernel(char* __restrict__ img,
                        const int* __restrict__ off, const int* __restrict__ srcs)
{
    int bid = blockIdx.x;               // 65536
    int xcd = bid & 7;
    int q = bid >> 3;                   // 0..8191
    int btl = q >> 8;                   // 0..31
    int chunk = q & 255;                // 0..255
    int bt = btl * 8 + xcd;             // all blocks of bt on one XCD -> 1MB img-x slab L2-hot
    int b = bt >> 6, t = bt & 63;
    int w = threadIdx.x >> 6, l = threadIdx.x & 63;
    int half = l >> 5, L = l & 31;
    const size_t base = ((size_t)b * 4096 + t) * 32768;   // + (n>>6)*2MB + row*256 + swz-col

    #pragma unroll
    for (int r = 0; r < 4; ++r) {
        int dst = chunk * 16 + w * 4 + r;
        int s = off[dst], e = off[dst + 1];
        float a0 = 0.f, a1 = 0.f, a2 = 0.f, a3 = 0.f;
        int i = s + half;
        for (; i + 6 < e; i += 8) {
            int s0 = srcs[i], s1 = srcs[i + 2], s2 = srcs[i + 4], s3 = srcs[i + 6];
            uint2 v0 = *(const uint2*)(img + base + ((size_t)(s0 >> 6) << 21)
                                       + ((s0 & 63) * 256) + ((L * 8) ^ ((s0 & 7) << 4)));
            uint2 v1 = *(const uint2*)(img + base + ((size_t)(s1 >> 6) << 21)
                                       + ((s1 & 63) * 256) + ((L * 8) ^ ((s1 & 7) << 4)));
            uint2 v2 = *(const uint2*)(img + base + ((size_t)(s2 >> 6) << 21)
                                       + ((s2 & 63) * 256) + ((L * 8) ^ ((s2 & 7) << 4)));
            uint2 v3 = *(const uint2*)(img + base + ((size_t)(s3 >> 6) << 21)
                                       + ((s3 & 63) * 256) + ((L * 8) ^ ((s3 & 7) << 4)));
            a0 += __uint_as_float(v0.x << 16) + __uint_as_float(v1.x << 16)
                + __uint_as_float(v2.x << 16) + __uint_as_float(v3.x << 16);
            a1 += __uint_as_float(v0.x & 0xffff0000u) + __uint_as_float(v1.x & 0xffff0000u)
                + __uint_as_float(v2.x & 0xffff0000u) + __uint_as_float(v3.x & 0xffff0000u);
            a2 += __uint_as_float(v0.y << 16) + __uint_as_float(v1.y << 16)
                + __uint_as_float(v2.y << 16) + __uint_as_float(v3.y << 16);
            a3 += __uint_as_float(v0.y & 0xffff0000u) + __uint_as_float(v1.y & 0xffff0000u)
                + __uint_as_float(v2.y & 0xffff0000u) + __uint_as_float(v3.y & 0xffff0000u);
        }
        for (; i < e; i += 2) {
            int s0 = srcs[i];
            uint2 v0 = *(const uint2*)(img + base + ((size_t)(s0 >> 6) << 21)
                                       + ((s0 & 63) * 256) + ((L * 8) ^ ((s0 & 7) << 4)));
            a0 += __uint_as_float(v0.x << 16);
            a1 += __uint_as_float(v0.x & 0xffff0000u);
            a2 += __uint_as_float(v0.y << 16);
            a3 += __uint_as_float(v0.y & 0xffff0000u);
        }
        // merge halves (even-edge sums + odd-edge sums)
        a0 += __shfl_xor(a0, 32);
        a1 += __shfl_xor(a1, 32);
        a2 += __shfl_xor(a2, 32);
        a3 += __shfl_xor(a3, 32);
        if (half == 0) {
            uint2 o;
            o.x = (unsigned)bf16r(a0) | ((unsigned)bf16r(a1) << 16);
            o.y = (unsigned)bf16r(a2) | ((unsigned)bf16r(a3) << 16);
            *(uint2*)(img + base + 16384 + ((size_t)(dst >> 6) << 21)
                      + ((dst & 63) * 256) + ((L * 8) ^ ((dst & 7) << 4))) = o;
        }
    }
}

// ================= persistent T-loop: mega2 core, contiguous staging, GEMV loss =================
__global__ __launch_bounds__(512, 2)
void mega8_kernel(const char* __restrict__ img,
                  const short* __restrict__ WcbP, const short* __restrict__ Wp4,
                  const short* __restrict__ WroP,
                  const float* __restrict__ degf,
                  const float* __restrict__ bvec, const float* __restrict__ b_mix,
                  const float* __restrict__ biasRZ,
                  const float* __restrict__ b_ih, const float* __restrict__ b_hh,
                  const float* __restrict__ b_ro,
                  const float* __restrict__ targets, const void* __restrict__ maskp,
                  const int* __restrict__ flag,
                  float* __restrict__ lossBlock)
{
    __shared__ char sX[16384];
    __shared__ char sA[16384];
    __shared__ char sMi[16384];
    __shared__ char sSt[16384];
    __shared__ float sdeg[64];
    __shared__ float pOut[2][64];
    __shared__ float pLoss[8];

    const int tid = threadIdx.x;
    const int w = tid >> 6, l = tid & 63, lo = l & 15, hi = l >> 4;
    const int nt = w;
    const int phys = blockIdx.x;
    const int b = phys >> 6;
    const int n0 = (phys & 63) * 64;
    const size_t tbase = (size_t)phys * TT * 32768;

    // ---- all B-fragments in registers, loaded once ----
    short8 wB[8], wR[8], wZ[8], wN[4], wH[4];
    #pragma unroll
    for (int ks = 0; ks < 8; ++ks) {
        wB[ks] = *(const short8*)(WcbP + (size_t)((((ks >> 2) * 8 + nt) * 4 + (ks & 3)) * 64 + l) * 8);
        wR[ks] = *(const short8*)(Wp4 + (size_t)((nt * 8 + ks) * 64 + l) * 8);
        wZ[ks] = *(const short8*)(Wp4 + (size_t)(((8 + nt) * 8 + ks) * 64 + l) * 8);
    }
    #pragma unroll
    for (int ks = 0; ks < 4; ++ks) {
        wN[ks] = *(const short8*)(Wp4 + (size_t)(((16 + nt) * 8 + ks) * 64 + l) * 8);
        wH[ks] = *(const short8*)(Wp4 + (size_t)(((24 + nt) * 8 + (ks + 4)) * 64 + l) * 8);
    }

    const int jcol = nt * 16 + lo;
    const float br = biasRZ[jcol], bz = biasRZ[128 + jcol];
    const float bi = b_ih[256 + jcol], bh = b_hh[256 + jcol];
    const float bv = bvec[jcol], bm = b_mix[jcol];
    const float bro = b_ro[0];
    const int fl = *flag;

    #pragma unroll
    for (int it = 0; it < 8; ++it) ((unsigned*)sSt)[tid + it * 512] = 0u;
    if (tid < 64) sdeg[tid] = degf[n0 + tid];
    float tgtCur = 0.f, mvCur = 0.f, lossAcc = 0.f;
    __syncthreads();

    for (int t = 0; t < TT; ++t) {
        // ---- targets/mask prefetch for t (consumed at end of step t+1) ----
        float tgtNext = 0.f, mvNext = 0.f;
        if (tid < 64) {
            size_t ti = (size_t)(b * TT + t) * NN + n0 + tid;
            tgtNext = targets[ti];
            mvNext = fl ? (((const unsigned char*)maskp)[ti] ? 1.f : 0.f)
                        : (((const int*)maskp)[ti] ? 1.f : 0.f);
        }

        // ---- sync stage: contiguous 32KB -> sX, sA (linear ds_write, pre-swizzled src) ----
        {
            const char* g = img + tbase + (size_t)t * 32768;
            #pragma unroll
            for (int k = 0; k < 4; ++k) {
                int u = tid + k * 512;
                short8 v = *(const short8*)(g + u * 16);
                if (k < 2) *(short8*)(sX + u * 16) = v;
                else       *(short8*)(sA + (u - 1024) * 16) = v;
            }
        }
        __syncthreads();   // bar1: tiles ready

        // ---- B: mi = agg@Wc + state@Wb + deg*bvec + b_mix ----
        f32x4 mAcc[4] = {};
        #pragma unroll
        for (int ks = 0; ks < 8; ++ks) {
            #pragma unroll
            for (int s4 = 0; s4 < 4; ++s4) {
                short8 af = (ks < 4)
                    ? *(const short8*)(sA + swz(s4 * 16 + lo, ks * 64 + hi * 16))
                    : *(const short8*)(sSt + swz(s4 * 16 + lo, (ks - 4) * 64 + hi * 16));
                mAcc[s4] = __builtin_amdgcn_mfma_f32_16x16x32_bf16(af, wB[ks], mAcc[s4], 0, 0, 0);
            }
        }
        #pragma unroll
        for (int s4 = 0; s4 < 4; ++s4)
            #pragma unroll
            for (int q = 0; q < 4; ++q) {
                int row = s4 * 16 + hi * 4 + q;
                float v = mAcc[s4][q] + sdeg[row] * bv + bm;
                *(unsigned short*)(sMi + swz(row, jcol * 2)) = bf16r(v);
            }
        __syncthreads();   // bar2: sMi ready

        // ---- C: R/Z (K=256), N (K=128, A=mi), H (K=128, A=sX) ----
        f32x4 aR[4] = {}, aZ[4] = {}, aN4[4] = {}, aH4[4] = {};
        #pragma unroll
        for (int ks = 0; ks < 8; ++ks) {
            short8 af[4];
            #pragma unroll
            for (int s4 = 0; s4 < 4; ++s4)
                af[s4] = (ks < 4)
                    ? *(const short8*)(sMi + swz(s4 * 16 + lo, ks * 64 + hi * 16))
                    : *(const short8*)(sX + swz(s4 * 16 + lo, (ks - 4) * 64 + hi * 16));
            #pragma unroll
            for (int s4 = 0; s4 < 4; ++s4)
                aR[s4] = __builtin_amdgcn_mfma_f32_16x16x32_bf16(af[s4], wR[ks], aR[s4], 0, 0, 0);
            #pragma unroll
            for (int s4 = 0; s4 < 4; ++s4)
                aZ[s4] = __builtin_amdgcn_mfma_f32_16x16x32_bf16(af[s4], wZ[ks], aZ[s4], 0, 0, 0);
            if (ks < 4) {
                #pragma unroll
                for (int s4 = 0; s4 < 4; ++s4)
                    aN4[s4] = __builtin_amdgcn_mfma_f32_16x16x32_bf16(af[s4], wN[ks], aN4[s4], 0, 0, 0);
            } else {
                #pragma unroll
                for (int s4 = 0; s4 < 4; ++s4)
                    aH4[s4] = __builtin_amdgcn_mfma_f32_16x16x32_bf16(af[s4], wH[ks - 4], aH4[s4], 0, 0, 0);
            }
        }

        // ---- D: gates, state write (u16 direct) ----
        #pragma unroll
        for (int s4 = 0; s4 < 4; ++s4)
            #pragma unroll
            for (int q = 0; q < 4; ++q) {
                int row = s4 * 16 + hi * 4 + q;
                float rg = sigm(aR[s4][q] + br);
                float zg = sigm(aZ[s4][q] + bz);
                float ng = tanhfast(aN4[s4][q] + bi + rg * (aH4[s4][q] + bh));
                float xv = bf2f(*(const unsigned short*)(sX + swz(row, jcol * 2)));
                float ns = (1.f - zg) * ng + zg * xv;
                *(unsigned short*)(sSt + swz(row, jcol * 2)) = bf16r(ns);
            }
        __syncthreads();   // bar3: sSt(t) published

        // ---- GEMV: out(t) = state(t)@W_ro -> pOut[t&1]; consume out(t-1) ----
        if (w < 4) {
            f32x4 acc = {};
            #pragma unroll
            for (int ks = 0; ks < 4; ++ks) {
                short8 af = *(const short8*)(sSt + swz(w * 16 + lo, ks * 64 + hi * 16));
                short8 bw = *(const short8*)(WroP + (size_t)(ks * 64 + l) * 8);
                acc = __builtin_amdgcn_mfma_f32_16x16x32_bf16(af, bw, acc, 0, 0, 0);
            }
            if (lo == 0) {
                #pragma unroll
                for (int q = 0; q < 4; ++q)
                    pOut[t & 1][w * 16 + hi * 4 + q] = acc[q];
            }
        }
        if (tid < 64 && t > 0) {
            float out = pOut[(t & 1) ^ 1][tid] + bro;
            float d = out - tgtCur;
            lossAcc += 0.5f * d * d * mvCur;
        }
        tgtCur = tgtNext; mvCur = mvNext;
    }

    __syncthreads();   // pOut[1] (t=63) visible to wave 0
    if (tid < 64) {
        float out = pOut[1][tid] + bro;
        float d = out - tgtCur;
        lossAcc += 0.5f * d * d * mvCur;
    }

    // ---- block loss reduce ----
    float v = lossAcc;
    #pragma unroll
    for (int o = 1; o < 64; o <<= 1) v += __shfl_xor(v, o);
    if (l == 0) pLoss[w] = v;
    __syncthreads();
    if (tid == 0) {
        float s = 0.f;
        #pragma unroll
        for (int ww = 0; ww < 8; ++ww) s += pLoss[ww];
        lossBlock[phys] = s;
    }
}

// ================= CSR build =================
__global__ void count_kernel(const int* __restrict__ dst, int* __restrict__ counts)
{
    int e = blockIdx.x * 256 + threadIdx.x;
    if (e < EE) atomicAdd(&counts[dst[e]], 1);
}

__global__ __launch_bounds__(1024)
void scan_kernel(const int* __restrict__ counts, int* __restrict__ off, int* __restrict__ cursor,
                 float* __restrict__ degf)
{
    __shared__ int s[1024];
    int tid = threadIdx.x;
    int base = tid * 4;
    int c[4]; int sum = 0;
    #pragma unroll
    for (int i = 0; i < 4; ++i) { c[i] = counts[base + i]; sum += c[i]; }
    s[tid] = sum; __syncthreads();
    for (int o = 1; o < 1024; o <<= 1) {
        int v = (tid >= o) ? s[tid - o] : 0;
        __syncthreads();
        s[tid] += v;
        __syncthreads();
    }
    int incl = s[tid];
    int run = incl - sum;
    #pragma unroll
    for (int i = 0; i < 4; ++i) {
        off[base + i] = run; cursor[base + i] = run;
        degf[base + i] = (float)c[i];
        run += c[i];
    }
    if (tid == 1023) off[4096] = incl;
}

__global__ void fill_kernel(const int* __restrict__ src, const int* __restrict__ dst,
                            int* __restrict__ cursor, int* __restrict__ csr_src)
{
    int e = blockIdx.x * 256 + threadIdx.x;
    if (e < EE) {
        int d = dst[e];
        int pos = atomicAdd(&cursor[d], 1);
        csr_src[pos] = src[e];
    }
}

// ================= mask detect / masked count =================
__global__ void detect_kernel(const unsigned char* __restrict__ maskb, int* __restrict__ flag)
{
    int i = blockIdx.x * 256 + threadIdx.x;
    bool hit = (i < BB * TT * NN) && (i & 3) && maskb[i];
    if (__any(hit) && (threadIdx.x & 63) == 0) atomicOr(flag, 1);
}

__global__ void masksum_kernel(const void* __restrict__ maskp, const int* __restrict__ flag,
                               float* __restrict__ den)
{
    int i = blockIdx.x * 256 + threadIdx.x;
    float v = 0.f;
    if (i < BB * TT * NN) {
        if (*flag) v = ((const unsigned char*)maskp)[i] ? 1.f : 0.f;
        else       v = ((const int*)maskp)[i] ? 1.f : 0.f;
    }
    #pragma unroll
    for (int o = 32; o > 0; o >>= 1) v += __shfl_down(v, o);
    __shared__ float sm[4];
    if ((threadIdx.x & 63) == 0) sm[threadIdx.x >> 6] = v;
    __syncthreads();
    if (threadIdx.x == 0) atomicAdd(den, sm[0] + sm[1] + sm[2] + sm[3]);
}

// ================= final reduce + dual-dtype output =================
__global__ __launch_bounds__(256)
void final_kernel(const float* __restrict__ lossBlock, const float* __restrict__ den,
                  unsigned* __restrict__ out)
{
    __shared__ float s[256];
    s[threadIdx.x] = lossBlock[threadIdx.x];
    __syncthreads();
    for (int o = 128; o > 0; o >>= 1) {
        if (threadIdx.x < o) s[threadIdx.x] += s[threadIdx.x + o];
        __syncthreads();
    }
    if (threadIdx.x == 0) {
        float L = s[0] / den[0];
        unsigned u = __float_as_uint(L);
        u += 0x7fffu + ((u >> 16) & 1u);
        unsigned hi = u >> 16;
        out[0] = hi * 0x10001u;   // bf16-exact low half; ~bf16 value as f32
    }
}

extern "C" void kernel_launch(void* const* d_in, const int* in_sizes, int n_in,
                              void* d_out, int out_size, void* d_ws, size_t ws_size,
                              hipStream_t stream)
{
    const float* x       = (const float*)d_in[0];
    const float* targets = (const float*)d_in[1];
    const float* W_msg   = (const float*)d_in[2];
    const float* b_msg   = (const float*)d_in[3];
    const float* W_mix   = (const float*)d_in[4];
    const float* b_mix   = (const float*)d_in[5];
    const float* W_ih    = (const float*)d_in[6];
    const float* b_ih    = (const float*)d_in[7];
    const float* W_hh    = (const float*)d_in[8];
    const float* b_hh    = (const float*)d_in[9];
    const float* W_ro    = (const float*)d_in[10];
    const float* b_ro    = (const float*)d_in[11];
    const void*  maskp   = d_in[12];
    const int*   esrc    = (const int*)d_in[13];
    const int*   edst    = (const int*)d_in[14];

    char* ws = (char*)d_ws;
    char* img = ws; ws += (size_t)256 * TT * 32768;   // 512 MB interleaved x/agg tile stream
    short* WcbP        = (short*)ws; ws += (size_t)4096 * 8 * 2;
    short* Wp4         = (short*)ws; ws += (size_t)32 * 8 * 64 * 8 * 2;
    short* WroP        = (short*)ws; ws += (size_t)256 * 8 * 2;
    float* biasRZ      = (float*)ws; ws += 256 * 4;
    float* bvec        = (float*)ws; ws += 128 * 4;
    float* degf        = (float*)ws; ws += 4096 * 4;
    float* lossBlock   = (float*)ws; ws += 256 * 4;
    int*   csr_off     = (int*)ws;   ws += 4104 * 4;
    int*   cursor      = (int*)ws;   ws += 4096 * 4;
    int*   counts      = (int*)ws;   ws += 4096 * 4;
    int*   csr_src     = (int*)ws;   ws += (size_t)EE * 4;
    int*   flag        = (int*)ws;   ws += 64;
    float* den         = (float*)ws; ws += 64;

    hipMemsetAsync(counts, 0, 4096 * 4, stream);
    hipMemsetAsync(flag, 0, 64, stream);
    hipMemsetAsync(den, 0, 4, stream);

    detect_kernel   <<<4096, 256, 0, stream>>>((const unsigned char*)maskp, flag);
    masksum_kernel  <<<4096, 256, 0, stream>>>(maskp, flag, den);
    count_kernel    <<<EE / 256, 256, 0, stream>>>(edst, counts);
    scan_kernel     <<<1, 1024, 0, stream>>>(counts, csr_off, cursor, degf);
    fill_kernel     <<<EE / 256, 256, 0, stream>>>(esrc, edst, cursor, csr_src);
    pack_wcb_kernel <<<16, 256, 0, stream>>>(W_msg, W_mix, WcbP);
    pack_ihh_kernel <<<64, 256, 0, stream>>>(W_ih, W_hh, Wp4);
    pack_wro_kernel <<<1, 256, 0, stream>>>(W_ro, WroP);
    pack_bias_kernel<<<1, 128, 0, stream>>>(b_ih, b_hh, b_msg, W_mix, biasRZ, bvec);

    cvt_img_kernel  <<<16384, 256, 0, stream>>>(x, img);
    gather_pair_kernel<<<65536, 256, 0, stream>>>(img, csr_off, csr_src);

    mega8_kernel<<<256, 512, 0, stream>>>(img, WcbP, Wp4, WroP, degf, bvec, b_mix, biasRZ,
                                          b_ih, b_hh, b_ro, targets, maskp, flag, lossBlock);
    final_kernel<<<1, 256, 0, stream>>>(lossBlock, den, (unsigned*)d_out);
}

// Round 14
// 1444.343 us; speedup vs baseline: 1.5295x; 1.0486x over previous
//
#include <hip/hip_runtime.h>
#include <hip/hip_bf16.h>
#include <stdint.h>

#define BB 4
#define TT 64
#define NN 4096
#define HH 128
#define EE 65536
#define BN (BB*NN)   // 16384

typedef __attribute__((ext_vector_type(8))) short short8;
typedef __attribute__((ext_vector_type(4))) float f32x4;

__device__ __forceinline__ unsigned short bf16r(float f) {
    unsigned u = __float_as_uint(f);
    u += 0x7fffu + ((u >> 16) & 1u);
    return (unsigned short)(u >> 16);
}
__device__ __forceinline__ unsigned cvt_pk_bf16(float lo_, float hi_) {
    unsigned r;
    asm("v_cvt_pk_bf16_f32 %0, %1, %2" : "=v"(r) : "v"(lo_), "v"(hi_));
    return r;
}
__device__ __forceinline__ unsigned short bf16s(float f) {
    unsigned r;
    asm("v_cvt_pk_bf16_f32 %0, %1, %1" : "=v"(r) : "v"(f));
    return (unsigned short)r;
}
__device__ __forceinline__ float bf2f(unsigned bits16) {
    return __uint_as_float(bits16 << 16);
}
__device__ __forceinline__ float sigm(float x) { return 1.f / (1.f + __expf(-x)); }
__device__ __forceinline__ float tanhfast(float x) {
    return 1.f - 2.f / (__expf(2.f * x) + 1.f);
}
// byte address within a [64][128]-bf16 tile, XOR-swizzled (16B-block permutation)
__device__ __forceinline__ unsigned swz(int row, int colbyte) {
    return (unsigned)(row * 256 + (colbyte ^ ((row & 7) << 4)));
}

// ================= packs =================
// Wc_f32 = W_msg @ W_mix[0:128]  (fp32, pack-time)
__global__ void pack_wc_kernel(const float* __restrict__ W_msg, const float* __restrict__ W_mix,
                               float* __restrict__ Wc)
{
    int idx = blockIdx.x * 256 + threadIdx.x;   // 16384
    int k = idx >> 7, j = idx & 127;
    float s = 0.f;
    for (int i = 0; i < 128; ++i) s += W_msg[k * 128 + i] * W_mix[i * 128 + j];
    Wc[idx] = s;
}

__global__ void pack_bvec_kernel(const float* __restrict__ b_msg, const float* __restrict__ W_mix,
                                 float* __restrict__ bvec)
{
    int j = threadIdx.x;   // 128
    float s = 0.f;
    for (int i = 0; i < 128; ++i) s += b_msg[i] * W_mix[i * 128 + j];
    bvec[j] = s;
}

// gvec[c] = bvec @ W_ih ; cvec[c] = b_mix@W_ih + b_ih + (c<256 ? b_hh[c] : 0)
__global__ void pack_gbias_kernel(const float* __restrict__ bvec, const float* __restrict__ b_mix,
                                  const float* __restrict__ W_ih, const float* __restrict__ b_ih,
                                  const float* __restrict__ b_hh,
                                  float* __restrict__ gvec, float* __restrict__ cvec)
{
    int c = threadIdx.x;   // 384
    float g = 0.f, gb = 0.f;
    for (int j = 0; j < 128; ++j) {
        g  += bvec[j]  * W_ih[j * 384 + c];
        gb += b_mix[j] * W_ih[j * 384 + c];
    }
    gvec[c] = g;
    cvec[c] = gb + b_ih[c] + (c < 256 ? b_hh[c] : 0.f);
}

// Gp[mat(9)][nt(8)][ks(4)][lane(64)][8]: mats 0-2 = G1 r/z/n (Wc@W_ih cols),
// 3-5 = G2 r/z/n (W_mix_bot@W_ih), 6-8 = W_hh r/z/n-slice.
__global__ void pack_G_kernel(const float* __restrict__ Wc, const float* __restrict__ W_mix,
                              const float* __restrict__ W_ih, const float* __restrict__ W_hh,
                              short* __restrict__ Gp)
{
    int idx = blockIdx.x * 256 + threadIdx.x;   // 9*8*4*64 = 18432
    if (idx >= 18432) return;
    int l = idx & 63, ks = (idx >> 6) & 3, nt = (idx >> 8) & 7, mat = idx >> 11;
    int lo = l & 15, hi = l >> 4;
    int col = nt * 16 + lo;
    short8 v;
    #pragma unroll
    for (int i = 0; i < 8; ++i) {
        int k = ks * 32 + hi * 8 + i;
        float s;
        if (mat < 3) {
            int c = mat * 128 + col;
            s = 0.f;
            for (int j = 0; j < 128; ++j) s += Wc[k * 128 + j] * W_ih[j * 384 + c];
        } else if (mat < 6) {
            int c = (mat - 3) * 128 + col;
            s = 0.f;
            for (int j = 0; j < 128; ++j) s += W_mix[(128 + k) * 128 + j] * W_ih[j * 384 + c];
        } else {
            int c = (mat - 6) * 128 + col;
            s = W_hh[k * 384 + c];
        }
        v[i] = (short)bf16r(s);
    }
    *(short8*)(Gp + (size_t)idx * 8) = v;
}

// W_roP: [ks(4)][lane(64)][8]; only col 0 nonzero = W_ro[k]
__global__ void pack_wro_kernel(const float* __restrict__ W_ro, short* __restrict__ out)
{
    int idx = threadIdx.x;      // 256
    int l = idx & 63, ks = idx >> 6;
    int lo = l & 15, hi = l >> 4;
    short8 v;
    #pragma unroll
    for (int i = 0; i < 8; ++i) {
        int k = ks * 32 + hi * 8 + i;
        v[i] = (lo == 0) ? (short)bf16r(W_ro[k]) : (short)0;
    }
    *(short8*)(out + (size_t)idx * 8) = v;
}

// ================= x -> pre-swizzled bf16 x-tiles inside img =================
// img tile layout: img[phys*64+t] = 32KB: [0,16K) x tile, [16K,32K) agg tile
__global__ __launch_bounds__(256)
void cvt_img_kernel(const float* __restrict__ x, char* __restrict__ img)
{
    int tileid = blockIdx.x;              // phys*64 + t  (16384)
    int phys = tileid >> 6, t = tileid & 63;
    int b = phys >> 6, n0 = (phys & 63) * 64;
    const float* __restrict__ src = x + ((size_t)(b * TT + t) * NN + n0) * HH;
    char* __restrict__ dst = img + (size_t)tileid * 32768;
    int tid = threadIdx.x;
    #pragma unroll
    for (int u4 = 0; u4 < 4; ++u4) {
        int unit = tid + u4 * 256;          // 1024 units of 16B
        int row = unit >> 4, g = unit & 15;
        const float* sp = src + row * HH + g * 8;
        float4 v0 = *(const float4*)sp;
        float4 v1 = *(const float4*)(sp + 4);
        uint4 o;
        o.x = cvt_pk_bf16(v0.x, v0.y);
        o.y = cvt_pk_bf16(v0.z, v0.w);
        o.z = cvt_pk_bf16(v1.x, v1.y);
        o.w = cvt_pk_bf16(v1.z, v1.w);
        *(uint4*)(dst + swz(row, g * 16)) = o;
    }
}

// ================= gather: half-wave edge pairing, bf16 source from img-x =================
__global__ __launch_bounds__(256)
void gather_pair_kernel(char* __restrict__ img,
                        const int* __restrict__ off, const int* __restrict__ srcs)
{
    int bid = blockIdx.x;               // 65536
    int xcd = bid & 7;
    int q = bid >> 3;                   // 0..8191
    int btl = q >> 8;                   // 0..31
    int chunk = q & 255;                // 0..255
    int bt = btl * 8 + xcd;             // all blocks of bt on one XCD -> 1MB img-x slab L2-hot
    int b = bt >> 6, t = bt & 63;
    int w = threadIdx.x >> 6, l = threadIdx.x & 63;
    int half = l >> 5, L = l & 31;
    const size_t base = ((size_t)b * 4096 + t) * 32768;

    #pragma unroll
    for (int r = 0; r < 4; ++r) {
        int dst = chunk * 16 + w * 4 + r;
        int s = off[dst], e = off[dst + 1];
        float a0 = 0.f, a1 = 0.f, a2 = 0.f, a3 = 0.f;
        int i = s + half;
        for (; i + 6 < e; i += 8) {
            int s0 = srcs[i], s1 = srcs[i + 2], s2 = srcs[i + 4], s3 = srcs[i + 6];
            uint2 v0 = *(const uint2*)(img + base + ((size_t)(s0 >> 6) << 21)
                                       + ((s0 & 63) * 256) + ((L * 8) ^ ((s0 & 7) << 4)));
            uint2 v1 = *(const uint2*)(img + base + ((size_t)(s1 >> 6) << 21)
                                       + ((s1 & 63) * 256) + ((L * 8) ^ ((s1 & 7) << 4)));
            uint2 v2 = *(const uint2*)(img + base + ((size_t)(s2 >> 6) << 21)
                                       + ((s2 & 63) * 256) + ((L * 8) ^ ((s2 & 7) << 4)));
            uint2 v3 = *(const uint2*)(img + base + ((size_t)(s3 >> 6) << 21)
                                       + ((s3 & 63) * 256) + ((L * 8) ^ ((s3 & 7) << 4)));
            a0 += __uint_as_float(v0.x << 16) + __uint_as_float(v1.x << 16)
                + __uint_as_float(v2.x << 16) + __uint_as_float(v3.x << 16);
            a1 += __uint_as_float(v0.x & 0xffff0000u) + __uint_as_float(v1.x & 0xffff0000u)
                + __uint_as_float(v2.x & 0xffff0000u) + __uint_as_float(v3.x & 0xffff0000u);
            a2 += __uint_as_float(v0.y << 16) + __uint_as_float(v1.y << 16)
                + __uint_as_float(v2.y << 16) + __uint_as_float(v3.y << 16);
            a3 += __uint_as_float(v0.y & 0xffff0000u) + __uint_as_float(v1.y & 0xffff0000u)
                + __uint_as_float(v2.y & 0xffff0000u) + __uint_as_float(v3.y & 0xffff0000u);
        }
        for (; i < e; i += 2) {
            int s0 = srcs[i];
            uint2 v0 = *(const uint2*)(img + base + ((size_t)(s0 >> 6) << 21)
                                       + ((s0 & 63) * 256) + ((L * 8) ^ ((s0 & 7) << 4)));
            a0 += __uint_as_float(v0.x << 16);
            a1 += __uint_as_float(v0.x & 0xffff0000u);
            a2 += __uint_as_float(v0.y << 16);
            a3 += __uint_as_float(v0.y & 0xffff0000u);
        }
        a0 += __shfl_xor(a0, 32);
        a1 += __shfl_xor(a1, 32);
        a2 += __shfl_xor(a2, 32);
        a3 += __shfl_xor(a3, 32);
        if (half == 0) {
            uint2 o;
            o.x = cvt_pk_bf16(a0, a1);
            o.y = cvt_pk_bf16(a2, a3);
            *(uint2*)(img + base + 16384 + ((size_t)(dst >> 6) << 21)
                      + ((dst & 63) * 256) + ((L * 8) ^ ((dst & 7) << 4))) = o;
        }
    }
}

// ================= persistent T-loop: single fused GEMM phase (W_mix folded away) =================
#define STEP9(T, SSC, SSN) { \
    const int t = (T); \
    float tgtNext = 0.f, mvNext = 0.f; \
    if (tid < 64) { \
        size_t ti = (size_t)(b * TT + t) * NN + n0 + tid; \
        tgtNext = targets[ti]; \
        mvNext = fl ? (((const unsigned char*)maskp)[ti] ? 1.f : 0.f) \
                    : (((const int*)maskp)[ti] ? 1.f : 0.f); \
    } \
    { \
        const char* g = img + tbase + (size_t)t * 32768; \
        _Pragma("unroll") \
        for (int k = 0; k < 4; ++k) { \
            int u = tid + k * 512; \
            short8 v = *(const short8*)(g + u * 16); \
            if (k < 2) *(short8*)(sX + u * 16) = v; \
            else       *(short8*)(sA + (u - 1024) * 16) = v; \
        } \
    } \
    __syncthreads();   /* bar1: tiles ready, prev sSt reads done */ \
    f32x4 R[4] = {}, Z[4] = {}, N4[4] = {}, H4[4] = {}; \
    _Pragma("unroll") \
    for (int ks = 0; ks < 4; ++ks) { \
        short8 af[4]; \
        _Pragma("unroll") \
        for (int s4 = 0; s4 < 4; ++s4) \
            af[s4] = *(const short8*)(sA + swz(s4 * 16 + lo, ks * 64 + hi * 16)); \
        _Pragma("unroll") \
        for (int s4 = 0; s4 < 4; ++s4) \
            R[s4] = __builtin_amdgcn_mfma_f32_16x16x32_bf16(af[s4], wf[0][ks], R[s4], 0, 0, 0); \
        _Pragma("unroll") \
        for (int s4 = 0; s4 < 4; ++s4) \
            Z[s4] = __builtin_amdgcn_mfma_f32_16x16x32_bf16(af[s4], wf[1][ks], Z[s4], 0, 0, 0); \
        _Pragma("unroll") \
        for (int s4 = 0; s4 < 4; ++s4) \
            N4[s4] = __builtin_amdgcn_mfma_f32_16x16x32_bf16(af[s4], wf[2][ks], N4[s4], 0, 0, 0); \
    } \
    _Pragma("unroll") \
    for (int ks = 0; ks < 4; ++ks) { \
        short8 af[4]; \
        _Pragma("unroll") \
        for (int s4 = 0; s4 < 4; ++s4) \
            af[s4] = *(const short8*)((const char*)SSC + swz(s4 * 16 + lo, ks * 64 + hi * 16)); \
        _Pragma("unroll") \
        for (int s4 = 0; s4 < 4; ++s4) \
            R[s4] = __builtin_amdgcn_mfma_f32_16x16x32_bf16(af[s4], wf[3][ks], R[s4], 0, 0, 0); \
        _Pragma("unroll") \
        for (int s4 = 0; s4 < 4; ++s4) \
            Z[s4] = __builtin_amdgcn_mfma_f32_16x16x32_bf16(af[s4], wf[4][ks], Z[s4], 0, 0, 0); \
        _Pragma("unroll") \
        for (int s4 = 0; s4 < 4; ++s4) \
            N4[s4] = __builtin_amdgcn_mfma_f32_16x16x32_bf16(af[s4], wf[5][ks], N4[s4], 0, 0, 0); \
    } \
    _Pragma("unroll") \
    for (int ks = 0; ks < 4; ++ks) { \
        short8 af[4]; \
        _Pragma("unroll") \
        for (int s4 = 0; s4 < 4; ++s4) \
            af[s4] = *(const short8*)(sX + swz(s4 * 16 + lo, ks * 64 + hi * 16)); \
        _Pragma("unroll") \
        for (int s4 = 0; s4 < 4; ++s4) \
            R[s4] = __builtin_amdgcn_mfma_f32_16x16x32_bf16(af[s4], wf[6][ks], R[s4], 0, 0, 0); \
        _Pragma("unroll") \
        for (int s4 = 0; s4 < 4; ++s4) \
            Z[s4] = __builtin_amdgcn_mfma_f32_16x16x32_bf16(af[s4], wf[7][ks], Z[s4], 0, 0, 0); \
        _Pragma("unroll") \
        for (int s4 = 0; s4 < 4; ++s4) \
            H4[s4] = __builtin_amdgcn_mfma_f32_16x16x32_bf16(af[s4], wf[8][ks], H4[s4], 0, 0, 0); \
    } \
    _Pragma("unroll") \
    for (int s4 = 0; s4 < 4; ++s4) \
        _Pragma("unroll") \
        for (int q = 0; q < 4; ++q) { \
            int row = s4 * 16 + hi * 4 + q; \
            float dg = sdeg[row]; \
            float rv = sigm(R[s4][q] + fmaf(dg, gvR, cR)); \
            float zv = sigm(Z[s4][q] + fmaf(dg, gvZ, cZ)); \
            float nv = tanhfast(N4[s4][q] + fmaf(dg, gvN, cN) + rv * (H4[s4][q] + bH)); \
            float xv = bf2f(*(const unsigned short*)(sX + swz(row, jcol * 2))); \
            float ns = fmaf(zv, xv - nv, nv); \
            *(unsigned short*)((char*)SSN + swz(row, jcol * 2)) = bf16s(ns); \
        } \
    __syncthreads();   /* bar2: SSN published; sX/sA consumed */ \
    if (w < 4) { \
        f32x4 acc = {}; \
        _Pragma("unroll") \
        for (int ks = 0; ks < 4; ++ks) { \
            short8 af = *(const short8*)((const char*)SSN + swz(w * 16 + lo, ks * 64 + hi * 16)); \
            short8 bw = *(const short8*)(WroP + (size_t)(ks * 64 + l) * 8); \
            acc = __builtin_amdgcn_mfma_f32_16x16x32_bf16(af, bw, acc, 0, 0, 0); \
        } \
        if (lo == 0) { \
            _Pragma("unroll") \
            for (int q = 0; q < 4; ++q) \
                pOut[t & 1][w * 16 + hi * 4 + q] = acc[q]; \
        } \
    } \
    if (tid < 64 && t > 0) { \
        float out = pOut[(t & 1) ^ 1][tid] + bro; \
        float d = out - tgtCur; \
        lossAcc += 0.5f * d * d * mvCur; \
    } \
    tgtCur = tgtNext; mvCur = mvNext; \
}

__global__ __launch_bounds__(512, 2)
void mega9_kernel(const char* __restrict__ img,
                  const short* __restrict__ Gp, const short* __restrict__ WroP,
                  const float* __restrict__ degf,
                  const float* __restrict__ gvec, const float* __restrict__ cvec,
                  const float* __restrict__ b_hh, const float* __restrict__ b_ro,
                  const float* __restrict__ targets, const void* __restrict__ maskp,
                  const int* __restrict__ flag,
                  float* __restrict__ lossBlock)
{
    __shared__ char sX[16384];
    __shared__ char sA[16384];
    __shared__ char sS0[16384];
    __shared__ char sS1[16384];
    __shared__ float sdeg[64];
    __shared__ float pOut[2][64];
    __shared__ float pLoss[8];

    const int tid = threadIdx.x;
    const int w = tid >> 6, l = tid & 63, lo = l & 15, hi = l >> 4;
    const int nt = w;
    const int phys = blockIdx.x;
    const int b = phys >> 6;
    const int n0 = (phys & 63) * 64;
    const size_t tbase = (size_t)phys * TT * 32768;

    // ---- 36 weight fragments in registers ----
    short8 wf[9][4];
    #pragma unroll
    for (int m = 0; m < 9; ++m)
        #pragma unroll
        for (int ks = 0; ks < 4; ++ks)
            wf[m][ks] = *(const short8*)(Gp + (size_t)(((m * 8 + nt) * 4 + ks) * 64 + l) * 8);

    const int jcol = nt * 16 + lo;
    const float gvR = gvec[jcol], gvZ = gvec[128 + jcol], gvN = gvec[256 + jcol];
    const float cR = cvec[jcol], cZ = cvec[128 + jcol], cN = cvec[256 + jcol];
    const float bH = b_hh[256 + jcol];
    const float bro = b_ro[0];
    const int fl = *flag;

    #pragma unroll
    for (int it = 0; it < 8; ++it) ((unsigned*)sS0)[tid + it * 512] = 0u;
    if (tid < 64) sdeg[tid] = degf[n0 + tid];
    float tgtCur = 0.f, mvCur = 0.f, lossAcc = 0.f;
    __syncthreads();

    for (int tt = 0; tt < TT; tt += 2) {
        STEP9(tt,     sS0, sS1)
        STEP9(tt + 1, sS1, sS0)
    }

    __syncthreads();   // pOut[1] (t=63) visible to wave 0
    if (tid < 64) {
        float out = pOut[1][tid] + bro;
        float d = out - tgtCur;
        lossAcc += 0.5f * d * d * mvCur;
    }

    float v = lossAcc;
    #pragma unroll
    for (int o = 1; o < 64; o <<= 1) v += __shfl_xor(v, o);
    if (l == 0) pLoss[w] = v;
    __syncthreads();
    if (tid == 0) {
        float s = 0.f;
        #pragma unroll
        for (int ww = 0; ww < 8; ++ww) s += pLoss[ww];
        lossBlock[phys] = s;
    }
}

// ================= CSR build =================
__global__ void count_kernel(const int* __restrict__ dst, int* __restrict__ counts)
{
    int e = blockIdx.x * 256 + threadIdx.x;
    if (e < EE) atomicAdd(&counts[dst[e]], 1);
}

__global__ __launch_bounds__(1024)
void scan_kernel(const int* __restrict__ counts, int* __restrict__ off, int* __restrict__ cursor,
                 float* __restrict__ degf)
{
    __shared__ int s[1024];
    int tid = threadIdx.x;
    int base = tid * 4;
    int c[4]; int sum = 0;
    #pragma unroll
    for (int i = 0; i < 4; ++i) { c[i] = counts[base + i]; sum += c[i]; }
    s[tid] = sum; __syncthreads();
    for (int o = 1; o < 1024; o <<= 1) {
        int v = (tid >= o) ? s[tid - o] : 0;
        __syncthreads();
        s[tid] += v;
        __syncthreads();
    }
    int incl = s[tid];
    int run = incl - sum;
    #pragma unroll
    for (int i = 0; i < 4; ++i) {
        off[base + i] = run; cursor[base + i] = run;
        degf[base + i] = (float)c[i];
        run += c[i];
    }
    if (tid == 1023) off[4096] = incl;
}

__global__ void fill_kernel(const int* __restrict__ src, const int* __restrict__ dst,
                            int* __restrict__ cursor, int* __restrict__ csr_src)
{
    int e = blockIdx.x * 256 + threadIdx.x;
    if (e < EE) {
        int d = dst[e];
        int pos = atomicAdd(&cursor[d], 1);
        csr_src[pos] = src[e];
    }
}

// ================= mask detect / masked count =================
__global__ void detect_kernel(const unsigned char* __restrict__ maskb, int* __restrict__ flag)
{
    int i = blockIdx.x * 256 + threadIdx.x;
    bool hit = (i < BB * TT * NN) && (i & 3) && maskb[i];
    if (__any(hit) && (threadIdx.x & 63) == 0) atomicOr(flag, 1);
}

__global__ void masksum_kernel(const void* __restrict__ maskp, const int* __restrict__ flag,
                               float* __restrict__ den)
{
    int i = blockIdx.x * 256 + threadIdx.x;
    float v = 0.f;
    if (i < BB * TT * NN) {
        if (*flag) v = ((const unsigned char*)maskp)[i] ? 1.f : 0.f;
        else       v = ((const int*)maskp)[i] ? 1.f : 0.f;
    }
    #pragma unroll
    for (int o = 32; o > 0; o >>= 1) v += __shfl_down(v, o);
    __shared__ float sm[4];
    if ((threadIdx.x & 63) == 0) sm[threadIdx.x >> 6] = v;
    __syncthreads();
    if (threadIdx.x == 0) atomicAdd(den, sm[0] + sm[1] + sm[2] + sm[3]);
}

// ================= final reduce + dual-dtype output =================
__global__ __launch_bounds__(256)
void final_kernel(const float* __restrict__ lossBlock, const float* __restrict__ den,
                  unsigned* __restrict__ out)
{
    __shared__ float s[256];
    s[threadIdx.x] = lossBlock[threadIdx.x];
    __syncthreads();
    for (int o = 128; o > 0; o >>= 1) {
        if (threadIdx.x < o) s[threadIdx.x] += s[threadIdx.x + o];
        __syncthreads();
    }
    if (threadIdx.x == 0) {
        float L = s[0] / den[0];
        unsigned u = __float_as_uint(L);
        u += 0x7fffu + ((u >> 16) & 1u);
        unsigned hi = u >> 16;
        out[0] = hi * 0x10001u;   // bf16-exact low half; ~bf16 value as f32
    }
}

extern "C" void kernel_launch(void* const* d_in, const int* in_sizes, int n_in,
                              void* d_out, int out_size, void* d_ws, size_t ws_size,
                              hipStream_t stream)
{
    const float* x       = (const float*)d_in[0];
    const float* targets = (const float*)d_in[1];
    const float* W_msg   = (const float*)d_in[2];
    const float* b_msg   = (const float*)d_in[3];
    const float* W_mix   = (const float*)d_in[4];
    const float* b_mix   = (const float*)d_in[5];
    const float* W_ih    = (const float*)d_in[6];
    const float* b_ih    = (const float*)d_in[7];
    const float* W_hh    = (const float*)d_in[8];
    const float* b_hh    = (const float*)d_in[9];
    const float* W_ro    = (const float*)d_in[10];
    const float* b_ro    = (const float*)d_in[11];
    const void*  maskp   = d_in[12];
    const int*   esrc    = (const int*)d_in[13];
    const int*   edst    = (const int*)d_in[14];

    char* ws = (char*)d_ws;
    char* img = ws; ws += (size_t)256 * TT * 32768;   // 512 MB interleaved x/agg tile stream
    short* Gp          = (short*)ws; ws += (size_t)18432 * 8 * 2;
    short* WroP        = (short*)ws; ws += (size_t)256 * 8 * 2;
    float* Wc_f32      = (float*)ws; ws += 16384 * 4;
    float* bvec        = (float*)ws; ws += 128 * 4;
    float* gvec        = (float*)ws; ws += 384 * 4;
    float* cvec        = (float*)ws; ws += 384 * 4;
    float* degf        = (float*)ws; ws += 4096 * 4;
    float* lossBlock   = (float*)ws; ws += 256 * 4;
    int*   csr_off     = (int*)ws;   ws += 4104 * 4;
    int*   cursor      = (int*)ws;   ws += 4096 * 4;
    int*   counts      = (int*)ws;   ws += 4096 * 4;
    int*   csr_src     = (int*)ws;   ws += (size_t)EE * 4;
    int*   flag        = (int*)ws;   ws += 64;
    float* den         = (float*)ws; ws += 64;

    hipMemsetAsync(counts, 0, 4096 * 4, stream);
    hipMemsetAsync(flag, 0, 64, stream);
    hipMemsetAsync(den, 0, 4, stream);

    detect_kernel   <<<4096, 256, 0, stream>>>((const unsigned char*)maskp, flag);
    masksum_kernel  <<<4096, 256, 0, stream>>>(maskp, flag, den);
    count_kernel    <<<EE / 256, 256, 0, stream>>>(edst, counts);
    scan_kernel     <<<1, 1024, 0, stream>>>(counts, csr_off, cursor, degf);
    fill_kernel     <<<EE / 256, 256, 0, stream>>>(esrc, edst, cursor, csr_src);
    pack_wc_kernel  <<<64, 256, 0, stream>>>(W_msg, W_mix, Wc_f32);
    pack_bvec_kernel<<<1, 128, 0, stream>>>(b_msg, W_mix, bvec);
    pack_gbias_kernel<<<1, 384, 0, stream>>>(bvec, b_mix, W_ih, b_ih, b_hh, gvec, cvec);
    pack_G_kernel   <<<72, 256, 0, stream>>>(Wc_f32, W_mix, W_ih, W_hh, Gp);
    pack_wro_kernel <<<1, 256, 0, stream>>>(W_ro, WroP);

    cvt_img_kernel  <<<16384, 256, 0, stream>>>(x, img);
    gather_pair_kernel<<<65536, 256, 0, stream>>>(img, csr_off, csr_src);

    mega9_kernel<<<256, 512, 0, stream>>>(img, Gp, WroP, degf, gvec, cvec, b_hh, b_ro,
                                          targets, maskp, flag, lossBlock);
    final_kernel<<<1, 256, 0, stream>>>(lossBlock, den, (unsigned*)d_out);
}

// Round 15
// 1307.715 us; speedup vs baseline: 1.6893x; 1.1045x over previous
//
#include <hip/hip_runtime.h>
#include <hip/hip_bf16.h>
#include <stdint.h>

#define BB 4
#define TT 64
#define NN 4096
#define HH 128
#define EE 65536
#define BN (BB*NN)   // 16384

typedef __attribute__((ext_vector_type(8))) short short8;
typedef __attribute__((ext_vector_type(4))) float f32x4;

__device__ __forceinline__ unsigned short bf16r(float f) {
    unsigned u = __float_as_uint(f);
    u += 0x7fffu + ((u >> 16) & 1u);
    return (unsigned short)(u >> 16);
}
__device__ __forceinline__ unsigned cvt_pk_bf16(float lo_, float hi_) {
    unsigned r;
    asm("v_cvt_pk_bf16_f32 %0, %1, %2" : "=v"(r) : "v"(lo_), "v"(hi_));
    return r;
}
__device__ __forceinline__ unsigned short bf16s(float f) {
    unsigned r;
    asm("v_cvt_pk_bf16_f32 %0, %1, %1" : "=v"(r) : "v"(f));
    return (unsigned short)r;
}
__device__ __forceinline__ float bf2f(unsigned bits16) {
    return __uint_as_float(bits16 << 16);
}
__device__ __forceinline__ float sigm(float x) { return 1.f / (1.f + __expf(-x)); }
__device__ __forceinline__ float tanhfast(float x) {
    return 1.f - 2.f / (__expf(2.f * x) + 1.f);
}
// byte address within a [64][128]-bf16 tile, XOR-swizzled (16B-block permutation)
__device__ __forceinline__ unsigned swz(int row, int colbyte) {
    return (unsigned)(row * 256 + (colbyte ^ ((row & 7) << 4)));
}

// ================= packs =================
// Wc_f32 = W_msg @ W_mix[0:128]  (fp32, pack-time)
__global__ void pack_wc_kernel(const float* __restrict__ W_msg, const float* __restrict__ W_mix,
                               float* __restrict__ Wc)
{
    int idx = blockIdx.x * 256 + threadIdx.x;   // 16384
    int k = idx >> 7, j = idx & 127;
    float s = 0.f;
    for (int i = 0; i < 128; ++i) s += W_msg[k * 128 + i] * W_mix[i * 128 + j];
    Wc[idx] = s;
}

__global__ void pack_bvec_kernel(const float* __restrict__ b_msg, const float* __restrict__ W_mix,
                                 float* __restrict__ bvec)
{
    int j = threadIdx.x;   // 128
    float s = 0.f;
    for (int i = 0; i < 128; ++i) s += b_msg[i] * W_mix[i * 128 + j];
    bvec[j] = s;
}

// gvec[c] = bvec @ W_ih ; cvec[c] = b_mix@W_ih + b_ih + (c<256 ? b_hh[c] : 0)
__global__ void pack_gbias_kernel(const float* __restrict__ bvec, const float* __restrict__ b_mix,
                                  const float* __restrict__ W_ih, const float* __restrict__ b_ih,
                                  const float* __restrict__ b_hh,
                                  float* __restrict__ gvec, float* __restrict__ cvec)
{
    int c = threadIdx.x;   // 384
    float g = 0.f, gb = 0.f;
    for (int j = 0; j < 128; ++j) {
        g  += bvec[j]  * W_ih[j * 384 + c];
        gb += b_mix[j] * W_ih[j * 384 + c];
    }
    gvec[c] = g;
    cvec[c] = gb + b_ih[c] + (c < 256 ? b_hh[c] : 0.f);
}

// Gp[mat(9)][nt(8)][ks(4)][lane(64)][8]: mats 0-2 = G1 r/z/n (Wc@W_ih cols),
// 3-5 = G2 r/z/n (W_mix_bot@W_ih), 6-8 = W_hh r/z/n-slice.
__global__ void pack_G_kernel(const float* __restrict__ Wc, const float* __restrict__ W_mix,
                              const float* __restrict__ W_ih, const float* __restrict__ W_hh,
                              short* __restrict__ Gp)
{
    int idx = blockIdx.x * 256 + threadIdx.x;   // 9*8*4*64 = 18432
    if (idx >= 18432) return;
    int l = idx & 63, ks = (idx >> 6) & 3, nt = (idx >> 8) & 7, mat = idx >> 11;
    int lo = l & 15, hi = l >> 4;
    int col = nt * 16 + lo;
    short8 v;
    #pragma unroll
    for (int i = 0; i < 8; ++i) {
        int k = ks * 32 + hi * 8 + i;
        float s;
        if (mat < 3) {
            int c = mat * 128 + col;
            s = 0.f;
            for (int j = 0; j < 128; ++j) s += Wc[k * 128 + j] * W_ih[j * 384 + c];
        } else if (mat < 6) {
            int c = (mat - 3) * 128 + col;
            s = 0.f;
            for (int j = 0; j < 128; ++j) s += W_mix[(128 + k) * 128 + j] * W_ih[j * 384 + c];
        } else {
            int c = (mat - 6) * 128 + col;
            s = W_hh[k * 384 + c];
        }
        v[i] = (short)bf16r(s);
    }
    *(short8*)(Gp + (size_t)idx * 8) = v;
}

// W_roP: [ks(4)][lane(64)][8]; only col 0 nonzero = W_ro[k]
__global__ void pack_wro_kernel(const float* __restrict__ W_ro, short* __restrict__ out)
{
    int idx = threadIdx.x;      // 256
    int l = idx & 63, ks = idx >> 6;
    int lo = l & 15, hi = l >> 4;
    short8 v;
    #pragma unroll
    for (int i = 0; i < 8; ++i) {
        int k = ks * 32 + hi * 8 + i;
        v[i] = (lo == 0) ? (short)bf16r(W_ro[k]) : (short)0;
    }
    *(short8*)(out + (size_t)idx * 8) = v;
}

// ================= x -> pre-swizzled bf16 x-tiles inside img =================
// img tile layout: img[phys*64+t] = 32KB: [0,16K) x tile, [16K,32K) agg tile
__global__ __launch_bounds__(256)
void cvt_img_kernel(const float* __restrict__ x, char* __restrict__ img)
{
    int tileid = blockIdx.x;              // phys*64 + t  (16384)
    int phys = tileid >> 6, t = tileid & 63;
    int b = phys >> 6, n0 = (phys & 63) * 64;
    const float* __restrict__ src = x + ((size_t)(b * TT + t) * NN + n0) * HH;
    char* __restrict__ dst = img + (size_t)tileid * 32768;
    int tid = threadIdx.x;
    #pragma unroll
    for (int u4 = 0; u4 < 4; ++u4) {
        int unit = tid + u4 * 256;          // 1024 units of 16B
        int row = unit >> 4, g = unit & 15;
        const float* sp = src + row * HH + g * 8;
        float4 v0 = *(const float4*)sp;
        float4 v1 = *(const float4*)(sp + 4);
        uint4 o;
        o.x = cvt_pk_bf16(v0.x, v0.y);
        o.y = cvt_pk_bf16(v0.z, v0.w);
        o.z = cvt_pk_bf16(v1.x, v1.y);
        o.w = cvt_pk_bf16(v1.z, v1.w);
        *(uint4*)(dst + swz(row, g * 16)) = o;
    }
}

// ================= gather: 4 bts/block, lanes split by bt-pair; edge addr computed once =====
// Lanes 0-31 accumulate bts {0,1}; lanes 32-63 bts {2,3}. Lane L covers cols 4L..4L+3 (8B).
__global__ __launch_bounds__(256)
void gather_quad_kernel(char* __restrict__ img,
                        const int* __restrict__ off, const int* __restrict__ srcs)
{
    int bid = blockIdx.x;               // 16384
    int xcd = bid & 7;
    int rest = bid >> 3;                // 0..2047
    int grp = rest >> 8;                // 0..7 (4 btl's each)
    int chunk = rest & 255;             // 0..255 (16 dst rows each)
    int w = threadIdx.x >> 6, l = threadIdx.x & 63;
    int half = l >> 5, L = l & 31;
    // this half's two bts
    size_t baseA, baseB;
    {
        int btA = (grp * 4 + half * 2 + 0) * 8 + xcd;
        int btB = (grp * 4 + half * 2 + 1) * 8 + xcd;
        baseA = ((size_t)(btA >> 6) * 4096 + (btA & 63)) * 32768;
        baseB = ((size_t)(btB >> 6) * 4096 + (btB & 63)) * 32768;
    }

    #pragma unroll
    for (int r = 0; r < 4; ++r) {
        int dst = chunk * 16 + w * 4 + r;
        int s = off[dst], e = off[dst + 1];
        float aA0 = 0.f, aA1 = 0.f, aA2 = 0.f, aA3 = 0.f;
        float aB0 = 0.f, aB1 = 0.f, aB2 = 0.f, aB3 = 0.f;
        int i = s;
        for (; i + 1 < e; i += 2) {
            int s0 = srcs[i], s1 = srcs[i + 1];
            size_t t0 = ((size_t)(s0 >> 6) << 21) + ((unsigned)(s0 & 63) << 8)
                      + ((L * 8) ^ ((s0 & 7) << 4));
            size_t t1 = ((size_t)(s1 >> 6) << 21) + ((unsigned)(s1 & 63) << 8)
                      + ((L * 8) ^ ((s1 & 7) << 4));
            uint2 vA0 = *(const uint2*)(img + baseA + t0);
            uint2 vB0 = *(const uint2*)(img + baseB + t0);
            uint2 vA1 = *(const uint2*)(img + baseA + t1);
            uint2 vB1 = *(const uint2*)(img + baseB + t1);
            aA0 += __uint_as_float(vA0.x << 16) + __uint_as_float(vA1.x << 16);
            aA1 += __uint_as_float(vA0.x & 0xffff0000u) + __uint_as_float(vA1.x & 0xffff0000u);
            aA2 += __uint_as_float(vA0.y << 16) + __uint_as_float(vA1.y << 16);
            aA3 += __uint_as_float(vA0.y & 0xffff0000u) + __uint_as_float(vA1.y & 0xffff0000u);
            aB0 += __uint_as_float(vB0.x << 16) + __uint_as_float(vB1.x << 16);
            aB1 += __uint_as_float(vB0.x & 0xffff0000u) + __uint_as_float(vB1.x & 0xffff0000u);
            aB2 += __uint_as_float(vB0.y << 16) + __uint_as_float(vB1.y << 16);
            aB3 += __uint_as_float(vB0.y & 0xffff0000u) + __uint_as_float(vB1.y & 0xffff0000u);
        }
        if (i < e) {
            int s0 = srcs[i];
            size_t t0 = ((size_t)(s0 >> 6) << 21) + ((unsigned)(s0 & 63) << 8)
                      + ((L * 8) ^ ((s0 & 7) << 4));
            uint2 vA0 = *(const uint2*)(img + baseA + t0);
            uint2 vB0 = *(const uint2*)(img + baseB + t0);
            aA0 += __uint_as_float(vA0.x << 16);
            aA1 += __uint_as_float(vA0.x & 0xffff0000u);
            aA2 += __uint_as_float(vA0.y << 16);
            aA3 += __uint_as_float(vA0.y & 0xffff0000u);
            aB0 += __uint_as_float(vB0.x << 16);
            aB1 += __uint_as_float(vB0.x & 0xffff0000u);
            aB2 += __uint_as_float(vB0.y << 16);
            aB3 += __uint_as_float(vB0.y & 0xffff0000u);
        }
        size_t doff = 16384 + ((size_t)(dst >> 6) << 21) + ((unsigned)(dst & 63) << 8)
                    + ((L * 8) ^ ((dst & 7) << 4));
        uint2 oA, oB;
        oA.x = cvt_pk_bf16(aA0, aA1);
        oA.y = cvt_pk_bf16(aA2, aA3);
        oB.x = cvt_pk_bf16(aB0, aB1);
        oB.y = cvt_pk_bf16(aB2, aB3);
        *(uint2*)(img + baseA + doff) = oA;
        *(uint2*)(img + baseB + doff) = oB;
    }
}

// ================= persistent T-loop: single fused GEMM phase (W_mix folded away) =================
#define STEP9(T, SSC, SSN) { \
    const int t = (T); \
    float tgtNext = 0.f, mvNext = 0.f; \
    if (tid < 64) { \
        size_t ti = (size_t)(b * TT + t) * NN + n0 + tid; \
        tgtNext = targets[ti]; \
        mvNext = fl ? (((const unsigned char*)maskp)[ti] ? 1.f : 0.f) \
                    : (((const int*)maskp)[ti] ? 1.f : 0.f); \
    } \
    { \
        const char* g = img + tbase + (size_t)t * 32768; \
        _Pragma("unroll") \
        for (int k = 0; k < 4; ++k) { \
            int u = tid + k * 512; \
            short8 v = *(const short8*)(g + u * 16); \
            if (k < 2) *(short8*)(sX + u * 16) = v; \
            else       *(short8*)(sA + (u - 1024) * 16) = v; \
        } \
    } \
    __syncthreads();   /* bar1: tiles ready, prev sSt reads done */ \
    f32x4 R[4] = {}, Z[4] = {}, N4[4] = {}, H4[4] = {}; \
    _Pragma("unroll") \
    for (int ks = 0; ks < 4; ++ks) { \
        short8 af[4]; \
        _Pragma("unroll") \
        for (int s4 = 0; s4 < 4; ++s4) \
            af[s4] = *(const short8*)(sA + swz(s4 * 16 + lo, ks * 64 + hi * 16)); \
        _Pragma("unroll") \
        for (int s4 = 0; s4 < 4; ++s4) \
            R[s4] = __builtin_amdgcn_mfma_f32_16x16x32_bf16(af[s4], wf[0][ks], R[s4], 0, 0, 0); \
        _Pragma("unroll") \
        for (int s4 = 0; s4 < 4; ++s4) \
            Z[s4] = __builtin_amdgcn_mfma_f32_16x16x32_bf16(af[s4], wf[1][ks], Z[s4], 0, 0, 0); \
        _Pragma("unroll") \
        for (int s4 = 0; s4 < 4; ++s4) \
            N4[s4] = __builtin_amdgcn_mfma_f32_16x16x32_bf16(af[s4], wf[2][ks], N4[s4], 0, 0, 0); \
    } \
    _Pragma("unroll") \
    for (int ks = 0; ks < 4; ++ks) { \
        short8 af[4]; \
        _Pragma("unroll") \
        for (int s4 = 0; s4 < 4; ++s4) \
            af[s4] = *(const short8*)((const char*)SSC + swz(s4 * 16 + lo, ks * 64 + hi * 16)); \
        _Pragma("unroll") \
        for (int s4 = 0; s4 < 4; ++s4) \
            R[s4] = __builtin_amdgcn_mfma_f32_16x16x32_bf16(af[s4], wf[3][ks], R[s4], 0, 0, 0); \
        _Pragma("unroll") \
        for (int s4 = 0; s4 < 4; ++s4) \
            Z[s4] = __builtin_amdgcn_mfma_f32_16x16x32_bf16(af[s4], wf[4][ks], Z[s4], 0, 0, 0); \
        _Pragma("unroll") \
        for (int s4 = 0; s4 < 4; ++s4) \
            N4[s4] = __builtin_amdgcn_mfma_f32_16x16x32_bf16(af[s4], wf[5][ks], N4[s4], 0, 0, 0); \
    } \
    _Pragma("unroll") \
    for (int ks = 0; ks < 4; ++ks) { \
        short8 af[4]; \
        _Pragma("unroll") \
        for (int s4 = 0; s4 < 4; ++s4) \
            af[s4] = *(const short8*)(sX + swz(s4 * 16 + lo, ks * 64 + hi * 16)); \
        _Pragma("unroll") \
        for (int s4 = 0; s4 < 4; ++s4) \
            R[s4] = __builtin_amdgcn_mfma_f32_16x16x32_bf16(af[s4], wf[6][ks], R[s4], 0, 0, 0); \
        _Pragma("unroll") \
        for (int s4 = 0; s4 < 4; ++s4) \
            Z[s4] = __builtin_amdgcn_mfma_f32_16x16x32_bf16(af[s4], wf[7][ks], Z[s4], 0, 0, 0); \
        _Pragma("unroll") \
        for (int s4 = 0; s4 < 4; ++s4) \
            H4[s4] = __builtin_amdgcn_mfma_f32_16x16x32_bf16(af[s4], wf[8][ks], H4[s4], 0, 0, 0); \
    } \
    _Pragma("unroll") \
    for (int s4 = 0; s4 < 4; ++s4) \
        _Pragma("unroll") \
        for (int q = 0; q < 4; ++q) { \
            int row = s4 * 16 + hi * 4 + q; \
            float dg = sdeg[row]; \
            float rv = sigm(R[s4][q] + fmaf(dg, gvR, cR)); \
            float zv = sigm(Z[s4][q] + fmaf(dg, gvZ, cZ)); \
            float nv = tanhfast(N4[s4][q] + fmaf(dg, gvN, cN) + rv * (H4[s4][q] + bH)); \
            float xv = bf2f(*(const unsigned short*)(sX + swz(row, jcol * 2))); \
            float ns = fmaf(zv, xv - nv, nv); \
            *(unsigned short*)((char*)SSN + swz(row, jcol * 2)) = bf16s(ns); \
        } \
    __syncthreads();   /* bar2: SSN published; sX/sA consumed */ \
    if (w < 4) { \
        f32x4 acc = {}; \
        _Pragma("unroll") \
        for (int ks = 0; ks < 4; ++ks) { \
            short8 af = *(const short8*)((const char*)SSN + swz(w * 16 + lo, ks * 64 + hi * 16)); \
            short8 bw = *(const short8*)(WroP + (size_t)(ks * 64 + l) * 8); \
            acc = __builtin_amdgcn_mfma_f32_16x16x32_bf16(af, bw, acc, 0, 0, 0); \
        } \
        if (lo == 0) { \
            _Pragma("unroll") \
            for (int q = 0; q < 4; ++q) \
                pOut[t & 1][w * 16 + hi * 4 + q] = acc[q]; \
        } \
    } \
    if (tid < 64 && t > 0) { \
        float out = pOut[(t & 1) ^ 1][tid] + bro; \
        float d = out - tgtCur; \
        lossAcc += 0.5f * d * d * mvCur; \
    } \
    tgtCur = tgtNext; mvCur = mvNext; \
}

__global__ __launch_bounds__(512, 2)
void mega9_kernel(const char* __restrict__ img,
                  const short* __restrict__ Gp, const short* __restrict__ WroP,
                  const float* __restrict__ degf,
                  const float* __restrict__ gvec, const float* __restrict__ cvec,
                  const float* __restrict__ b_hh, const float* __restrict__ b_ro,
                  const float* __restrict__ targets, const void* __restrict__ maskp,
                  const int* __restrict__ flag,
                  float* __restrict__ lossBlock)
{
    __shared__ char sX[16384];
    __shared__ char sA[16384];
    __shared__ char sS0[16384];
    __shared__ char sS1[16384];
    __shared__ float sdeg[64];
    __shared__ float pOut[2][64];
    __shared__ float pLoss[8];

    const int tid = threadIdx.x;
    const int w = tid >> 6, l = tid & 63, lo = l & 15, hi = l >> 4;
    const int nt = w;
    const int phys = blockIdx.x;
    const int b = phys >> 6;
    const int n0 = (phys & 63) * 64;
    const size_t tbase = (size_t)phys * TT * 32768;

    // ---- 36 weight fragments in registers ----
    short8 wf[9][4];
    #pragma unroll
    for (int m = 0; m < 9; ++m)
        #pragma unroll
        for (int ks = 0; ks < 4; ++ks)
            wf[m][ks] = *(const short8*)(Gp + (size_t)(((m * 8 + nt) * 4 + ks) * 64 + l) * 8);

    const int jcol = nt * 16 + lo;
    const float gvR = gvec[jcol], gvZ = gvec[128 + jcol], gvN = gvec[256 + jcol];
    const float cR = cvec[jcol], cZ = cvec[128 + jcol], cN = cvec[256 + jcol];
    const float bH = b_hh[256 + jcol];
    const float bro = b_ro[0];
    const int fl = *flag;

    #pragma unroll
    for (int it = 0; it < 8; ++it) ((unsigned*)sS0)[tid + it * 512] = 0u;
    if (tid < 64) sdeg[tid] = degf[n0 + tid];
    float tgtCur = 0.f, mvCur = 0.f, lossAcc = 0.f;
    __syncthreads();

    for (int tt = 0; tt < TT; tt += 2) {
        STEP9(tt,     sS0, sS1)
        STEP9(tt + 1, sS1, sS0)
    }

    __syncthreads();   // pOut[1] (t=63) visible to wave 0
    if (tid < 64) {
        float out = pOut[1][tid] + bro;
        float d = out - tgtCur;
        lossAcc += 0.5f * d * d * mvCur;
    }

    float v = lossAcc;
    #pragma unroll
    for (int o = 1; o < 64; o <<= 1) v += __shfl_xor(v, o);
    if (l == 0) pLoss[w] = v;
    __syncthreads();
    if (tid == 0) {
        float s = 0.f;
        #pragma unroll
        for (int ww = 0; ww < 8; ++ww) s += pLoss[ww];
        lossBlock[phys] = s;
    }
}

// ================= CSR build =================
__global__ void count_kernel(const int* __restrict__ dst, int* __restrict__ counts)
{
    int e = blockIdx.x * 256 + threadIdx.x;
    if (e < EE) atomicAdd(&counts[dst[e]], 1);
}

__global__ __launch_bounds__(1024)
void scan_kernel(const int* __restrict__ counts, int* __restrict__ off, int* __restrict__ cursor,
                 float* __restrict__ degf)
{
    __shared__ int s[1024];
    int tid = threadIdx.x;
    int base = tid * 4;
    int c[4]; int sum = 0;
    #pragma unroll
    for (int i = 0; i < 4; ++i) { c[i] = counts[base + i]; sum += c[i]; }
    s[tid] = sum; __syncthreads();
    for (int o = 1; o < 1024; o <<= 1) {
        int v = (tid >= o) ? s[tid - o] : 0;
        __syncthreads();
        s[tid] += v;
        __syncthreads();
    }
    int incl = s[tid];
    int run = incl - sum;
    #pragma unroll
    for (int i = 0; i < 4; ++i) {
        off[base + i] = run; cursor[base + i] = run;
        degf[base + i] = (float)c[i];
        run += c[i];
    }
    if (tid == 1023) off[4096] = incl;
}

__global__ void fill_kernel(const int* __restrict__ src, const int* __restrict__ dst,
                            int* __restrict__ cursor, int* __restrict__ csr_src)
{
    int e = blockIdx.x * 256 + threadIdx.x;
    if (e < EE) {
        int d = dst[e];
        int pos = atomicAdd(&cursor[d], 1);
        csr_src[pos] = src[e];
    }
}

// ================= mask detect / masked count =================
__global__ void detect_kernel(const unsigned char* __restrict__ maskb, int* __restrict__ flag)
{
    int i = blockIdx.x * 256 + threadIdx.x;
    bool hit = (i < BB * TT * NN) && (i & 3) && maskb[i];
    if (__any(hit) && (threadIdx.x & 63) == 0) atomicOr(flag, 1);
}

__global__ void masksum_kernel(const void* __restrict__ maskp, const int* __restrict__ flag,
                               float* __restrict__ den)
{
    int i = blockIdx.x * 256 + threadIdx.x;
    float v = 0.f;
    if (i < BB * TT * NN) {
        if (*flag) v = ((const unsigned char*)maskp)[i] ? 1.f : 0.f;
        else       v = ((const int*)maskp)[i] ? 1.f : 0.f;
    }
    #pragma unroll
    for (int o = 32; o > 0; o >>= 1) v += __shfl_down(v, o);
    __shared__ float sm[4];
    if ((threadIdx.x & 63) == 0) sm[threadIdx.x >> 6] = v;
    __syncthreads();
    if (threadIdx.x == 0) atomicAdd(den, sm[0] + sm[1] + sm[2] + sm[3]);
}

// ================= final reduce + dual-dtype output =================
__global__ __launch_bounds__(256)
void final_kernel(const float* __restrict__ lossBlock, const float* __restrict__ den,
                  unsigned* __restrict__ out)
{
    __shared__ float s[256];
    s[threadIdx.x] = lossBlock[threadIdx.x];
    __syncthreads();
    for (int o = 128; o > 0; o >>= 1) {
        if (threadIdx.x < o) s[threadIdx.x] += s[threadIdx.x + o];
        __syncthreads();
    }
    if (threadIdx.x == 0) {
        float L = s[0] / den[0];
        unsigned u = __float_as_uint(L);
        u += 0x7fffu + ((u >> 16) & 1u);
        unsigned hi = u >> 16;
        out[0] = hi * 0x10001u;   // bf16-exact low half; ~bf16 value as f32
    }
}

extern "C" void kernel_launch(void* const* d_in, const int* in_sizes, int n_in,
                              void* d_out, int out_size, void* d_ws, size_t ws_size,
                              hipStream_t stream)
{
    const float* x       = (const float*)d_in[0];
    const float* targets = (const float*)d_in[1];
    const float* W_msg   = (const float*)d_in[2];
    const float* b_msg   = (const float*)d_in[3];
    const float* W_mix   = (const float*)d_in[4];
    const float* b_mix   = (const float*)d_in[5];
    const float* W_ih    = (const float*)d_in[6];
    const float* b_ih    = (const float*)d_in[7];
    const float* W_hh    = (const float*)d_in[8];
    const float* b_hh    = (const float*)d_in[9];
    const float* W_ro    = (const float*)d_in[10];
    const float* b_ro    = (const float*)d_in[11];
    const void*  maskp   = d_in[12];
    const int*   esrc    = (const int*)d_in[13];
    const int*   edst    = (const int*)d_in[14];

    char* ws = (char*)d_ws;
    char* img = ws; ws += (size_t)256 * TT * 32768;   // 512 MB interleaved x/agg tile stream
    short* Gp          = (short*)ws; ws += (size_t)18432 * 8 * 2;
    short* WroP        = (short*)ws; ws += (size_t)256 * 8 * 2;
    float* Wc_f32      = (float*)ws; ws += 16384 * 4;
    float* bvec        = (float*)ws; ws += 128 * 4;
    float* gvec        = (float*)ws; ws += 384 * 4;
    float* cvec        = (float*)ws; ws += 384 * 4;
    float* degf        = (float*)ws; ws += 4096 * 4;
    float* lossBlock   = (float*)ws; ws += 256 * 4;
    int*   csr_off     = (int*)ws;   ws += 4104 * 4;
    int*   cursor      = (int*)ws;   ws += 4096 * 4;
    int*   counts      = (int*)ws;   ws += 4096 * 4;
    int*   csr_src     = (int*)ws;   ws += (size_t)EE * 4;
    int*   flag        = (int*)ws;   ws += 64;
    float* den         = (float*)ws; ws += 64;

    hipMemsetAsync(counts, 0, 4096 * 4, stream);
    hipMemsetAsync(flag, 0, 64, stream);
    hipMemsetAsync(den, 0, 4, stream);

    detect_kernel   <<<4096, 256, 0, stream>>>((const unsigned char*)maskp, flag);
    masksum_kernel  <<<4096, 256, 0, stream>>>(maskp, flag, den);
    count_kernel    <<<EE / 256, 256, 0, stream>>>(edst, counts);
    scan_kernel     <<<1, 1024, 0, stream>>>(counts, csr_off, cursor, degf);
    fill_kernel     <<<EE / 256, 256, 0, stream>>>(esrc, edst, cursor, csr_src);
    pack_wc_kernel  <<<64, 256, 0, stream>>>(W_msg, W_mix, Wc_f32);
    pack_bvec_kernel<<<1, 128, 0, stream>>>(b_msg, W_mix, bvec);
    pack_gbias_kernel<<<1, 384, 0, stream>>>(bvec, b_mix, W_ih, b_ih, b_hh, gvec, cvec);
    pack_G_kernel   <<<72, 256, 0, stream>>>(Wc_f32, W_mix, W_ih, W_hh, Gp);
    pack_wro_kernel <<<1, 256, 0, stream>>>(W_ro, WroP);

    cvt_img_kernel  <<<16384, 256, 0, stream>>>(x, img);
    gather_quad_kernel<<<16384, 256, 0, stream>>>(img, csr_off, csr_src);

    mega9_kernel<<<256, 512, 0, stream>>>(img, Gp, WroP, degf, gvec, cvec, b_hh, b_ro,
                                          targets, maskp, flag, lossBlock);
    final_kernel<<<1, 256, 0, stream>>>(lossBlock, den, (unsigned*)d_out);
}

// Round 16
// 1261.762 us; speedup vs baseline: 1.7508x; 1.0364x over previous
//
#include <hip/hip_runtime.h>
#include <hip/hip_bf16.h>
#include <stdint.h>

#define BB 4
#define TT 64
#define NN 4096
#define HH 128
#define EE 65536
#define BN (BB*NN)   // 16384

typedef __attribute__((ext_vector_type(8))) short short8;
typedef __attribute__((ext_vector_type(4))) float f32x4;

__device__ __forceinline__ unsigned short bf16r(float f) {
    unsigned u = __float_as_uint(f);
    u += 0x7fffu + ((u >> 16) & 1u);
    return (unsigned short)(u >> 16);
}
__device__ __forceinline__ unsigned cvt_pk_bf16(float lo_, float hi_) {
    unsigned r;
    asm("v_cvt_pk_bf16_f32 %0, %1, %2" : "=v"(r) : "v"(lo_), "v"(hi_));
    return r;
}
__device__ __forceinline__ unsigned short bf16s(float f) {
    unsigned r;
    asm("v_cvt_pk_bf16_f32 %0, %1, %1" : "=v"(r) : "v"(f));
    return (unsigned short)r;
}
__device__ __forceinline__ float bf2f(unsigned bits16) {
    return __uint_as_float(bits16 << 16);
}
__device__ __forceinline__ float sigm(float x) { return 1.f / (1.f + __expf(-x)); }
__device__ __forceinline__ float tanhfast(float x) {
    return 1.f - 2.f / (__expf(2.f * x) + 1.f);
}
// byte address within a [64][128]-bf16 tile, XOR-swizzled (16B-block permutation)
__device__ __forceinline__ unsigned swz(int row, int colbyte) {
    return (unsigned)(row * 256 + (colbyte ^ ((row & 7) << 4)));
}

#define GLD_LDS16(g, s) __builtin_amdgcn_global_load_lds( \
    (const __attribute__((address_space(1))) void*)(g), \
    (__attribute__((address_space(3))) void*)(s), 16, 0, 0)

// ================= packs =================
// Wc_f32 = W_msg @ W_mix[0:128]  (fp32, pack-time)
__global__ void pack_wc_kernel(const float* __restrict__ W_msg, const float* __restrict__ W_mix,
                               float* __restrict__ Wc)
{
    int idx = blockIdx.x * 256 + threadIdx.x;   // 16384
    int k = idx >> 7, j = idx & 127;
    float s = 0.f;
    for (int i = 0; i < 128; ++i) s += W_msg[k * 128 + i] * W_mix[i * 128 + j];
    Wc[idx] = s;
}

__global__ void pack_bvec_kernel(const float* __restrict__ b_msg, const float* __restrict__ W_mix,
                                 float* __restrict__ bvec)
{
    int j = threadIdx.x;   // 128
    float s = 0.f;
    for (int i = 0; i < 128; ++i) s += b_msg[i] * W_mix[i * 128 + j];
    bvec[j] = s;
}

// gvec[c] = bvec @ W_ih ; cvec[c] = b_mix@W_ih + b_ih + (c<256 ? b_hh[c] : 0)
__global__ void pack_gbias_kernel(const float* __restrict__ bvec, const float* __restrict__ b_mix,
                                  const float* __restrict__ W_ih, const float* __restrict__ b_ih,
                                  const float* __restrict__ b_hh,
                                  float* __restrict__ gvec, float* __restrict__ cvec)
{
    int c = threadIdx.x;   // 384
    float g = 0.f, gb = 0.f;
    for (int j = 0; j < 128; ++j) {
        g  += bvec[j]  * W_ih[j * 384 + c];
        gb += b_mix[j] * W_ih[j * 384 + c];
    }
    gvec[c] = g;
    cvec[c] = gb + b_ih[c] + (c < 256 ? b_hh[c] : 0.f);
}

// Gp[mat(9)][nt(8)][ks(4)][lane(64)][8]: mats 0-2 = G1 r/z/n (Wc@W_ih cols),
// 3-5 = G2 r/z/n (W_mix_bot@W_ih), 6-8 = W_hh r/z/n-slice.
__global__ void pack_G_kernel(const float* __restrict__ Wc, const float* __restrict__ W_mix,
                              const float* __restrict__ W_ih, const float* __restrict__ W_hh,
                              short* __restrict__ Gp)
{
    int idx = blockIdx.x * 256 + threadIdx.x;   // 9*8*4*64 = 18432
    if (idx >= 18432) return;
    int l = idx & 63, ks = (idx >> 6) & 3, nt = (idx >> 8) & 7, mat = idx >> 11;
    int lo = l & 15, hi = l >> 4;
    int col = nt * 16 + lo;
    short8 v;
    #pragma unroll
    for (int i = 0; i < 8; ++i) {
        int k = ks * 32 + hi * 8 + i;
        float s;
        if (mat < 3) {
            int c = mat * 128 + col;
            s = 0.f;
            for (int j = 0; j < 128; ++j) s += Wc[k * 128 + j] * W_ih[j * 384 + c];
        } else if (mat < 6) {
            int c = (mat - 3) * 128 + col;
            s = 0.f;
            for (int j = 0; j < 128; ++j) s += W_mix[(128 + k) * 128 + j] * W_ih[j * 384 + c];
        } else {
            int c = (mat - 6) * 128 + col;
            s = W_hh[k * 384 + c];
        }
        v[i] = (short)bf16r(s);
    }
    *(short8*)(Gp + (size_t)idx * 8) = v;
}

// W_roP: [ks(4)][lane(64)][8]; only col 0 nonzero = W_ro[k]
__global__ void pack_wro_kernel(const float* __restrict__ W_ro, short* __restrict__ out)
{
    int idx = threadIdx.x;      // 256
    int l = idx & 63, ks = idx >> 6;
    int lo = l & 15, hi = l >> 4;
    short8 v;
    #pragma unroll
    for (int i = 0; i < 8; ++i) {
        int k = ks * 32 + hi * 8 + i;
        v[i] = (lo == 0) ? (short)bf16r(W_ro[k]) : (short)0;
    }
    *(short8*)(out + (size_t)idx * 8) = v;
}

// ================= x -> pre-swizzled bf16 x-tiles inside img =================
// img tile layout: img[phys*64+t] = 32KB: [0,16K) x tile, [16K,32K) agg tile
__global__ __launch_bounds__(256)
void cvt_img_kernel(const float* __restrict__ x, char* __restrict__ img)
{
    int tileid = blockIdx.x;              // phys*64 + t  (16384)
    int phys = tileid >> 6, t = tileid & 63;
    int b = phys >> 6, n0 = (phys & 63) * 64;
    const float* __restrict__ src = x + ((size_t)(b * TT + t) * NN + n0) * HH;
    char* __restrict__ dst = img + (size_t)tileid * 32768;
    int tid = threadIdx.x;
    #pragma unroll
    for (int u4 = 0; u4 < 4; ++u4) {
        int unit = tid + u4 * 256;          // 1024 units of 16B
        int row = unit >> 4, g = unit & 15;
        const float* sp = src + row * HH + g * 8;
        float4 v0 = *(const float4*)sp;
        float4 v1 = *(const float4*)(sp + 4);
        uint4 o;
        o.x = cvt_pk_bf16(v0.x, v0.y);
        o.y = cvt_pk_bf16(v0.z, v0.w);
        o.z = cvt_pk_bf16(v1.x, v1.y);
        o.w = cvt_pk_bf16(v1.z, v1.w);
        *(uint4*)(dst + swz(row, g * 16)) = o;
    }
}

// ================= gather: 4 bts/block, lanes split by bt-pair; edge addr computed once =====
__global__ __launch_bounds__(256)
void gather_quad_kernel(char* __restrict__ img,
                        const int* __restrict__ off, const int* __restrict__ srcs)
{
    int bid = blockIdx.x;               // 16384
    int xcd = bid & 7;
    int rest = bid >> 3;                // 0..2047
    int grp = rest >> 8;                // 0..7 (4 btl's each)
    int chunk = rest & 255;             // 0..255 (16 dst rows each)
    int w = threadIdx.x >> 6, l = threadIdx.x & 63;
    int half = l >> 5, L = l & 31;
    size_t baseA, baseB;
    {
        int btA = (grp * 4 + half * 2 + 0) * 8 + xcd;
        int btB = (grp * 4 + half * 2 + 1) * 8 + xcd;
        baseA = ((size_t)(btA >> 6) * 4096 + (btA & 63)) * 32768;
        baseB = ((size_t)(btB >> 6) * 4096 + (btB & 63)) * 32768;
    }

    #pragma unroll
    for (int r = 0; r < 4; ++r) {
        int dst = chunk * 16 + w * 4 + r;
        int s = off[dst], e = off[dst + 1];
        float aA0 = 0.f, aA1 = 0.f, aA2 = 0.f, aA3 = 0.f;
        float aB0 = 0.f, aB1 = 0.f, aB2 = 0.f, aB3 = 0.f;
        int i = s;
        for (; i + 1 < e; i += 2) {
            int s0 = srcs[i], s1 = srcs[i + 1];
            size_t t0 = ((size_t)(s0 >> 6) << 21) + ((unsigned)(s0 & 63) << 8)
                      + ((L * 8) ^ ((s0 & 7) << 4));
            size_t t1 = ((size_t)(s1 >> 6) << 21) + ((unsigned)(s1 & 63) << 8)
                      + ((L * 8) ^ ((s1 & 7) << 4));
            uint2 vA0 = *(const uint2*)(img + baseA + t0);
            uint2 vB0 = *(const uint2*)(img + baseB + t0);
            uint2 vA1 = *(const uint2*)(img + baseA + t1);
            uint2 vB1 = *(const uint2*)(img + baseB + t1);
            aA0 += __uint_as_float(vA0.x << 16) + __uint_as_float(vA1.x << 16);
            aA1 += __uint_as_float(vA0.x & 0xffff0000u) + __uint_as_float(vA1.x & 0xffff0000u);
            aA2 += __uint_as_float(vA0.y << 16) + __uint_as_float(vA1.y << 16);
            aA3 += __uint_as_float(vA0.y & 0xffff0000u) + __uint_as_float(vA1.y & 0xffff0000u);
            aB0 += __uint_as_float(vB0.x << 16) + __uint_as_float(vB1.x << 16);
            aB1 += __uint_as_float(vB0.x & 0xffff0000u) + __uint_as_float(vB1.x & 0xffff0000u);
            aB2 += __uint_as_float(vB0.y << 16) + __uint_as_float(vB1.y << 16);
            aB3 += __uint_as_float(vB0.y & 0xffff0000u) + __uint_as_float(vB1.y & 0xffff0000u);
        }
        if (i < e) {
            int s0 = srcs[i];
            size_t t0 = ((size_t)(s0 >> 6) << 21) + ((unsigned)(s0 & 63) << 8)
                      + ((L * 8) ^ ((s0 & 7) << 4));
            uint2 vA0 = *(const uint2*)(img + baseA + t0);
            uint2 vB0 = *(const uint2*)(img + baseB + t0);
            aA0 += __uint_as_float(vA0.x << 16);
            aA1 += __uint_as_float(vA0.x & 0xffff0000u);
            aA2 += __uint_as_float(vA0.y << 16);
            aA3 += __uint_as_float(vA0.y & 0xffff0000u);
            aB0 += __uint_as_float(vB0.x << 16);
            aB1 += __uint_as_float(vB0.x & 0xffff0000u);
            aB2 += __uint_as_float(vB0.y << 16);
            aB3 += __uint_as_float(vB0.y & 0xffff0000u);
        }
        size_t doff = 16384 + ((size_t)(dst >> 6) << 21) + ((unsigned)(dst & 63) << 8)
                    + ((L * 8) ^ ((dst & 7) << 4));
        uint2 oA, oB;
        oA.x = cvt_pk_bf16(aA0, aA1);
        oA.y = cvt_pk_bf16(aA2, aA3);
        oB.x = cvt_pk_bf16(aB0, aB1);
        oB.y = cvt_pk_bf16(aB2, aB3);
        *(uint2*)(img + baseA + doff) = oA;
        *(uint2*)(img + baseB + doff) = oB;
    }
}

// ======== persistent T-loop: 1 barrier/step, global_load_lds dbuf staging ========
#define STEP10(T, SXC, SXN, SAC, SAN, SSC, SSN) { \
    const int t = (T); \
    float tgtNext = 0.f, mvNext = 0.f; \
    if (tid < 64) { \
        size_t ti = (size_t)(b * TT + t) * NN + n0 + tid; \
        tgtNext = targets[ti]; \
        mvNext = fl ? (((const unsigned char*)maskp)[ti] ? 1.f : 0.f) \
                    : (((const int*)maskp)[ti] ? 1.f : 0.f); \
    } \
    /* issue async staging for t+1 (drained at this step's barrier) */ \
    if (t + 1 < TT) { \
        const char* g = img + tbase + (size_t)(t + 1) * 32768 + (w * 2) * 1024 + l * 16; \
        GLD_LDS16(g,                 (char*)SXN + (w * 2) * 1024); \
        GLD_LDS16(g + 1024,          (char*)SXN + (w * 2 + 1) * 1024); \
        GLD_LDS16(g + 16384,         (char*)SAN + (w * 2) * 1024); \
        GLD_LDS16(g + 16384 + 1024,  (char*)SAN + (w * 2 + 1) * 1024); \
    } \
    f32x4 R[4] = {}, Z[4] = {}, N4[4] = {}, H4[4] = {}; \
    _Pragma("unroll") \
    for (int ks = 0; ks < 4; ++ks) { \
        short8 af[4]; \
        _Pragma("unroll") \
        for (int s4 = 0; s4 < 4; ++s4) \
            af[s4] = *(const short8*)((const char*)SAC + swz(s4 * 16 + lo, ks * 64 + hi * 16)); \
        _Pragma("unroll") \
        for (int s4 = 0; s4 < 4; ++s4) \
            R[s4] = __builtin_amdgcn_mfma_f32_16x16x32_bf16(af[s4], wf[0][ks], R[s4], 0, 0, 0); \
        _Pragma("unroll") \
        for (int s4 = 0; s4 < 4; ++s4) \
            Z[s4] = __builtin_amdgcn_mfma_f32_16x16x32_bf16(af[s4], wf[1][ks], Z[s4], 0, 0, 0); \
        _Pragma("unroll") \
        for (int s4 = 0; s4 < 4; ++s4) \
            N4[s4] = __builtin_amdgcn_mfma_f32_16x16x32_bf16(af[s4], wf[2][ks], N4[s4], 0, 0, 0); \
    } \
    _Pragma("unroll") \
    for (int ks = 0; ks < 4; ++ks) { \
        short8 af[4]; \
        _Pragma("unroll") \
        for (int s4 = 0; s4 < 4; ++s4) \
            af[s4] = *(const short8*)((const char*)SSC + swz(s4 * 16 + lo, ks * 64 + hi * 16)); \
        _Pragma("unroll") \
        for (int s4 = 0; s4 < 4; ++s4) \
            R[s4] = __builtin_amdgcn_mfma_f32_16x16x32_bf16(af[s4], wf[3][ks], R[s4], 0, 0, 0); \
        _Pragma("unroll") \
        for (int s4 = 0; s4 < 4; ++s4) \
            Z[s4] = __builtin_amdgcn_mfma_f32_16x16x32_bf16(af[s4], wf[4][ks], Z[s4], 0, 0, 0); \
        _Pragma("unroll") \
        for (int s4 = 0; s4 < 4; ++s4) \
            N4[s4] = __builtin_amdgcn_mfma_f32_16x16x32_bf16(af[s4], wf[5][ks], N4[s4], 0, 0, 0); \
    } \
    _Pragma("unroll") \
    for (int ks = 0; ks < 4; ++ks) { \
        short8 af[4]; \
        _Pragma("unroll") \
        for (int s4 = 0; s4 < 4; ++s4) \
            af[s4] = *(const short8*)((const char*)SXC + swz(s4 * 16 + lo, ks * 64 + hi * 16)); \
        _Pragma("unroll") \
        for (int s4 = 0; s4 < 4; ++s4) \
            R[s4] = __builtin_amdgcn_mfma_f32_16x16x32_bf16(af[s4], wf[6][ks], R[s4], 0, 0, 0); \
        _Pragma("unroll") \
        for (int s4 = 0; s4 < 4; ++s4) \
            Z[s4] = __builtin_amdgcn_mfma_f32_16x16x32_bf16(af[s4], wf[7][ks], Z[s4], 0, 0, 0); \
        _Pragma("unroll") \
        for (int s4 = 0; s4 < 4; ++s4) \
            H4[s4] = __builtin_amdgcn_mfma_f32_16x16x32_bf16(af[s4], wf[8][ks], H4[s4], 0, 0, 0); \
    } \
    _Pragma("unroll") \
    for (int s4 = 0; s4 < 4; ++s4) \
        _Pragma("unroll") \
        for (int q = 0; q < 4; ++q) { \
            int row = s4 * 16 + hi * 4 + q; \
            float dg = sdeg[row]; \
            float rv = sigm(R[s4][q] + fmaf(dg, gvR, cR)); \
            float zv = sigm(Z[s4][q] + fmaf(dg, gvZ, cZ)); \
            float nv = tanhfast(N4[s4][q] + fmaf(dg, gvN, cN) + rv * (H4[s4][q] + bH)); \
            float xv = bf2f(*(const unsigned short*)((const char*)SXC + swz(row, jcol * 2))); \
            float ns = fmaf(zv, xv - nv, nv); \
            *(unsigned short*)((char*)SSN + swz(row, jcol * 2)) = bf16s(ns); \
        } \
    __syncthreads();   /* ONE barrier: drains gld_lds(t+1); publishes SSN */ \
    if (w < 4) { \
        f32x4 acc = {}; \
        _Pragma("unroll") \
        for (int ks = 0; ks < 4; ++ks) { \
            short8 af = *(const short8*)((const char*)SSN + swz(w * 16 + lo, ks * 64 + hi * 16)); \
            short8 bw = *(const short8*)(WroP + (size_t)(ks * 64 + l) * 8); \
            acc = __builtin_amdgcn_mfma_f32_16x16x32_bf16(af, bw, acc, 0, 0, 0); \
        } \
        if (lo == 0) { \
            _Pragma("unroll") \
            for (int q = 0; q < 4; ++q) \
                pOut[t & 1][w * 16 + hi * 4 + q] = acc[q]; \
        } \
    } \
    if (tid < 64 && t > 0) { \
        float out = pOut[(t & 1) ^ 1][tid] + bro; \
        float d = out - tgtCur; \
        lossAcc += 0.5f * d * d * mvCur; \
    } \
    tgtCur = tgtNext; mvCur = mvNext; \
}

__global__ __launch_bounds__(512, 2)
void mega10_kernel(const char* __restrict__ img,
                   const short* __restrict__ Gp, const short* __restrict__ WroP,
                   const float* __restrict__ degf,
                   const float* __restrict__ gvec, const float* __restrict__ cvec,
                   const float* __restrict__ b_hh, const float* __restrict__ b_ro,
                   const float* __restrict__ targets, const void* __restrict__ maskp,
                   const int* __restrict__ flag,
                   float* __restrict__ lossBlock)
{
    __shared__ char sX0[16384];
    __shared__ char sX1[16384];
    __shared__ char sA0[16384];
    __shared__ char sA1[16384];
    __shared__ char sS0[16384];
    __shared__ char sS1[16384];
    __shared__ float sdeg[64];
    __shared__ float pOut[2][64];
    __shared__ float pLoss[8];

    const int tid = threadIdx.x;
    const int w = tid >> 6, l = tid & 63, lo = l & 15, hi = l >> 4;
    const int nt = w;
    const int phys = blockIdx.x;
    const int b = phys >> 6;
    const int n0 = (phys & 63) * 64;
    const size_t tbase = (size_t)phys * TT * 32768;

    // ---- 36 weight fragments in registers ----
    short8 wf[9][4];
    #pragma unroll
    for (int m = 0; m < 9; ++m)
        #pragma unroll
        for (int ks = 0; ks < 4; ++ks)
            wf[m][ks] = *(const short8*)(Gp + (size_t)(((m * 8 + nt) * 4 + ks) * 64 + l) * 8);

    const int jcol = nt * 16 + lo;
    const float gvR = gvec[jcol], gvZ = gvec[128 + jcol], gvN = gvec[256 + jcol];
    const float cR = cvec[jcol], cZ = cvec[128 + jcol], cN = cvec[256 + jcol];
    const float bH = b_hh[256 + jcol];
    const float bro = b_ro[0];
    const int fl = *flag;

    // ---- prologue: async-stage t=0, zero state ----
    {
        const char* g = img + tbase + (w * 2) * 1024 + l * 16;
        GLD_LDS16(g,                sX0 + (w * 2) * 1024);
        GLD_LDS16(g + 1024,         sX0 + (w * 2 + 1) * 1024);
        GLD_LDS16(g + 16384,        sA0 + (w * 2) * 1024);
        GLD_LDS16(g + 16384 + 1024, sA0 + (w * 2 + 1) * 1024);
    }
    #pragma unroll
    for (int it = 0; it < 8; ++it) ((unsigned*)sS0)[tid + it * 512] = 0u;
    if (tid < 64) sdeg[tid] = degf[n0 + tid];
    float tgtCur = 0.f, mvCur = 0.f, lossAcc = 0.f;
    __syncthreads();   // drains prologue staging

    for (int tt = 0; tt < TT; tt += 2) {
        STEP10(tt,     sX0, sX1, sA0, sA1, sS0, sS1)
        STEP10(tt + 1, sX1, sX0, sA1, sA0, sS1, sS0)
    }

    __syncthreads();   // pOut[1] (t=63) visible to wave 0
    if (tid < 64) {
        float out = pOut[1][tid] + bro;
        float d = out - tgtCur;
        lossAcc += 0.5f * d * d * mvCur;
    }

    float v = lossAcc;
    #pragma unroll
    for (int o = 1; o < 64; o <<= 1) v += __shfl_xor(v, o);
    if (l == 0) pLoss[w] = v;
    __syncthreads();
    if (tid == 0) {
        float s = 0.f;
        #pragma unroll
        for (int ww = 0; ww < 8; ++ww) s += pLoss[ww];
        lossBlock[phys] = s;
    }
}

// ================= CSR build =================
__global__ void count_kernel(const int* __restrict__ dst, int* __restrict__ counts)
{
    int e = blockIdx.x * 256 + threadIdx.x;
    if (e < EE) atomicAdd(&counts[dst[e]], 1);
}

__global__ __launch_bounds__(1024)
void scan_kernel(const int* __restrict__ counts, int* __restrict__ off, int* __restrict__ cursor,
                 float* __restrict__ degf)
{
    __shared__ int s[1024];
    int tid = threadIdx.x;
    int base = tid * 4;
    int c[4]; int sum = 0;
    #pragma unroll
    for (int i = 0; i < 4; ++i) { c[i] = counts[base + i]; sum += c[i]; }
    s[tid] = sum; __syncthreads();
    for (int o = 1; o < 1024; o <<= 1) {
        int v = (tid >= o) ? s[tid - o] : 0;
        __syncthreads();
        s[tid] += v;
        __syncthreads();
    }
    int incl = s[tid];
    int run = incl - sum;
    #pragma unroll
    for (int i = 0; i < 4; ++i) {
        off[base + i] = run; cursor[base + i] = run;
        degf[base + i] = (float)c[i];
        run += c[i];
    }
    if (tid == 1023) off[4096] = incl;
}

__global__ void fill_kernel(const int* __restrict__ src, const int* __restrict__ dst,
                            int* __restrict__ cursor, int* __restrict__ csr_src)
{
    int e = blockIdx.x * 256 + threadIdx.x;
    if (e < EE) {
        int d = dst[e];
        int pos = atomicAdd(&cursor[d], 1);
        csr_src[pos] = src[e];
    }
}

// ================= mask detect / masked count =================
__global__ void detect_kernel(const unsigned char* __restrict__ maskb, int* __restrict__ flag)
{
    int i = blockIdx.x * 256 + threadIdx.x;
    bool hit = (i < BB * TT * NN) && (i & 3) && maskb[i];
    if (__any(hit) && (threadIdx.x & 63) == 0) atomicOr(flag, 1);
}

__global__ void masksum_kernel(const void* __restrict__ maskp, const int* __restrict__ flag,
                               float* __restrict__ den)
{
    int i = blockIdx.x * 256 + threadIdx.x;
    float v = 0.f;
    if (i < BB * TT * NN) {
        if (*flag) v = ((const unsigned char*)maskp)[i] ? 1.f : 0.f;
        else       v = ((const int*)maskp)[i] ? 1.f : 0.f;
    }
    #pragma unroll
    for (int o = 32; o > 0; o >>= 1) v += __shfl_down(v, o);
    __shared__ float sm[4];
    if ((threadIdx.x & 63) == 0) sm[threadIdx.x >> 6] = v;
    __syncthreads();
    if (threadIdx.x == 0) atomicAdd(den, sm[0] + sm[1] + sm[2] + sm[3]);
}

// ================= final reduce + dual-dtype output =================
__global__ __launch_bounds__(256)
void final_kernel(const float* __restrict__ lossBlock, const float* __restrict__ den,
                  unsigned* __restrict__ out)
{
    __shared__ float s[256];
    s[threadIdx.x] = lossBlock[threadIdx.x];
    __syncthreads();
    for (int o = 128; o > 0; o >>= 1) {
        if (threadIdx.x < o) s[threadIdx.x] += s[threadIdx.x + o];
        __syncthreads();
    }
    if (threadIdx.x == 0) {
        float L = s[0] / den[0];
        unsigned u = __float_as_uint(L);
        u += 0x7fffu + ((u >> 16) & 1u);
        unsigned hi = u >> 16;
        out[0] = hi * 0x10001u;   // bf16-exact low half; ~bf16 value as f32
    }
}

extern "C" void kernel_launch(void* const* d_in, const int* in_sizes, int n_in,
                              void* d_out, int out_size, void* d_ws, size_t ws_size,
                              hipStream_t stream)
{
    const float* x       = (const float*)d_in[0];
    const float* targets = (const float*)d_in[1];
    const float* W_msg   = (const float*)d_in[2];
    const float* b_msg   = (const float*)d_in[3];
    const float* W_mix   = (const float*)d_in[4];
    const float* b_mix   = (const float*)d_in[5];
    const float* W_ih    = (const float*)d_in[6];
    const float* b_ih    = (const float*)d_in[7];
    const float* W_hh    = (const float*)d_in[8];
    const float* b_hh    = (const float*)d_in[9];
    const float* W_ro    = (const float*)d_in[10];
    const float* b_ro    = (const float*)d_in[11];
    const void*  maskp   = d_in[12];
    const int*   esrc    = (const int*)d_in[13];
    const int*   edst    = (const int*)d_in[14];

    char* ws = (char*)d_ws;
    char* img = ws; ws += (size_t)256 * TT * 32768;   // 512 MB interleaved x/agg tile stream
    short* Gp          = (short*)ws; ws += (size_t)18432 * 8 * 2;
    short* WroP        = (short*)ws; ws += (size_t)256 * 8 * 2;
    float* Wc_f32      = (float*)ws; ws += 16384 * 4;
    float* bvec        = (float*)ws; ws += 128 * 4;
    float* gvec        = (float*)ws; ws += 384 * 4;
    float* cvec        = (float*)ws; ws += 384 * 4;
    float* degf        = (float*)ws; ws += 4096 * 4;
    float* lossBlock   = (float*)ws; ws += 256 * 4;
    int*   csr_off     = (int*)ws;   ws += 4104 * 4;
    int*   cursor      = (int*)ws;   ws += 4096 * 4;
    int*   counts      = (int*)ws;   ws += 4096 * 4;
    int*   csr_src     = (int*)ws;   ws += (size_t)EE * 4;
    int*   flag        = (int*)ws;   ws += 64;
    float* den         = (float*)ws; ws += 64;

    hipMemsetAsync(counts, 0, 4096 * 4, stream);
    hipMemsetAsync(flag, 0, 64, stream);
    hipMemsetAsync(den, 0, 4, stream);

    detect_kernel   <<<4096, 256, 0, stream>>>((const unsigned char*)maskp, flag);
    masksum_kernel  <<<4096, 256, 0, stream>>>(maskp, flag, den);
    count_kernel    <<<EE / 256, 256, 0, stream>>>(edst, counts);
    scan_kernel     <<<1, 1024, 0, stream>>>(counts, csr_off, cursor, degf);
    fill_kernel     <<<EE / 256, 256, 0, stream>>>(esrc, edst, cursor, csr_src);
    pack_wc_kernel  <<<64, 256, 0, stream>>>(W_msg, W_mix, Wc_f32);
    pack_bvec_kernel<<<1, 128, 0, stream>>>(b_msg, W_mix, bvec);
    pack_gbias_kernel<<<1, 384, 0, stream>>>(bvec, b_mix, W_ih, b_ih, b_hh, gvec, cvec);
    pack_G_kernel   <<<72, 256, 0, stream>>>(Wc_f32, W_mix, W_ih, W_hh, Gp);
    pack_wro_kernel <<<1, 256, 0, stream>>>(W_ro, WroP);

    cvt_img_kernel  <<<16384, 256, 0, stream>>>(x, img);
    gather_quad_kernel<<<16384, 256, 0, stream>>>(img, csr_off, csr_src);

    mega10_kernel<<<256, 512, 0, stream>>>(img, Gp, WroP, degf, gvec, cvec, b_hh, b_ro,
                                           targets, maskp, flag, lossBlock);
    final_kernel<<<1, 256, 0, stream>>>(lossBlock, den, (unsigned*)d_out);
}

// Round 17
// 1214.331 us; speedup vs baseline: 1.8192x; 1.0391x over previous
//
#include <hip/hip_runtime.h>
#include <hip/hip_bf16.h>
#include <stdint.h>

#define BB 4
#define TT 64
#define NN 4096
#define HH 128
#define EE 65536
#define BN (BB*NN)   // 16384

typedef __attribute__((ext_vector_type(8))) short short8;
typedef __attribute__((ext_vector_type(4))) float f32x4;

__device__ __forceinline__ unsigned short bf16r(float f) {
    unsigned u = __float_as_uint(f);
    u += 0x7fffu + ((u >> 16) & 1u);
    return (unsigned short)(u >> 16);
}
__device__ __forceinline__ unsigned cvt_pk_bf16(float lo_, float hi_) {
    unsigned r;
    asm("v_cvt_pk_bf16_f32 %0, %1, %2" : "=v"(r) : "v"(lo_), "v"(hi_));
    return r;
}
__device__ __forceinline__ unsigned short bf16s(float f) {
    unsigned r;
    asm("v_cvt_pk_bf16_f32 %0, %1, %1" : "=v"(r) : "v"(f));
    return (unsigned short)r;
}
__device__ __forceinline__ float bf2f(unsigned bits16) {
    return __uint_as_float(bits16 << 16);
}
__device__ __forceinline__ float sigm(float x) { return 1.f / (1.f + __expf(-x)); }
__device__ __forceinline__ float tanhfast(float x) {
    return 1.f - 2.f / (__expf(2.f * x) + 1.f);
}
// byte address within a [64][128]-bf16 tile; 4-bit XOR swizzle -> 4-way floor on b128 frag reads
__device__ __forceinline__ unsigned swz(int row, int colbyte) {
    return (unsigned)(row * 256 + (colbyte ^ ((row & 15) << 4)));
}

#define GLD_LDS16(g, s) __builtin_amdgcn_global_load_lds( \
    (const __attribute__((address_space(1))) void*)(g), \
    (__attribute__((address_space(3))) void*)(s), 16, 0, 0)

// ================= packs =================
__global__ void pack_wc_kernel(const float* __restrict__ W_msg, const float* __restrict__ W_mix,
                               float* __restrict__ Wc)
{
    int idx = blockIdx.x * 256 + threadIdx.x;   // 16384
    int k = idx >> 7, j = idx & 127;
    float s = 0.f;
    for (int i = 0; i < 128; ++i) s += W_msg[k * 128 + i] * W_mix[i * 128 + j];
    Wc[idx] = s;
}

__global__ void pack_bvec_kernel(const float* __restrict__ b_msg, const float* __restrict__ W_mix,
                                 float* __restrict__ bvec)
{
    int j = threadIdx.x;   // 128
    float s = 0.f;
    for (int i = 0; i < 128; ++i) s += b_msg[i] * W_mix[i * 128 + j];
    bvec[j] = s;
}

__global__ void pack_gbias_kernel(const float* __restrict__ bvec, const float* __restrict__ b_mix,
                                  const float* __restrict__ W_ih, const float* __restrict__ b_ih,
                                  const float* __restrict__ b_hh,
                                  float* __restrict__ gvec, float* __restrict__ cvec)
{
    int c = threadIdx.x;   // 384
    float g = 0.f, gb = 0.f;
    for (int j = 0; j < 128; ++j) {
        g  += bvec[j]  * W_ih[j * 384 + c];
        gb += b_mix[j] * W_ih[j * 384 + c];
    }
    gvec[c] = g;
    cvec[c] = gb + b_ih[c] + (c < 256 ? b_hh[c] : 0.f);
}

// Gp[mat(9)][nt(8)][ks(4)][lane(64)][8]
__global__ void pack_G_kernel(const float* __restrict__ Wc, const float* __restrict__ W_mix,
                              const float* __restrict__ W_ih, const float* __restrict__ W_hh,
                              short* __restrict__ Gp)
{
    int idx = blockIdx.x * 256 + threadIdx.x;   // 18432
    if (idx >= 18432) return;
    int l = idx & 63, ks = (idx >> 6) & 3, nt = (idx >> 8) & 7, mat = idx >> 11;
    int lo = l & 15, hi = l >> 4;
    int col = nt * 16 + lo;
    short8 v;
    #pragma unroll
    for (int i = 0; i < 8; ++i) {
        int k = ks * 32 + hi * 8 + i;
        float s;
        if (mat < 3) {
            int c = mat * 128 + col;
            s = 0.f;
            for (int j = 0; j < 128; ++j) s += Wc[k * 128 + j] * W_ih[j * 384 + c];
        } else if (mat < 6) {
            int c = (mat - 3) * 128 + col;
            s = 0.f;
            for (int j = 0; j < 128; ++j) s += W_mix[(128 + k) * 128 + j] * W_ih[j * 384 + c];
        } else {
            int c = (mat - 6) * 128 + col;
            s = W_hh[k * 384 + c];
        }
        v[i] = (short)bf16r(s);
    }
    *(short8*)(Gp + (size_t)idx * 8) = v;
}

// W_roP: [ks(4)][lane(64)][8]; only col 0 nonzero = W_ro[k]
__global__ void pack_wro_kernel(const float* __restrict__ W_ro, short* __restrict__ out)
{
    int idx = threadIdx.x;      // 256
    int l = idx & 63, ks = idx >> 6;
    int lo = l & 15, hi = l >> 4;
    short8 v;
    #pragma unroll
    for (int i = 0; i < 8; ++i) {
        int k = ks * 32 + hi * 8 + i;
        v[i] = (lo == 0) ? (short)bf16r(W_ro[k]) : (short)0;
    }
    *(short8*)(out + (size_t)idx * 8) = v;
}

// ================= x -> pre-swizzled bf16 x-tiles inside img =================
__global__ __launch_bounds__(256)
void cvt_img_kernel(const float* __restrict__ x, char* __restrict__ img)
{
    int tileid = blockIdx.x;              // phys*64 + t  (16384)
    int phys = tileid >> 6, t = tileid & 63;
    int b = phys >> 6, n0 = (phys & 63) * 64;
    const float* __restrict__ src = x + ((size_t)(b * TT + t) * NN + n0) * HH;
    char* __restrict__ dst = img + (size_t)tileid * 32768;
    int tid = threadIdx.x;
    #pragma unroll
    for (int u4 = 0; u4 < 4; ++u4) {
        int unit = tid + u4 * 256;          // 1024 units of 16B
        int row = unit >> 4, g = unit & 15;
        const float* sp = src + row * HH + g * 8;
        float4 v0 = *(const float4*)sp;
        float4 v1 = *(const float4*)(sp + 4);
        uint4 o;
        o.x = cvt_pk_bf16(v0.x, v0.y);
        o.y = cvt_pk_bf16(v0.z, v0.w);
        o.z = cvt_pk_bf16(v1.x, v1.y);
        o.w = cvt_pk_bf16(v1.z, v1.w);
        *(uint4*)(dst + swz(row, g * 16)) = o;
    }
}

// ================= gather: 4 bts/block, 4-edge unroll, edge addr computed once =====
__global__ __launch_bounds__(256)
void gather_quad_kernel(char* __restrict__ img,
                        const int* __restrict__ off, const int* __restrict__ srcs)
{
    int bid = blockIdx.x;               // 16384
    int xcd = bid & 7;
    int rest = bid >> 3;                // 0..2047
    int grp = rest >> 8;                // 0..7
    int chunk = rest & 255;             // 0..255
    int w = threadIdx.x >> 6, l = threadIdx.x & 63;
    int half = l >> 5, L = l & 31;
    size_t baseA, baseB;
    {
        int btA = (grp * 4 + half * 2 + 0) * 8 + xcd;
        int btB = (grp * 4 + half * 2 + 1) * 8 + xcd;
        baseA = ((size_t)(btA >> 6) * 4096 + (btA & 63)) * 32768;
        baseB = ((size_t)(btB >> 6) * 4096 + (btB & 63)) * 32768;
    }

    #pragma unroll
    for (int r = 0; r < 4; ++r) {
        int dst = chunk * 16 + w * 4 + r;
        int s = off[dst], e = off[dst + 1];
        float aA0 = 0.f, aA1 = 0.f, aA2 = 0.f, aA3 = 0.f;
        float aB0 = 0.f, aB1 = 0.f, aB2 = 0.f, aB3 = 0.f;
        int i = s;
        for (; i + 3 < e; i += 4) {
            int s0 = srcs[i], s1 = srcs[i + 1], s2 = srcs[i + 2], s3 = srcs[i + 3];
            size_t t0 = ((size_t)(s0 >> 6) << 21) + ((unsigned)(s0 & 63) << 8)
                      + ((L * 8) ^ ((s0 & 15) << 4));
            size_t t1 = ((size_t)(s1 >> 6) << 21) + ((unsigned)(s1 & 63) << 8)
                      + ((L * 8) ^ ((s1 & 15) << 4));
            size_t t2 = ((size_t)(s2 >> 6) << 21) + ((unsigned)(s2 & 63) << 8)
                      + ((L * 8) ^ ((s2 & 15) << 4));
            size_t t3 = ((size_t)(s3 >> 6) << 21) + ((unsigned)(s3 & 63) << 8)
                      + ((L * 8) ^ ((s3 & 15) << 4));
            uint2 vA0 = *(const uint2*)(img + baseA + t0);
            uint2 vB0 = *(const uint2*)(img + baseB + t0);
            uint2 vA1 = *(const uint2*)(img + baseA + t1);
            uint2 vB1 = *(const uint2*)(img + baseB + t1);
            uint2 vA2 = *(const uint2*)(img + baseA + t2);
            uint2 vB2 = *(const uint2*)(img + baseB + t2);
            uint2 vA3 = *(const uint2*)(img + baseA + t3);
            uint2 vB3 = *(const uint2*)(img + baseB + t3);
            aA0 += (__uint_as_float(vA0.x << 16) + __uint_as_float(vA1.x << 16))
                 + (__uint_as_float(vA2.x << 16) + __uint_as_float(vA3.x << 16));
            aA1 += (__uint_as_float(vA0.x & 0xffff0000u) + __uint_as_float(vA1.x & 0xffff0000u))
                 + (__uint_as_float(vA2.x & 0xffff0000u) + __uint_as_float(vA3.x & 0xffff0000u));
            aA2 += (__uint_as_float(vA0.y << 16) + __uint_as_float(vA1.y << 16))
                 + (__uint_as_float(vA2.y << 16) + __uint_as_float(vA3.y << 16));
            aA3 += (__uint_as_float(vA0.y & 0xffff0000u) + __uint_as_float(vA1.y & 0xffff0000u))
                 + (__uint_as_float(vA2.y & 0xffff0000u) + __uint_as_float(vA3.y & 0xffff0000u));
            aB0 += (__uint_as_float(vB0.x << 16) + __uint_as_float(vB1.x << 16))
                 + (__uint_as_float(vB2.x << 16) + __uint_as_float(vB3.x << 16));
            aB1 += (__uint_as_float(vB0.x & 0xffff0000u) + __uint_as_float(vB1.x & 0xffff0000u))
                 + (__uint_as_float(vB2.x & 0xffff0000u) + __uint_as_float(vB3.x & 0xffff0000u));
            aB2 += (__uint_as_float(vB0.y << 16) + __uint_as_float(vB1.y << 16))
                 + (__uint_as_float(vB2.y << 16) + __uint_as_float(vB3.y << 16));
            aB3 += (__uint_as_float(vB0.y & 0xffff0000u) + __uint_as_float(vB1.y & 0xffff0000u))
                 + (__uint_as_float(vB2.y & 0xffff0000u) + __uint_as_float(vB3.y & 0xffff0000u));
        }
        for (; i < e; ++i) {
            int s0 = srcs[i];
            size_t t0 = ((size_t)(s0 >> 6) << 21) + ((unsigned)(s0 & 63) << 8)
                      + ((L * 8) ^ ((s0 & 15) << 4));
            uint2 vA0 = *(const uint2*)(img + baseA + t0);
            uint2 vB0 = *(const uint2*)(img + baseB + t0);
            aA0 += __uint_as_float(vA0.x << 16);
            aA1 += __uint_as_float(vA0.x & 0xffff0000u);
            aA2 += __uint_as_float(vA0.y << 16);
            aA3 += __uint_as_float(vA0.y & 0xffff0000u);
            aB0 += __uint_as_float(vB0.x << 16);
            aB1 += __uint_as_float(vB0.x & 0xffff0000u);
            aB2 += __uint_as_float(vB0.y << 16);
            aB3 += __uint_as_float(vB0.y & 0xffff0000u);
        }
        size_t doff = 16384 + ((size_t)(dst >> 6) << 21) + ((unsigned)(dst & 63) << 8)
                    + ((L * 8) ^ ((dst & 15) << 4));
        uint2 oA, oB;
        oA.x = cvt_pk_bf16(aA0, aA1);
        oA.y = cvt_pk_bf16(aA2, aA3);
        oB.x = cvt_pk_bf16(aB0, aB1);
        oB.y = cvt_pk_bf16(aB2, aB3);
        *(uint2*)(img + baseA + doff) = oA;
        *(uint2*)(img + baseB + doff) = oB;
    }
}

// ======== persistent T-loop: 1 barrier/step, gld_lds dbuf staging, 8-wave GEMV ========
#define STEP10(T, SXC, SXN, SAC, SAN, SSC, SSN) { \
    const int t = (T); \
    float tgtNext = 0.f, mvNext = 0.f; \
    if (tid < 64) { \
        size_t ti = (size_t)(b * TT + t) * NN + n0 + tid; \
        tgtNext = targets[ti]; \
        mvNext = fl ? (((const unsigned char*)maskp)[ti] ? 1.f : 0.f) \
                    : (((const int*)maskp)[ti] ? 1.f : 0.f); \
    } \
    if (t + 1 < TT) { \
        const char* g = img + tbase + (size_t)(t + 1) * 32768 + (w * 2) * 1024 + l * 16; \
        GLD_LDS16(g,                 (char*)SXN + (w * 2) * 1024); \
        GLD_LDS16(g + 1024,          (char*)SXN + (w * 2 + 1) * 1024); \
        GLD_LDS16(g + 16384,         (char*)SAN + (w * 2) * 1024); \
        GLD_LDS16(g + 16384 + 1024,  (char*)SAN + (w * 2 + 1) * 1024); \
    } \
    f32x4 R[4] = {}, Z[4] = {}, N4[4] = {}, H4[4] = {}; \
    _Pragma("unroll") \
    for (int ks = 0; ks < 4; ++ks) { \
        short8 af[4]; \
        _Pragma("unroll") \
        for (int s4 = 0; s4 < 4; ++s4) \
            af[s4] = *(const short8*)((const char*)SAC + swz(s4 * 16 + lo, ks * 64 + hi * 16)); \
        _Pragma("unroll") \
        for (int s4 = 0; s4 < 4; ++s4) \
            R[s4] = __builtin_amdgcn_mfma_f32_16x16x32_bf16(af[s4], wf[0][ks], R[s4], 0, 0, 0); \
        _Pragma("unroll") \
        for (int s4 = 0; s4 < 4; ++s4) \
            Z[s4] = __builtin_amdgcn_mfma_f32_16x16x32_bf16(af[s4], wf[1][ks], Z[s4], 0, 0, 0); \
        _Pragma("unroll") \
        for (int s4 = 0; s4 < 4; ++s4) \
            N4[s4] = __builtin_amdgcn_mfma_f32_16x16x32_bf16(af[s4], wf[2][ks], N4[s4], 0, 0, 0); \
    } \
    _Pragma("unroll") \
    for (int ks = 0; ks < 4; ++ks) { \
        short8 af[4]; \
        _Pragma("unroll") \
        for (int s4 = 0; s4 < 4; ++s4) \
            af[s4] = *(const short8*)((const char*)SSC + swz(s4 * 16 + lo, ks * 64 + hi * 16)); \
        _Pragma("unroll") \
        for (int s4 = 0; s4 < 4; ++s4) \
            R[s4] = __builtin_amdgcn_mfma_f32_16x16x32_bf16(af[s4], wf[3][ks], R[s4], 0, 0, 0); \
        _Pragma("unroll") \
        for (int s4 = 0; s4 < 4; ++s4) \
            Z[s4] = __builtin_amdgcn_mfma_f32_16x16x32_bf16(af[s4], wf[4][ks], Z[s4], 0, 0, 0); \
        _Pragma("unroll") \
        for (int s4 = 0; s4 < 4; ++s4) \
            N4[s4] = __builtin_amdgcn_mfma_f32_16x16x32_bf16(af[s4], wf[5][ks], N4[s4], 0, 0, 0); \
    } \
    _Pragma("unroll") \
    for (int ks = 0; ks < 4; ++ks) { \
        short8 af[4]; \
        _Pragma("unroll") \
        for (int s4 = 0; s4 < 4; ++s4) \
            af[s4] = *(const short8*)((const char*)SXC + swz(s4 * 16 + lo, ks * 64 + hi * 16)); \
        _Pragma("unroll") \
        for (int s4 = 0; s4 < 4; ++s4) \
            R[s4] = __builtin_amdgcn_mfma_f32_16x16x32_bf16(af[s4], wf[6][ks], R[s4], 0, 0, 0); \
        _Pragma("unroll") \
        for (int s4 = 0; s4 < 4; ++s4) \
            Z[s4] = __builtin_amdgcn_mfma_f32_16x16x32_bf16(af[s4], wf[7][ks], Z[s4], 0, 0, 0); \
        _Pragma("unroll") \
        for (int s4 = 0; s4 < 4; ++s4) \
            H4[s4] = __builtin_amdgcn_mfma_f32_16x16x32_bf16(af[s4], wf[8][ks], H4[s4], 0, 0, 0); \
    } \
    _Pragma("unroll") \
    for (int s4 = 0; s4 < 4; ++s4) \
        _Pragma("unroll") \
        for (int q = 0; q < 4; ++q) { \
            int row = s4 * 16 + hi * 4 + q; \
            float dg = sdeg[row]; \
            float rv = sigm(R[s4][q] + fmaf(dg, gvR, cR)); \
            float zv = sigm(Z[s4][q] + fmaf(dg, gvZ, cZ)); \
            float nv = tanhfast(N4[s4][q] + fmaf(dg, gvN, cN) + rv * (H4[s4][q] + bH)); \
            float xv = bf2f(*(const unsigned short*)((const char*)SXC + swz(row, jcol * 2))); \
            float ns = fmaf(zv, xv - nv, nv); \
            *(unsigned short*)((char*)SSN + swz(row, jcol * 2)) = bf16s(ns); \
        } \
    __syncthreads();   /* ONE barrier: drains gld_lds(t+1); publishes SSN */ \
    { \
        const int band = w & 3, khalf = w >> 2; \
        f32x4 acc = {}; \
        _Pragma("unroll") \
        for (int kk = 0; kk < 2; ++kk) { \
            int ks = khalf * 2 + kk; \
            short8 af = *(const short8*)((const char*)SSN + swz(band * 16 + lo, ks * 64 + hi * 16)); \
            short8 bw = *(const short8*)(WroP + (size_t)(ks * 64 + l) * 8); \
            acc = __builtin_amdgcn_mfma_f32_16x16x32_bf16(af, bw, acc, 0, 0, 0); \
        } \
        if (lo == 0) { \
            _Pragma("unroll") \
            for (int q = 0; q < 4; ++q) \
                pOut[t & 1][khalf][band * 16 + hi * 4 + q] = acc[q]; \
        } \
    } \
    if (tid < 64 && t > 0) { \
        float out = pOut[(t & 1) ^ 1][0][tid] + pOut[(t & 1) ^ 1][1][tid] + bro; \
        float d = out - tgtCur; \
        lossAcc += 0.5f * d * d * mvCur; \
    } \
    tgtCur = tgtNext; mvCur = mvNext; \
}

__global__ __launch_bounds__(512, 2)
void mega10_kernel(const char* __restrict__ img,
                   const short* __restrict__ Gp, const short* __restrict__ WroP,
                   const float* __restrict__ degf,
                   const float* __restrict__ gvec, const float* __restrict__ cvec,
                   const float* __restrict__ b_hh, const float* __restrict__ b_ro,
                   const float* __restrict__ targets, const void* __restrict__ maskp,
                   const int* __restrict__ flag,
                   float* __restrict__ lossBlock)
{
    __shared__ char sX0[16384];
    __shared__ char sX1[16384];
    __shared__ char sA0[16384];
    __shared__ char sA1[16384];
    __shared__ char sS0[16384];
    __shared__ char sS1[16384];
    __shared__ float sdeg[64];
    __shared__ float pOut[2][2][64];
    __shared__ float pLoss[8];

    const int tid = threadIdx.x;
    const int w = tid >> 6, l = tid & 63, lo = l & 15, hi = l >> 4;
    const int nt = w;
    const int phys = blockIdx.x;
    const int b = phys >> 6;
    const int n0 = (phys & 63) * 64;
    const size_t tbase = (size_t)phys * TT * 32768;

    // ---- 36 weight fragments in registers ----
    short8 wf[9][4];
    #pragma unroll
    for (int m = 0; m < 9; ++m)
        #pragma unroll
        for (int ks = 0; ks < 4; ++ks)
            wf[m][ks] = *(const short8*)(Gp + (size_t)(((m * 8 + nt) * 4 + ks) * 64 + l) * 8);

    const int jcol = nt * 16 + lo;
    const float gvR = gvec[jcol], gvZ = gvec[128 + jcol], gvN = gvec[256 + jcol];
    const float cR = cvec[jcol], cZ = cvec[128 + jcol], cN = cvec[256 + jcol];
    const float bH = b_hh[256 + jcol];
    const float bro = b_ro[0];
    const int fl = *flag;

    // ---- prologue: async-stage t=0, zero state ----
    {
        const char* g = img + tbase + (w * 2) * 1024 + l * 16;
        GLD_LDS16(g,                sX0 + (w * 2) * 1024);
        GLD_LDS16(g + 1024,         sX0 + (w * 2 + 1) * 1024);
        GLD_LDS16(g + 16384,        sA0 + (w * 2) * 1024);
        GLD_LDS16(g + 16384 + 1024, sA0 + (w * 2 + 1) * 1024);
    }
    #pragma unroll
    for (int it = 0; it < 8; ++it) ((unsigned*)sS0)[tid + it * 512] = 0u;
    if (tid < 64) sdeg[tid] = degf[n0 + tid];
    float tgtCur = 0.f, mvCur = 0.f, lossAcc = 0.f;
    __syncthreads();   // drains prologue staging

    for (int tt = 0; tt < TT; tt += 2) {
        STEP10(tt,     sX0, sX1, sA0, sA1, sS0, sS1)
        STEP10(tt + 1, sX1, sX0, sA1, sA0, sS1, sS0)
    }

    __syncthreads();   // pOut[1] (t=63) visible to wave 0
    if (tid < 64) {
        float out = pOut[1][0][tid] + pOut[1][1][tid] + bro;
        float d = out - tgtCur;
        lossAcc += 0.5f * d * d * mvCur;
    }

    float v = lossAcc;
    #pragma unroll
    for (int o = 1; o < 64; o <<= 1) v += __shfl_xor(v, o);
    if (l == 0) pLoss[w] = v;
    __syncthreads();
    if (tid == 0) {
        float s = 0.f;
        #pragma unroll
        for (int ww = 0; ww < 8; ++ww) s += pLoss[ww];
        lossBlock[phys] = s;
    }
}

// ================= CSR build =================
__global__ void count_kernel(const int* __restrict__ dst, int* __restrict__ counts)
{
    int e = blockIdx.x * 256 + threadIdx.x;
    if (e < EE) atomicAdd(&counts[dst[e]], 1);
}

__global__ __launch_bounds__(1024)
void scan_kernel(const int* __restrict__ counts, int* __restrict__ off, int* __restrict__ cursor,
                 float* __restrict__ degf)
{
    __shared__ int s[1024];
    int tid = threadIdx.x;
    int base = tid * 4;
    int c[4]; int sum = 0;
    #pragma unroll
    for (int i = 0; i < 4; ++i) { c[i] = counts[base + i]; sum += c[i]; }
    s[tid] = sum; __syncthreads();
    for (int o = 1; o < 1024; o <<= 1) {
        int v = (tid >= o) ? s[tid - o] : 0;
        __syncthreads();
        s[tid] += v;
        __syncthreads();
    }
    int incl = s[tid];
    int run = incl - sum;
    #pragma unroll
    for (int i = 0; i < 4; ++i) {
        off[base + i] = run; cursor[base + i] = run;
        degf[base + i] = (float)c[i];
        run += c[i];
    }
    if (tid == 1023) off[4096] = incl;
}

__global__ void fill_kernel(const int* __restrict__ src, const int* __restrict__ dst,
                            int* __restrict__ cursor, int* __restrict__ csr_src)
{
    int e = blockIdx.x * 256 + threadIdx.x;
    if (e < EE) {
        int d = dst[e];
        int pos = atomicAdd(&cursor[d], 1);
        csr_src[pos] = src[e];
    }
}

// ================= mask detect / masked count =================
__global__ void detect_kernel(const unsigned char* __restrict__ maskb, int* __restrict__ flag)
{
    int i = blockIdx.x * 256 + threadIdx.x;
    bool hit = (i < BB * TT * NN) && (i & 3) && maskb[i];
    if (__any(hit) && (threadIdx.x & 63) == 0) atomicOr(flag, 1);
}

__global__ void masksum_kernel(const void* __restrict__ maskp, const int* __restrict__ flag,
                               float* __restrict__ den)
{
    int i = blockIdx.x * 256 + threadIdx.x;
    float v = 0.f;
    if (i < BB * TT * NN) {
        if (*flag) v = ((const unsigned char*)maskp)[i] ? 1.f : 0.f;
        else       v = ((const int*)maskp)[i] ? 1.f : 0.f;
    }
    #pragma unroll
    for (int o = 32; o > 0; o >>= 1) v += __shfl_down(v, o);
    __shared__ float sm[4];
    if ((threadIdx.x & 63) == 0) sm[threadIdx.x >> 6] = v;
    __syncthreads();
    if (threadIdx.x == 0) atomicAdd(den, sm[0] + sm[1] + sm[2] + sm[3]);
}

// ================= final reduce + dual-dtype output =================
__global__ __launch_bounds__(256)
void final_kernel(const float* __restrict__ lossBlock, const float* __restrict__ den,
                  unsigned* __restrict__ out)
{
    __shared__ float s[256];
    s[threadIdx.x] = lossBlock[threadIdx.x];
    __syncthreads();
    for (int o = 128; o > 0; o >>= 1) {
        if (threadIdx.x < o) s[threadIdx.x] += s[threadIdx.x + o];
        __syncthreads();
    }
    if (threadIdx.x == 0) {
        float L = s[0] / den[0];
        unsigned u = __float_as_uint(L);
        u += 0x7fffu + ((u >> 16) & 1u);
        unsigned hi = u >> 16;
        out[0] = hi * 0x10001u;   // bf16-exact low half; ~bf16 value as f32
    }
}

extern "C" void kernel_launch(void* const* d_in, const int* in_sizes, int n_in,
                              void* d_out, int out_size, void* d_ws, size_t ws_size,
                              hipStream_t stream)
{
    const float* x       = (const float*)d_in[0];
    const float* targets = (const float*)d_in[1];
    const float* W_msg   = (const float*)d_in[2];
    const float* b_msg   = (const float*)d_in[3];
    const float* W_mix   = (const float*)d_in[4];
    const float* b_mix   = (const float*)d_in[5];
    const float* W_ih    = (const float*)d_in[6];
    const float* b_ih    = (const float*)d_in[7];
    const float* W_hh    = (const float*)d_in[8];
    const float* b_hh    = (const float*)d_in[9];
    const float* W_ro    = (const float*)d_in[10];
    const float* b_ro    = (const float*)d_in[11];
    const void*  maskp   = d_in[12];
    const int*   esrc    = (const int*)d_in[13];
    const int*   edst    = (const int*)d_in[14];

    char* ws = (char*)d_ws;
    char* img = ws; ws += (size_t)256 * TT * 32768;   // 512 MB interleaved x/agg tile stream
    short* Gp          = (short*)ws; ws += (size_t)18432 * 8 * 2;
    short* WroP        = (short*)ws; ws += (size_t)256 * 8 * 2;
    float* Wc_f32      = (float*)ws; ws += 16384 * 4;
    float* bvec        = (float*)ws; ws += 128 * 4;
    float* gvec        = (float*)ws; ws += 384 * 4;
    float* cvec        = (float*)ws; ws += 384 * 4;
    float* degf        = (float*)ws; ws += 4096 * 4;
    float* lossBlock   = (float*)ws; ws += 256 * 4;
    int*   csr_off     = (int*)ws;   ws += 4104 * 4;
    int*   cursor      = (int*)ws;   ws += 4096 * 4;
    int*   counts      = (int*)ws;   ws += 4096 * 4;
    int*   csr_src     = (int*)ws;   ws += (size_t)EE * 4;
    int*   flag        = (int*)ws;   ws += 64;
    float* den         = (float*)ws; ws += 64;

    hipMemsetAsync(counts, 0, 4096 * 4, stream);
    hipMemsetAsync(flag, 0, 64, stream);
    hipMemsetAsync(den, 0, 4, stream);

    detect_kernel   <<<4096, 256, 0, stream>>>((const unsigned char*)maskp, flag);
    masksum_kernel  <<<4096, 256, 0, stream>>>(maskp, flag, den);
    count_kernel    <<<EE / 256, 256, 0, stream>>>(edst, counts);
    scan_kernel     <<<1, 1024, 0, stream>>>(counts, csr_off, cursor, degf);
    fill_kernel     <<<EE / 256, 256, 0, stream>>>(esrc, edst, cursor, csr_src);
    pack_wc_kernel  <<<64, 256, 0, stream>>>(W_msg, W_mix, Wc_f32);
    pack_bvec_kernel<<<1, 128, 0, stream>>>(b_msg, W_mix, bvec);
    pack_gbias_kernel<<<1, 384, 0, stream>>>(bvec, b_mix, W_ih, b_ih, b_hh, gvec, cvec);
    pack_G_kernel   <<<72, 256, 0, stream>>>(Wc_f32, W_mix, W_ih, W_hh, Gp);
    pack_wro_kernel <<<1, 256, 0, stream>>>(W_ro, WroP);

    cvt_img_kernel  <<<16384, 256, 0, stream>>>(x, img);
    gather_quad_kernel<<<16384, 256, 0, stream>>>(img, csr_off, csr_src);

    mega10_kernel<<<256, 512, 0, stream>>>(img, Gp, WroP, degf, gvec, cvec, b_hh, b_ro,
                                           targets, maskp, flag, lossBlock);
    final_kernel<<<1, 256, 0, stream>>>(lossBlock, den, (unsigned*)d_out);
}

// Round 18
// 1211.536 us; speedup vs baseline: 1.8234x; 1.0023x over previous
//
#include <hip/hip_runtime.h>
#include <hip/hip_bf16.h>
#include <stdint.h>

#define BB 4
#define TT 64
#define NN 4096
#define HH 128
#define EE 65536
#define BN (BB*NN)   // 16384

typedef __attribute__((ext_vector_type(8))) short short8;
typedef __attribute__((ext_vector_type(4))) float f32x4;

__device__ __forceinline__ unsigned short bf16r(float f) {
    unsigned u = __float_as_uint(f);
    u += 0x7fffu + ((u >> 16) & 1u);
    return (unsigned short)(u >> 16);
}
__device__ __forceinline__ unsigned cvt_pk_bf16(float lo_, float hi_) {
    unsigned r;
    asm("v_cvt_pk_bf16_f32 %0, %1, %2" : "=v"(r) : "v"(lo_), "v"(hi_));
    return r;
}
__device__ __forceinline__ unsigned short bf16s(float f) {
    unsigned r;
    asm("v_cvt_pk_bf16_f32 %0, %1, %1" : "=v"(r) : "v"(f));
    return (unsigned short)r;
}
__device__ __forceinline__ float bf2f(unsigned bits16) {
    return __uint_as_float(bits16 << 16);
}
__device__ __forceinline__ float sigm(float x) { return 1.f / (1.f + __expf(-x)); }
__device__ __forceinline__ float tanhfast(float x) {
    return 1.f - 2.f / (__expf(2.f * x) + 1.f);
}
// byte address within a [64][128]-bf16 tile; 4-bit XOR swizzle -> conflict-free b128 frag reads
__device__ __forceinline__ unsigned swz(int row, int colbyte) {
    return (unsigned)(row * 256 + (colbyte ^ ((row & 15) << 4)));
}

#define GLD_LDS16(g, s) __builtin_amdgcn_global_load_lds( \
    (const __attribute__((address_space(1))) void*)(g), \
    (__attribute__((address_space(3))) void*)(s), 16, 0, 0)

// ================= packs =================
__global__ void pack_wc_kernel(const float* __restrict__ W_msg, const float* __restrict__ W_mix,
                               float* __restrict__ Wc)
{
    int idx = blockIdx.x * 256 + threadIdx.x;   // 16384
    int k = idx >> 7, j = idx & 127;
    float s = 0.f;
    for (int i = 0; i < 128; ++i) s += W_msg[k * 128 + i] * W_mix[i * 128 + j];
    Wc[idx] = s;
}

__global__ void pack_bvec_kernel(const float* __restrict__ b_msg, const float* __restrict__ W_mix,
                                 float* __restrict__ bvec)
{
    int j = threadIdx.x;   // 128
    float s = 0.f;
    for (int i = 0; i < 128; ++i) s += b_msg[i] * W_mix[i * 128 + j];
    bvec[j] = s;
}

__global__ void pack_gbias_kernel(const float* __restrict__ bvec, const float* __restrict__ b_mix,
                                  const float* __restrict__ W_ih, const float* __restrict__ b_ih,
                                  const float* __restrict__ b_hh,
                                  float* __restrict__ gvec, float* __restrict__ cvec)
{
    int c = threadIdx.x;   // 384
    float g = 0.f, gb = 0.f;
    for (int j = 0; j < 128; ++j) {
        g  += bvec[j]  * W_ih[j * 384 + c];
        gb += b_mix[j] * W_ih[j * 384 + c];
    }
    gvec[c] = g;
    cvec[c] = gb + b_ih[c] + (c < 256 ? b_hh[c] : 0.f);
}

// Gp[mat(9)][nt(8)][ks(4)][lane(64)][8]
__global__ void pack_G_kernel(const float* __restrict__ Wc, const float* __restrict__ W_mix,
                              const float* __restrict__ W_ih, const float* __restrict__ W_hh,
                              short* __restrict__ Gp)
{
    int idx = blockIdx.x * 256 + threadIdx.x;   // 18432
    if (idx >= 18432) return;
    int l = idx & 63, ks = (idx >> 6) & 3, nt = (idx >> 8) & 7, mat = idx >> 11;
    int lo = l & 15, hi = l >> 4;
    int col = nt * 16 + lo;
    short8 v;
    #pragma unroll
    for (int i = 0; i < 8; ++i) {
        int k = ks * 32 + hi * 8 + i;
        float s;
        if (mat < 3) {
            int c = mat * 128 + col;
            s = 0.f;
            for (int j = 0; j < 128; ++j) s += Wc[k * 128 + j] * W_ih[j * 384 + c];
        } else if (mat < 6) {
            int c = (mat - 3) * 128 + col;
            s = 0.f;
            for (int j = 0; j < 128; ++j) s += W_mix[(128 + k) * 128 + j] * W_ih[j * 384 + c];
        } else {
            int c = (mat - 6) * 128 + col;
            s = W_hh[k * 384 + c];
        }
        v[i] = (short)bf16r(s);
    }
    *(short8*)(Gp + (size_t)idx * 8) = v;
}

// W_roP: [ks(4)][lane(64)][8]; only col 0 nonzero = W_ro[k]
__global__ void pack_wro_kernel(const float* __restrict__ W_ro, short* __restrict__ out)
{
    int idx = threadIdx.x;      // 256
    int l = idx & 63, ks = idx >> 6;
    int lo = l & 15, hi = l >> 4;
    short8 v;
    #pragma unroll
    for (int i = 0; i < 8; ++i) {
        int k = ks * 32 + hi * 8 + i;
        v[i] = (lo == 0) ? (short)bf16r(W_ro[k]) : (short)0;
    }
    *(short8*)(out + (size_t)idx * 8) = v;
}

// ================= x -> pre-swizzled bf16 x-tiles inside img =================
__global__ __launch_bounds__(256)
void cvt_img_kernel(const float* __restrict__ x, char* __restrict__ img)
{
    int tileid = blockIdx.x;              // phys*64 + t  (16384)
    int phys = tileid >> 6, t = tileid & 63;
    int b = phys >> 6, n0 = (phys & 63) * 64;
    const float* __restrict__ src = x + ((size_t)(b * TT + t) * NN + n0) * HH;
    char* __restrict__ dst = img + (size_t)tileid * 32768;
    int tid = threadIdx.x;
    #pragma unroll
    for (int u4 = 0; u4 < 4; ++u4) {
        int unit = tid + u4 * 256;          // 1024 units of 16B
        int row = unit >> 4, g = unit & 15;
        const float* sp = src + row * HH + g * 8;
        float4 v0 = *(const float4*)sp;
        float4 v1 = *(const float4*)(sp + 4);
        uint4 o;
        o.x = cvt_pk_bf16(v0.x, v0.y);
        o.y = cvt_pk_bf16(v0.z, v0.w);
        o.z = cvt_pk_bf16(v1.x, v1.y);
        o.w = cvt_pk_bf16(v1.z, v1.w);
        *(uint4*)(dst + swz(row, g * 16)) = o;
    }
}

// ================= gather: 4 bts/block, 8-edge unroll (16 loads in flight) =====
#define GQ_ADDR(sv) (((size_t)((sv) >> 6) << 21) + ((unsigned)((sv) & 63) << 8) \
                     + ((L * 8) ^ (((sv) & 15) << 4)))
#define GQ_ACC(vA, vB) do { \
    aA0 += __uint_as_float((vA).x << 16); \
    aA1 += __uint_as_float((vA).x & 0xffff0000u); \
    aA2 += __uint_as_float((vA).y << 16); \
    aA3 += __uint_as_float((vA).y & 0xffff0000u); \
    aB0 += __uint_as_float((vB).x << 16); \
    aB1 += __uint_as_float((vB).x & 0xffff0000u); \
    aB2 += __uint_as_float((vB).y << 16); \
    aB3 += __uint_as_float((vB).y & 0xffff0000u); } while (0)

__global__ __launch_bounds__(256)
void gather_quad_kernel(char* __restrict__ img,
                        const int* __restrict__ off, const int* __restrict__ srcs)
{
    int bid = blockIdx.x;               // 16384
    int xcd = bid & 7;
    int rest = bid >> 3;                // 0..2047
    int grp = rest >> 8;                // 0..7
    int chunk = rest & 255;             // 0..255
    int w = threadIdx.x >> 6, l = threadIdx.x & 63;
    int half = l >> 5, L = l & 31;
    size_t baseA, baseB;
    {
        int btA = (grp * 4 + half * 2 + 0) * 8 + xcd;
        int btB = (grp * 4 + half * 2 + 1) * 8 + xcd;
        baseA = ((size_t)(btA >> 6) * 4096 + (btA & 63)) * 32768;
        baseB = ((size_t)(btB >> 6) * 4096 + (btB & 63)) * 32768;
    }

    #pragma unroll
    for (int r = 0; r < 4; ++r) {
        int dst = chunk * 16 + w * 4 + r;
        int s = off[dst], e = off[dst + 1];
        float aA0 = 0.f, aA1 = 0.f, aA2 = 0.f, aA3 = 0.f;
        float aB0 = 0.f, aB1 = 0.f, aB2 = 0.f, aB3 = 0.f;
        int i = s;
        for (; i + 7 < e; i += 8) {
            size_t t0 = GQ_ADDR(srcs[i + 0]);
            size_t t1 = GQ_ADDR(srcs[i + 1]);
            size_t t2 = GQ_ADDR(srcs[i + 2]);
            size_t t3 = GQ_ADDR(srcs[i + 3]);
            size_t t4 = GQ_ADDR(srcs[i + 4]);
            size_t t5 = GQ_ADDR(srcs[i + 5]);
            size_t t6 = GQ_ADDR(srcs[i + 6]);
            size_t t7 = GQ_ADDR(srcs[i + 7]);
            uint2 vA0 = *(const uint2*)(img + baseA + t0);
            uint2 vB0 = *(const uint2*)(img + baseB + t0);
            uint2 vA1 = *(const uint2*)(img + baseA + t1);
            uint2 vB1 = *(const uint2*)(img + baseB + t1);
            uint2 vA2 = *(const uint2*)(img + baseA + t2);
            uint2 vB2 = *(const uint2*)(img + baseB + t2);
            uint2 vA3 = *(const uint2*)(img + baseA + t3);
            uint2 vB3 = *(const uint2*)(img + baseB + t3);
            uint2 vA4 = *(const uint2*)(img + baseA + t4);
            uint2 vB4 = *(const uint2*)(img + baseB + t4);
            uint2 vA5 = *(const uint2*)(img + baseA + t5);
            uint2 vB5 = *(const uint2*)(img + baseB + t5);
            uint2 vA6 = *(const uint2*)(img + baseA + t6);
            uint2 vB6 = *(const uint2*)(img + baseB + t6);
            uint2 vA7 = *(const uint2*)(img + baseA + t7);
            uint2 vB7 = *(const uint2*)(img + baseB + t7);
            GQ_ACC(vA0, vB0); GQ_ACC(vA1, vB1); GQ_ACC(vA2, vB2); GQ_ACC(vA3, vB3);
            GQ_ACC(vA4, vB4); GQ_ACC(vA5, vB5); GQ_ACC(vA6, vB6); GQ_ACC(vA7, vB7);
        }
        for (; i + 3 < e; i += 4) {
            size_t t0 = GQ_ADDR(srcs[i + 0]);
            size_t t1 = GQ_ADDR(srcs[i + 1]);
            size_t t2 = GQ_ADDR(srcs[i + 2]);
            size_t t3 = GQ_ADDR(srcs[i + 3]);
            uint2 vA0 = *(const uint2*)(img + baseA + t0);
            uint2 vB0 = *(const uint2*)(img + baseB + t0);
            uint2 vA1 = *(const uint2*)(img + baseA + t1);
            uint2 vB1 = *(const uint2*)(img + baseB + t1);
            uint2 vA2 = *(const uint2*)(img + baseA + t2);
            uint2 vB2 = *(const uint2*)(img + baseB + t2);
            uint2 vA3 = *(const uint2*)(img + baseA + t3);
            uint2 vB3 = *(const uint2*)(img + baseB + t3);
            GQ_ACC(vA0, vB0); GQ_ACC(vA1, vB1); GQ_ACC(vA2, vB2); GQ_ACC(vA3, vB3);
        }
        for (; i < e; ++i) {
            size_t t0 = GQ_ADDR(srcs[i]);
            uint2 vA0 = *(const uint2*)(img + baseA + t0);
            uint2 vB0 = *(const uint2*)(img + baseB + t0);
            GQ_ACC(vA0, vB0);
        }
        size_t doff = 16384 + ((size_t)(dst >> 6) << 21) + ((unsigned)(dst & 63) << 8)
                    + ((L * 8) ^ ((dst & 15) << 4));
        uint2 oA, oB;
        oA.x = cvt_pk_bf16(aA0, aA1);
        oA.y = cvt_pk_bf16(aA2, aA3);
        oB.x = cvt_pk_bf16(aB0, aB1);
        oB.y = cvt_pk_bf16(aB2, aB3);
        *(uint2*)(img + baseA + doff) = oA;
        *(uint2*)(img + baseB + doff) = oB;
    }
}

// ======== persistent T-loop: 1 barrier/step, gld_lds dbuf staging, 8-wave GEMV ========
#define STEP10(T, SXC, SXN, SAC, SAN, SSC, SSN) { \
    const int t = (T); \
    float tgtNext = 0.f, mvNext = 0.f; \
    if (tid < 64) { \
        size_t ti = (size_t)(b * TT + t) * NN + n0 + tid; \
        tgtNext = targets[ti]; \
        mvNext = fl ? (((const unsigned char*)maskp)[ti] ? 1.f : 0.f) \
                    : (((const int*)maskp)[ti] ? 1.f : 0.f); \
    } \
    if (t + 1 < TT) { \
        const char* g = img + tbase + (size_t)(t + 1) * 32768 + (w * 2) * 1024 + l * 16; \
        GLD_LDS16(g,                 (char*)SXN + (w * 2) * 1024); \
        GLD_LDS16(g + 1024,          (char*)SXN + (w * 2 + 1) * 1024); \
        GLD_LDS16(g + 16384,         (char*)SAN + (w * 2) * 1024); \
        GLD_LDS16(g + 16384 + 1024,  (char*)SAN + (w * 2 + 1) * 1024); \
    } \
    f32x4 R[4] = {}, Z[4] = {}, N4[4] = {}, H4[4] = {}; \
    _Pragma("unroll") \
    for (int ks = 0; ks < 4; ++ks) { \
        short8 af[4]; \
        _Pragma("unroll") \
        for (int s4 = 0; s4 < 4; ++s4) \
            af[s4] = *(const short8*)((const char*)SAC + swz(s4 * 16 + lo, ks * 64 + hi * 16)); \
        _Pragma("unroll") \
        for (int s4 = 0; s4 < 4; ++s4) \
            R[s4] = __builtin_amdgcn_mfma_f32_16x16x32_bf16(af[s4], wf[0][ks], R[s4], 0, 0, 0); \
        _Pragma("unroll") \
        for (int s4 = 0; s4 < 4; ++s4) \
            Z[s4] = __builtin_amdgcn_mfma_f32_16x16x32_bf16(af[s4], wf[1][ks], Z[s4], 0, 0, 0); \
        _Pragma("unroll") \
        for (int s4 = 0; s4 < 4; ++s4) \
            N4[s4] = __builtin_amdgcn_mfma_f32_16x16x32_bf16(af[s4], wf[2][ks], N4[s4], 0, 0, 0); \
    } \
    _Pragma("unroll") \
    for (int ks = 0; ks < 4; ++ks) { \
        short8 af[4]; \
        _Pragma("unroll") \
        for (int s4 = 0; s4 < 4; ++s4) \
            af[s4] = *(const short8*)((const char*)SSC + swz(s4 * 16 + lo, ks * 64 + hi * 16)); \
        _Pragma("unroll") \
        for (int s4 = 0; s4 < 4; ++s4) \
            R[s4] = __builtin_amdgcn_mfma_f32_16x16x32_bf16(af[s4], wf[3][ks], R[s4], 0, 0, 0); \
        _Pragma("unroll") \
        for (int s4 = 0; s4 < 4; ++s4) \
            Z[s4] = __builtin_amdgcn_mfma_f32_16x16x32_bf16(af[s4], wf[4][ks], Z[s4], 0, 0, 0); \
        _Pragma("unroll") \
        for (int s4 = 0; s4 < 4; ++s4) \
            N4[s4] = __builtin_amdgcn_mfma_f32_16x16x32_bf16(af[s4], wf[5][ks], N4[s4], 0, 0, 0); \
    } \
    _Pragma("unroll") \
    for (int ks = 0; ks < 4; ++ks) { \
        short8 af[4]; \
        _Pragma("unroll") \
        for (int s4 = 0; s4 < 4; ++s4) \
            af[s4] = *(const short8*)((const char*)SXC + swz(s4 * 16 + lo, ks * 64 + hi * 16)); \
        _Pragma("unroll") \
        for (int s4 = 0; s4 < 4; ++s4) \
            R[s4] = __builtin_amdgcn_mfma_f32_16x16x32_bf16(af[s4], wf[6][ks], R[s4], 0, 0, 0); \
        _Pragma("unroll") \
        for (int s4 = 0; s4 < 4; ++s4) \
            Z[s4] = __builtin_amdgcn_mfma_f32_16x16x32_bf16(af[s4], wf[7][ks], Z[s4], 0, 0, 0); \
        _Pragma("unroll") \
        for (int s4 = 0; s4 < 4; ++s4) \
            H4[s4] = __builtin_amdgcn_mfma_f32_16x16x32_bf16(af[s4], wf[8][ks], H4[s4], 0, 0, 0); \
    } \
    _Pragma("unroll") \
    for (int s4 = 0; s4 < 4; ++s4) \
        _Pragma("unroll") \
        for (int q = 0; q < 4; ++q) { \
            int row = s4 * 16 + hi * 4 + q; \
            float dg = sdeg[row]; \
            float rv = sigm(R[s4][q] + fmaf(dg, gvR, cR)); \
            float zv = sigm(Z[s4][q] + fmaf(dg, gvZ, cZ)); \
            float nv = tanhfast(N4[s4][q] + fmaf(dg, gvN, cN) + rv * (H4[s4][q] + bH)); \
            float xv = bf2f(*(const unsigned short*)((const char*)SXC + swz(row, jcol * 2))); \
            float ns = fmaf(zv, xv - nv, nv); \
            *(unsigned short*)((char*)SSN + swz(row, jcol * 2)) = bf16s(ns); \
        } \
    __syncthreads();   /* ONE barrier: drains gld_lds(t+1); publishes SSN */ \
    { \
        const int band = w & 3, khalf = w >> 2; \
        f32x4 acc = {}; \
        _Pragma("unroll") \
        for (int kk = 0; kk < 2; ++kk) { \
            int ks = khalf * 2 + kk; \
            short8 af = *(const short8*)((const char*)SSN + swz(band * 16 + lo, ks * 64 + hi * 16)); \
            short8 bw = *(const short8*)(WroP + (size_t)(ks * 64 + l) * 8); \
            acc = __builtin_amdgcn_mfma_f32_16x16x32_bf16(af, bw, acc, 0, 0, 0); \
        } \
        if (lo == 0) { \
            _Pragma("unroll") \
            for (int q = 0; q < 4; ++q) \
                pOut[t & 1][khalf][band * 16 + hi * 4 + q] = acc[q]; \
        } \
    } \
    if (tid < 64 && t > 0) { \
        float out = pOut[(t & 1) ^ 1][0][tid] + pOut[(t & 1) ^ 1][1][tid] + bro; \
        float d = out - tgtCur; \
        lossAcc += 0.5f * d * d * mvCur; \
    } \
    tgtCur = tgtNext; mvCur = mvNext; \
}

__global__ __launch_bounds__(512, 2)
void mega10_kernel(const char* __restrict__ img,
                   const short* __restrict__ Gp, const short* __restrict__ WroP,
                   const float* __restrict__ degf,
                   const float* __restrict__ gvec, const float* __restrict__ cvec,
                   const float* __restrict__ b_hh, const float* __restrict__ b_ro,
                   const float* __restrict__ targets, const void* __restrict__ maskp,
                   const int* __restrict__ flag,
                   float* __restrict__ lossBlock)
{
    __shared__ char sX0[16384];
    __shared__ char sX1[16384];
    __shared__ char sA0[16384];
    __shared__ char sA1[16384];
    __shared__ char sS0[16384];
    __shared__ char sS1[16384];
    __shared__ float sdeg[64];
    __shared__ float pOut[2][2][64];
    __shared__ float pLoss[8];

    const int tid = threadIdx.x;
    const int w = tid >> 6, l = tid & 63, lo = l & 15, hi = l >> 4;
    const int nt = w;
    const int phys = blockIdx.x;
    const int b = phys >> 6;
    const int n0 = (phys & 63) * 64;
    const size_t tbase = (size_t)phys * TT * 32768;

    // ---- 36 weight fragments in registers ----
    short8 wf[9][4];
    #pragma unroll
    for (int m = 0; m < 9; ++m)
        #pragma unroll
        for (int ks = 0; ks < 4; ++ks)
            wf[m][ks] = *(const short8*)(Gp + (size_t)(((m * 8 + nt) * 4 + ks) * 64 + l) * 8);

    const int jcol = nt * 16 + lo;
    const float gvR = gvec[jcol], gvZ = gvec[128 + jcol], gvN = gvec[256 + jcol];
    const float cR = cvec[jcol], cZ = cvec[128 + jcol], cN = cvec[256 + jcol];
    const float bH = b_hh[256 + jcol];
    const float bro = b_ro[0];
    const int fl = *flag;

    // ---- prologue: async-stage t=0, zero state ----
    {
        const char* g = img + tbase + (w * 2) * 1024 + l * 16;
        GLD_LDS16(g,                sX0 + (w * 2) * 1024);
        GLD_LDS16(g + 1024,         sX0 + (w * 2 + 1) * 1024);
        GLD_LDS16(g + 16384,        sA0 + (w * 2) * 1024);
        GLD_LDS16(g + 16384 + 1024, sA0 + (w * 2 + 1) * 1024);
    }
    #pragma unroll
    for (int it = 0; it < 8; ++it) ((unsigned*)sS0)[tid + it * 512] = 0u;
    if (tid < 64) sdeg[tid] = degf[n0 + tid];
    float tgtCur = 0.f, mvCur = 0.f, lossAcc = 0.f;
    __syncthreads();   // drains prologue staging

    for (int tt = 0; tt < TT; tt += 2) {
        STEP10(tt,     sX0, sX1, sA0, sA1, sS0, sS1)
        STEP10(tt + 1, sX1, sX0, sA1, sA0, sS1, sS0)
    }

    __syncthreads();   // pOut[1] (t=63) visible to wave 0
    if (tid < 64) {
        float out = pOut[1][0][tid] + pOut[1][1][tid] + bro;
        float d = out - tgtCur;
        lossAcc += 0.5f * d * d * mvCur;
    }

    float v = lossAcc;
    #pragma unroll
    for (int o = 1; o < 64; o <<= 1) v += __shfl_xor(v, o);
    if (l == 0) pLoss[w] = v;
    __syncthreads();
    if (tid == 0) {
        float s = 0.f;
        #pragma unroll
        for (int ww = 0; ww < 8; ++ww) s += pLoss[ww];
        lossBlock[phys] = s;
    }
}

// ================= CSR build =================
__global__ void count_kernel(const int* __restrict__ dst, int* __restrict__ counts)
{
    int e = blockIdx.x * 256 + threadIdx.x;
    if (e < EE) atomicAdd(&counts[dst[e]], 1);
}

__global__ __launch_bounds__(1024)
void scan_kernel(const int* __restrict__ counts, int* __restrict__ off, int* __restrict__ cursor,
                 float* __restrict__ degf)
{
    __shared__ int s[1024];
    int tid = threadIdx.x;
    int base = tid * 4;
    int c[4]; int sum = 0;
    #pragma unroll
    for (int i = 0; i < 4; ++i) { c[i] = counts[base + i]; sum += c[i]; }
    s[tid] = sum; __syncthreads();
    for (int o = 1; o < 1024; o <<= 1) {
        int v = (tid >= o) ? s[tid - o] : 0;
        __syncthreads();
        s[tid] += v;
        __syncthreads();
    }
    int incl = s[tid];
    int run = incl - sum;
    #pragma unroll
    for (int i = 0; i < 4; ++i) {
        off[base + i] = run; cursor[base + i] = run;
        degf[base + i] = (float)c[i];
        run += c[i];
    }
    if (tid == 1023) off[4096] = incl;
}

__global__ void fill_kernel(const int* __restrict__ src, const int* __restrict__ dst,
                            int* __restrict__ cursor, int* __restrict__ csr_src)
{
    int e = blockIdx.x * 256 + threadIdx.x;
    if (e < EE) {
        int d = dst[e];
        int pos = atomicAdd(&cursor[d], 1);
        csr_src[pos] = src[e];
    }
}

// ================= mask detect / masked count =================
__global__ void detect_kernel(const unsigned char* __restrict__ maskb, int* __restrict__ flag)
{
    int i = blockIdx.x * 256 + threadIdx.x;
    bool hit = (i < BB * TT * NN) && (i & 3) && maskb[i];
    if (__any(hit) && (threadIdx.x & 63) == 0) atomicOr(flag, 1);
}

__global__ void masksum_kernel(const void* __restrict__ maskp, const int* __restrict__ flag,
                               float* __restrict__ den)
{
    int i = blockIdx.x * 256 + threadIdx.x;
    float v = 0.f;
    if (i < BB * TT * NN) {
        if (*flag) v = ((const unsigned char*)maskp)[i] ? 1.f : 0.f;
        else       v = ((const int*)maskp)[i] ? 1.f : 0.f;
    }
    #pragma unroll
    for (int o = 32; o > 0; o >>= 1) v += __shfl_down(v, o);
    __shared__ float sm[4];
    if ((threadIdx.x & 63) == 0) sm[threadIdx.x >> 6] = v;
    __syncthreads();
    if (threadIdx.x == 0) atomicAdd(den, sm[0] + sm[1] + sm[2] + sm[3]);
}

// ================= final reduce + dual-dtype output =================
__global__ __launch_bounds__(256)
void final_kernel(const float* __restrict__ lossBlock, const float* __restrict__ den,
                  unsigned* __restrict__ out)
{
    __shared__ float s[256];
    s[threadIdx.x] = lossBlock[threadIdx.x];
    __syncthreads();
    for (int o = 128; o > 0; o >>= 1) {
        if (threadIdx.x < o) s[threadIdx.x] += s[threadIdx.x + o];
        __syncthreads();
    }
    if (threadIdx.x == 0) {
        float L = s[0] / den[0];
        unsigned u = __float_as_uint(L);
        u += 0x7fffu + ((u >> 16) & 1u);
        unsigned hi = u >> 16;
        out[0] = hi * 0x10001u;   // bf16-exact low half; ~bf16 value as f32
    }
}

extern "C" void kernel_launch(void* const* d_in, const int* in_sizes, int n_in,
                              void* d_out, int out_size, void* d_ws, size_t ws_size,
                              hipStream_t stream)
{
    const float* x       = (const float*)d_in[0];
    const float* targets = (const float*)d_in[1];
    const float* W_msg   = (const float*)d_in[2];
    const float* b_msg   = (const float*)d_in[3];
    const float* W_mix   = (const float*)d_in[4];
    const float* b_mix   = (const float*)d_in[5];
    const float* W_ih    = (const float*)d_in[6];
    const float* b_ih    = (const float*)d_in[7];
    const float* W_hh    = (const float*)d_in[8];
    const float* b_hh    = (const float*)d_in[9];
    const float* W_ro    = (const float*)d_in[10];
    const float* b_ro    = (const float*)d_in[11];
    const void*  maskp   = d_in[12];
    const int*   esrc    = (const int*)d_in[13];
    const int*   edst    = (const int*)d_in[14];

    char* ws = (char*)d_ws;
    char* img = ws; ws += (size_t)256 * TT * 32768;   // 512 MB interleaved x/agg tile stream
    short* Gp          = (short*)ws; ws += (size_t)18432 * 8 * 2;
    short* WroP        = (short*)ws; ws += (size_t)256 * 8 * 2;
    float* Wc_f32      = (float*)ws; ws += 16384 * 4;
    float* bvec        = (float*)ws; ws += 128 * 4;
    float* gvec        = (float*)ws; ws += 384 * 4;
    float* cvec        = (float*)ws; ws += 384 * 4;
    float* degf        = (float*)ws; ws += 4096 * 4;
    float* lossBlock   = (float*)ws; ws += 256 * 4;
    int*   csr_off     = (int*)ws;   ws += 4104 * 4;
    int*   cursor      = (int*)ws;   ws += 4096 * 4;
    int*   counts      = (int*)ws;   ws += 4096 * 4;
    int*   csr_src     = (int*)ws;   ws += (size_t)EE * 4;
    int*   flag        = (int*)ws;   ws += 64;
    float* den         = (float*)ws; ws += 64;

    hipMemsetAsync(counts, 0, 4096 * 4, stream);
    hipMemsetAsync(flag, 0, 64, stream);
    hipMemsetAsync(den, 0, 4, stream);

    detect_kernel   <<<4096, 256, 0, stream>>>((const unsigned char*)maskp, flag);
    masksum_kernel  <<<4096, 256, 0, stream>>>(maskp, flag, den);
    count_kernel    <<<EE / 256, 256, 0, stream>>>(edst, counts);
    scan_kernel     <<<1, 1024, 0, stream>>>(counts, csr_off, cursor, degf);
    fill_kernel     <<<EE / 256, 256, 0, stream>>>(esrc, edst, cursor, csr_src);
    pack_wc_kernel  <<<64, 256, 0, stream>>>(W_msg, W_mix, Wc_f32);
    pack_bvec_kernel<<<1, 128, 0, stream>>>(b_msg, W_mix, bvec);
    pack_gbias_kernel<<<1, 384, 0, stream>>>(bvec, b_mix, W_ih, b_ih, b_hh, gvec, cvec);
    pack_G_kernel   <<<72, 256, 0, stream>>>(Wc_f32, W_mix, W_ih, W_hh, Gp);
    pack_wro_kernel <<<1, 256, 0, stream>>>(W_ro, WroP);

    cvt_img_kernel  <<<16384, 256, 0, stream>>>(x, img);
    gather_quad_kernel<<<16384, 256, 0, stream>>>(img, csr_off, csr_src);

    mega10_kernel<<<256, 512, 0, stream>>>(img, Gp, WroP, degf, gvec, cvec, b_hh, b_ro,
                                           targets, maskp, flag, lossBlock);
    final_kernel<<<1, 256, 0, stream>>>(lossBlock, den, (unsigned*)d_out);
}